// Round 11
// baseline (763.796 us; speedup 1.0000x reference)
//
#include <hip/hip_runtime.h>
#include <hip/hip_bf16.h>

// E=128 GH=8 GD=16 GL=3 | SH=4 SD=32 SL=4 | N=32 GC=64 GS=16 DEG=64 BMOL=16
// M_conf=4096 M_scaf=1024 M_tot=5120. All float tensors fp32.
// Schedule (seq shifted one stage ahead of graph):
//  D1 front | D2 edge+sqkv0 | D3 ln+sattn0 | per l=0..2: (gqkv_l+stail_l),(gattn_l+sqkv_{l+1}),(gtail_l+sattn_{l+1})
//  D12 stail3 | D13 head

// ---------------------------------------------------------------- shared-mem structs (union'd per combo kernel)
struct __align__(16) EdgeSm  { float efs[64][4]; float As[32][68]; float Bs[32][136]; };      // ~27.1KB
struct __align__(16) G16Sm   { float Sa[32][20]; float Bs[32][136]; };                        // ~19.9KB
struct __align__(16) GAttnSm { float qs[32][17], ksh[32][17], vsh[32][17], ss[32][33], rs[32]; };
struct __align__(16) SAttnSm { float kv[32][33], qs2[32][33], ss2[32][129], red[32][8], red2[32][8]; }; // ~26.4KB
struct __align__(16) TailSm  { float x1[16][132]; float hid[16][260]; float sbuf[4352]; float Sa[32][20]; };

union K1U { EdgeSm e; G16Sm g; };
union K2U { float sred4[4]; SAttnSm s; };
union K3U { G16Sm g; TailSm t; };
union K4U { GAttnSm a; G16Sm g; };
union K5U { TailSm t; SAttnSm s; };

// ---------------------------------------------------------------- merged front-end
__global__ __launch_bounds__(256) void front_k(
    const float* __restrict__ cx, const float* __restrict__ sx,
    const float* __restrict__ w, const float* __restrict__ b,
    float* __restrict__ h, float* __restrict__ aggr,
    const float* __restrict__ cpos, const float* __restrict__ spos, float* __restrict__ dist,
    const int* __restrict__ tokens, const float* __restrict__ tok_emb,
    const float* __restrict__ pos_emb, float* __restrict__ xs)
{
  __shared__ float sP[128];
  const int bx = blockIdx.x, tid = threadIdx.x;
  if (bx < 1280) {
    int r = bx * 2 + (tid >> 7), e = tid & 127;
    const float* x = (r < 2048) ? (cx + (size_t)r * 64) : (sx + (size_t)(r - 2048) * 64);
    float* xrow = sP + (tid >> 7) * 64;
    if (e < 64) xrow[e] = x[e];
    __syncthreads();
    float acc = b[e];
    for (int a = 0; a < 64; a++) acc += xrow[a] * w[a * 128 + e];
    h[(size_t)r * 128 + e] = acc;
    aggr[(size_t)r * 128 + e] = 0.0f;
  } else if (bx < 1360) {
    int g = bx - 1280;
    const float* p = (g < 64) ? (cpos + (size_t)g * 96) : (spos + (size_t)(g - 64) * 96);
    if (tid < 96) sP[tid] = p[tid];
    __syncthreads();
    #pragma unroll
    for (int jj = 0; jj < 4; jj++) {
      int idx = tid * 4 + jj;
      int i = idx >> 5, j = idx & 31;
      float dx = sP[i * 3 + 0] - sP[j * 3 + 0];
      float dy = sP[i * 3 + 1] - sP[j * 3 + 1];
      float dz = sP[i * 3 + 2] - sP[j * 3 + 2];
      float d2 = dx * dx + dy * dy + dz * dz;
      dist[(size_t)g * 1024 + idx] = (d2 > 0.0f) ? sqrtf(d2) : 0.0f;
    }
  } else {
    int r = (bx - 1360) * 2 + (tid >> 7), e = tid & 127;
    int tk = tokens[r];
    xs[(size_t)r * 128 + e] = tok_emb[(size_t)tk * 128 + e] + pos_emb[(size_t)(r & 127) * 128 + e];
  }
}

// ---------------------------------------------------------------- edge body: 64-edge tile x 14-kt chunk,
// hd in regs, micro 4 rows x (4+4 split cols) -> B reads are 4-address broadcasts. grid part: 1120.
__device__ __forceinline__ void edge_body(EdgeSm& sm, int eb,
    const float* __restrict__ cea, const float* __restrict__ sea,
    const int* __restrict__ cei, const int* __restrict__ sei,
    const float* __restrict__ h,
    const float* __restrict__ elw, const float* __restrict__ elb,
    float* __restrict__ aggr)
{
  const int tid = threadIdx.x;
  const int m0 = (eb % 80) * 64;
  const int kt0 = (eb / 80) * 14;
  const int c0 = kt0 >> 2;          // 14 kts span <=4 c's (c0..c0+3), c<=48 always
  {
    int t = tid >> 2, cc = tid & 3;
    int c = c0 + cc;
    int m = m0 + t;
    const float* attr = (m < 4096) ? (cea + (size_t)m * 17) : (sea + (size_t)(m - 4096) * 17);
    float val;
    if (c < 16) val = attr[c];
    else if (c < 48) {
      float d = fminf(fmaxf(attr[16], 0.0f), 10.0f);
      float t2 = d - (float)((c - 16) * (5.0 / 31.0));
      val = expf(-38.44f * t2 * t2);           // gamma = (31/5)^2
    } else val = 1.0f;
    sm.efs[t][cc] = val;
  }
  const int gk = tid & 31, g8 = tid >> 5;      // A-gen: k lane, 8-edge group
  float hreg[8][4];
  #pragma unroll
  for (int i = 0; i < 8; i++) {
    int m = m0 + g8 * 8 + i;
    int dst = (m < 4096) ? cei[4096 + m] : (sei[1024 + (m - 4096)] + 2048);
    const float* hp = h + (size_t)dst * 128 + gk;
    hreg[i][0] = hp[0]; hreg[i][1] = hp[32]; hreg[i][2] = hp[64]; hreg[i][3] = hp[96];
  }
  const int rg = tid & 15, cg = tid >> 4;
  const int r0 = 4 * rg, ca = 4 * cg, cb = 64 + 4 * cg;
  const int se = tid >> 1, sk = (tid & 1) * 16;
  float acc[4][8] = {};
  __syncthreads();
  #pragma unroll 1
  for (int kt = kt0; kt < kt0 + 14; kt++) {
    int c = kt >> 2, cc = c - c0, j = kt & 3;
    float4 a0, a1;
    a0.x = sm.efs[g8 * 8 + 0][cc] * hreg[0][j];
    a0.y = sm.efs[g8 * 8 + 1][cc] * hreg[1][j];
    a0.z = sm.efs[g8 * 8 + 2][cc] * hreg[2][j];
    a0.w = sm.efs[g8 * 8 + 3][cc] * hreg[3][j];
    a1.x = sm.efs[g8 * 8 + 4][cc] * hreg[4][j];
    a1.y = sm.efs[g8 * 8 + 5][cc] * hreg[5][j];
    a1.z = sm.efs[g8 * 8 + 6][cc] * hreg[6][j];
    a1.w = sm.efs[g8 * 8 + 7][cc] * hreg[7][j];
    *(float4*)&sm.As[gk][g8 * 8] = a0;
    *(float4*)&sm.As[gk][g8 * 8 + 4] = a1;
    const float* bp = ((c < 48) ? (elw + (size_t)c * 16384) : elb) + (size_t)se * 128 + j * 32 + sk;
    float4 w0 = *(const float4*)(bp + 0);
    float4 w1 = *(const float4*)(bp + 4);
    float4 w2 = *(const float4*)(bp + 8);
    float4 w3 = *(const float4*)(bp + 12);
    sm.Bs[sk + 0][se] = w0.x;  sm.Bs[sk + 1][se] = w0.y;  sm.Bs[sk + 2][se] = w0.z;  sm.Bs[sk + 3][se] = w0.w;
    sm.Bs[sk + 4][se] = w1.x;  sm.Bs[sk + 5][se] = w1.y;  sm.Bs[sk + 6][se] = w1.z;  sm.Bs[sk + 7][se] = w1.w;
    sm.Bs[sk + 8][se] = w2.x;  sm.Bs[sk + 9][se] = w2.y;  sm.Bs[sk + 10][se] = w2.z; sm.Bs[sk + 11][se] = w2.w;
    sm.Bs[sk + 12][se] = w3.x; sm.Bs[sk + 13][se] = w3.y; sm.Bs[sk + 14][se] = w3.z; sm.Bs[sk + 15][se] = w3.w;
    __syncthreads();
    #pragma unroll
    for (int kk = 0; kk < 32; kk++) {
      float4 a = *(const float4*)&sm.As[kk][r0];
      float4 b0 = *(const float4*)&sm.Bs[kk][ca];
      float4 b1 = *(const float4*)&sm.Bs[kk][cb];
      acc[0][0] += a.x * b0.x; acc[0][1] += a.x * b0.y; acc[0][2] += a.x * b0.z; acc[0][3] += a.x * b0.w;
      acc[0][4] += a.x * b1.x; acc[0][5] += a.x * b1.y; acc[0][6] += a.x * b1.z; acc[0][7] += a.x * b1.w;
      acc[1][0] += a.y * b0.x; acc[1][1] += a.y * b0.y; acc[1][2] += a.y * b0.z; acc[1][3] += a.y * b0.w;
      acc[1][4] += a.y * b1.x; acc[1][5] += a.y * b1.y; acc[1][6] += a.y * b1.z; acc[1][7] += a.y * b1.w;
      acc[2][0] += a.z * b0.x; acc[2][1] += a.z * b0.y; acc[2][2] += a.z * b0.z; acc[2][3] += a.z * b0.w;
      acc[2][4] += a.z * b1.x; acc[2][5] += a.z * b1.y; acc[2][6] += a.z * b1.z; acc[2][7] += a.z * b1.w;
      acc[3][0] += a.w * b0.x; acc[3][1] += a.w * b0.y; acc[3][2] += a.w * b0.z; acc[3][3] += a.w * b0.w;
      acc[3][4] += a.w * b1.x; acc[3][5] += a.w * b1.y; acc[3][6] += a.w * b1.z; acc[3][7] += a.w * b1.w;
    }
    __syncthreads();
  }
  #pragma unroll
  for (int i = 0; i < 4; i++) {
    int m = m0 + r0 + i;
    int src = (m < 4096) ? cei[m] : (sei[m - 4096] + 2048);
    float* dst = aggr + (size_t)src * 128;
    atomicAdd(dst + ca + 0, acc[i][0]);
    atomicAdd(dst + ca + 1, acc[i][1]);
    atomicAdd(dst + ca + 2, acc[i][2]);
    atomicAdd(dst + ca + 3, acc[i][3]);
    atomicAdd(dst + cb + 0, acc[i][4]);
    atomicAdd(dst + cb + 1, acc[i][5]);
    atomicAdd(dst + cb + 2, acc[i][6]);
    atomicAdd(dst + cb + 3, acc[i][7]);
  }
}

// ---------------------------------------------------------------- BM=16 GEMM body (K=128)
__device__ __forceinline__ void gemm16_body(G16Sm& sm,
    const float* __restrict__ A, const float* __restrict__ Bp,
    const float* __restrict__ biasp, float* __restrict__ Cp,
    int row0, int ldb, int ldc)
{
  const int tid = threadIdx.x;
  const int tm = tid >> 5, tn = tid & 31;
  const int t0 = 2 * tm, e0 = 4 * tn;
  const int ar = tid >> 4, ak = (tid & 15) * 2;
  const int bk = tid >> 3, be = (tid & 7) * 16;
  float acc[2][4] = {};
  for (int k0 = 0; k0 < 128; k0 += 32) {
    float2 av = *(const float2*)(A + (size_t)(row0 + ar) * 128 + k0 + ak);
    sm.Sa[ak][ar] = av.x; sm.Sa[ak + 1][ar] = av.y;
    const float* bp = Bp + (size_t)(k0 + bk) * ldb + be;
    float4 b0v = *(const float4*)(bp + 0);
    float4 b1v = *(const float4*)(bp + 4);
    float4 b2v = *(const float4*)(bp + 8);
    float4 b3v = *(const float4*)(bp + 12);
    sm.Bs[bk][be + 0] = b0v.x;  sm.Bs[bk][be + 1] = b0v.y;  sm.Bs[bk][be + 2] = b0v.z;  sm.Bs[bk][be + 3] = b0v.w;
    sm.Bs[bk][be + 4] = b1v.x;  sm.Bs[bk][be + 5] = b1v.y;  sm.Bs[bk][be + 6] = b1v.z;  sm.Bs[bk][be + 7] = b1v.w;
    sm.Bs[bk][be + 8] = b2v.x;  sm.Bs[bk][be + 9] = b2v.y;  sm.Bs[bk][be + 10] = b2v.z; sm.Bs[bk][be + 11] = b2v.w;
    sm.Bs[bk][be + 12] = b3v.x; sm.Bs[bk][be + 13] = b3v.y; sm.Bs[bk][be + 14] = b3v.z; sm.Bs[bk][be + 15] = b3v.w;
    __syncthreads();
    #pragma unroll
    for (int kk = 0; kk < 32; kk++) {
      float2 a = *(const float2*)&sm.Sa[kk][t0];
      float4 b = *(const float4*)&sm.Bs[kk][e0];
      acc[0][0] += a.x * b.x; acc[0][1] += a.x * b.y; acc[0][2] += a.x * b.z; acc[0][3] += a.x * b.w;
      acc[1][0] += a.y * b.x; acc[1][1] += a.y * b.y; acc[1][2] += a.y * b.z; acc[1][3] += a.y * b.w;
    }
    __syncthreads();
  }
  #pragma unroll
  for (int i = 0; i < 2; i++) {
    float* cp = Cp + (size_t)(row0 + t0 + i) * ldc + e0;
    #pragma unroll
    for (int j = 0; j < 4; j++) cp[j] = acc[i][j] + biasp[e0 + j];
  }
}

// ---------------------------------------------------------------- graph attention body (N=32, GD=16)
__device__ __forceinline__ void gattn_body(GAttnSm& sm, int g, int h,
    const float* __restrict__ q, const float* __restrict__ k,
    const float* __restrict__ v, const float* __restrict__ dist, float* __restrict__ o)
{
  const int tid = threadIdx.x;
  {
    int idx = tid * 2;
    int i = idx >> 4, d = idx & 15;
    size_t base = ((size_t)(g * 32 + i)) * 128 + h * 16 + d;
    sm.qs[i][d] = q[base];  sm.qs[i][d + 1] = q[base + 1];
    sm.ksh[i][d] = k[base]; sm.ksh[i][d + 1] = k[base + 1];
    sm.vsh[i][d] = v[base]; sm.vsh[i][d + 1] = v[base + 1];
  }
  __syncthreads();
  {
    int i = tid >> 3, j0 = (tid & 7) * 4;
    for (int j = j0; j < j0 + 4; j++) {
      float a = 0;
      #pragma unroll
      for (int d = 0; d < 16; d++) a += sm.qs[i][d] * sm.ksh[j][d];
      a = a * 0.25f + dist[(size_t)g * 1024 + i * 32 + j];
      sm.ss[i][j] = fminf(fmaxf(a, -10.0f), 10.0f);
    }
  }
  __syncthreads();
  if (tid < 32) {
    float m = -1e30f;
    for (int j = 0; j < 32; j++) m = fmaxf(m, sm.ss[tid][j]);
    float s = 0;
    for (int j = 0; j < 32; j++) { float ex = expf(sm.ss[tid][j] - m); sm.ss[tid][j] = ex; s += ex; }
    sm.rs[tid] = 1.0f / s;
  }
  __syncthreads();
  {
    int idx = tid * 2;
    int i = idx >> 4, d = idx & 15;
    float a0 = 0, a1 = 0;
    for (int j = 0; j < 32; j++) { float wj = sm.ss[i][j]; a0 += wj * sm.vsh[j][d]; a1 += wj * sm.vsh[j][d + 1]; }
    float r = sm.rs[i];
    size_t base = ((size_t)(g * 32 + i)) * 128 + h * 16 + d;
    o[base] = a0 * r; o[base + 1] = a1 * r;
  }
}

// ---------------------------------------------------------------- seq attention body (L=128, SD=32), K/V tiled
// Bit-identical math to the full-LDS version: same dot order, same stride-8 partial sums, same j-ascending V accum.
__device__ __forceinline__ void sattn_body(SAttnSm& sm, int b, int h, int qt,
    const float* __restrict__ qkv, float* __restrict__ o)
{
  const int tid = threadIdx.x;
  {
    int i = tid >> 3, d0 = (tid & 7) * 4;
    const float* qp = qkv + ((size_t)(b * 128 + qt * 32 + i)) * 384 + h * 32 + d0;
    sm.qs2[i][d0 + 0] = qp[0]; sm.qs2[i][d0 + 1] = qp[1];
    sm.qs2[i][d0 + 2] = qp[2]; sm.qs2[i][d0 + 3] = qp[3];
  }
  const int i = tid >> 3, sub = tid & 7;
  // --- K tiles: scores into ss2 ---
  for (int jt = 0; jt < 4; jt++) {
    {
      int r = tid >> 3, dd = (tid & 7) * 4;
      const float* kp = qkv + ((size_t)(b * 128 + jt * 32 + r)) * 384 + 128 + h * 32 + dd;
      float4 kv4 = *(const float4*)kp;
      sm.kv[r][dd + 0] = kv4.x; sm.kv[r][dd + 1] = kv4.y;
      sm.kv[r][dd + 2] = kv4.z; sm.kv[r][dd + 3] = kv4.w;
    }
    __syncthreads();
    {
      int j0 = jt * 32 + sub * 4;
      for (int j = j0; j < j0 + 4; j++) {
        int jr = j - jt * 32;
        float a = 0;
        #pragma unroll
        for (int d = 0; d < 32; d++) a += sm.qs2[i][d] * sm.kv[jr][d];
        sm.ss2[i][j] = a * 0.17677669529663687f;   // 1/sqrt(32)
      }
    }
    __syncthreads();
  }
  // --- softmax stats (identical structure) ---
  float m = -1e30f;
  for (int j = sub; j < 128; j += 8) m = fmaxf(m, sm.ss2[i][j]);
  sm.red[i][sub] = m;
  __syncthreads();
  float mm = sm.red[i][0];
  #pragma unroll
  for (int t = 1; t < 8; t++) mm = fmaxf(mm, sm.red[i][t]);
  float ps = 0;
  for (int j = sub; j < 128; j += 8) { float ex = expf(sm.ss2[i][j] - mm); sm.ss2[i][j] = ex; ps += ex; }
  sm.red2[i][sub] = ps;
  __syncthreads();
  float s = 0;
  #pragma unroll
  for (int t = 0; t < 8; t++) s += sm.red2[i][t];
  float rinv = 1.0f / s;
  // --- V tiles: accumulate in ascending j ---
  float a0 = 0, a1 = 0, a2 = 0, a3 = 0;
  const int d0 = sub * 4;
  for (int jt = 0; jt < 4; jt++) {
    __syncthreads();
    {
      int r = tid >> 3, dd = (tid & 7) * 4;
      const float* vp = qkv + ((size_t)(b * 128 + jt * 32 + r)) * 384 + 256 + h * 32 + dd;
      float4 vv = *(const float4*)vp;
      sm.kv[r][dd + 0] = vv.x; sm.kv[r][dd + 1] = vv.y;
      sm.kv[r][dd + 2] = vv.z; sm.kv[r][dd + 3] = vv.w;
    }
    __syncthreads();
    for (int jr = 0; jr < 32; jr++) {
      float wj = sm.ss2[i][jt * 32 + jr];
      a0 += wj * sm.kv[jr][d0 + 0]; a1 += wj * sm.kv[jr][d0 + 1];
      a2 += wj * sm.kv[jr][d0 + 2]; a3 += wj * sm.kv[jr][d0 + 3];
    }
  }
  float* op = o + ((size_t)(b * 128 + qt * 32 + i)) * 128 + h * 32 + d0;
  op[0] = a0 * rinv; op[1] = a1 * rinv; op[2] = a2 * rinv; op[3] = a3 * rinv;
}

// ---------------------------------------------------------------- layer tail body (O-proj+LN, FFN, +res LN)
__device__ __forceinline__ void tail_body(TailSm& sm, int row0, const float* __restrict__ A,
    const float* __restrict__ Wo, const float* __restrict__ bo, const float* __restrict__ res,
    const float* __restrict__ g1, const float* __restrict__ b1n,
    const float* __restrict__ W1, const float* __restrict__ b1f,
    const float* __restrict__ W2, const float* __restrict__ b2f,
    const float* __restrict__ g2, const float* __restrict__ b2n,
    float* __restrict__ Out)
{
  float (*BsA)[136] = (float(*)[136])sm.sbuf;
  float (*Bs1)[260] = (float(*)[260])sm.sbuf;
  float (*Bs2)[136] = (float(*)[136])sm.sbuf;
  const int tid = threadIdx.x;
  // ---- stage A: x1 = LN(A@Wo + bo + res) ----
  {
    const int tm = tid >> 5, tn = tid & 31;
    const int t0 = 2 * tm, e0 = 4 * tn;
    const int ar = tid >> 4, ak = (tid & 15) * 2;
    const int bk = tid >> 3, be = (tid & 7) * 16;
    float acc[2][4] = {};
    for (int k0 = 0; k0 < 128; k0 += 32) {
      float2 av = *(const float2*)(A + (size_t)(row0 + ar) * 128 + k0 + ak);
      sm.Sa[ak][ar] = av.x; sm.Sa[ak + 1][ar] = av.y;
      const float* bp = Wo + (size_t)(k0 + bk) * 128 + be;
      float4 b0v = *(const float4*)(bp + 0);
      float4 b1v = *(const float4*)(bp + 4);
      float4 b2v = *(const float4*)(bp + 8);
      float4 b3v = *(const float4*)(bp + 12);
      BsA[bk][be + 0] = b0v.x;  BsA[bk][be + 1] = b0v.y;  BsA[bk][be + 2] = b0v.z;  BsA[bk][be + 3] = b0v.w;
      BsA[bk][be + 4] = b1v.x;  BsA[bk][be + 5] = b1v.y;  BsA[bk][be + 6] = b1v.z;  BsA[bk][be + 7] = b1v.w;
      BsA[bk][be + 8] = b2v.x;  BsA[bk][be + 9] = b2v.y;  BsA[bk][be + 10] = b2v.z; BsA[bk][be + 11] = b2v.w;
      BsA[bk][be + 12] = b3v.x; BsA[bk][be + 13] = b3v.y; BsA[bk][be + 14] = b3v.z; BsA[bk][be + 15] = b3v.w;
      __syncthreads();
      #pragma unroll
      for (int kk = 0; kk < 32; kk++) {
        float2 a = *(const float2*)&sm.Sa[kk][t0];
        float4 b = *(const float4*)&BsA[kk][e0];
        acc[0][0] += a.x * b.x; acc[0][1] += a.x * b.y; acc[0][2] += a.x * b.z; acc[0][3] += a.x * b.w;
        acc[1][0] += a.y * b.x; acc[1][1] += a.y * b.y; acc[1][2] += a.y * b.z; acc[1][3] += a.y * b.w;
      }
      __syncthreads();
    }
    #pragma unroll
    for (int i = 0; i < 2; i++) {
      int r = row0 + t0 + i;
      float v0 = acc[i][0] + bo[e0 + 0] + res[(size_t)r * 128 + e0 + 0];
      float v1 = acc[i][1] + bo[e0 + 1] + res[(size_t)r * 128 + e0 + 1];
      float v2 = acc[i][2] + bo[e0 + 2] + res[(size_t)r * 128 + e0 + 2];
      float v3 = acc[i][3] + bo[e0 + 3] + res[(size_t)r * 128 + e0 + 3];
      float s = v0 + v1 + v2 + v3;
      #pragma unroll
      for (int o = 1; o < 32; o <<= 1) s += __shfl_xor(s, o);
      float mean = s * (1.0f / 128.0f);
      float d0 = v0 - mean, d1 = v1 - mean, d2 = v2 - mean, d3 = v3 - mean;
      float sq = d0 * d0 + d1 * d1 + d2 * d2 + d3 * d3;
      #pragma unroll
      for (int o = 1; o < 32; o <<= 1) sq += __shfl_xor(sq, o);
      float rstd = 1.0f / sqrtf(sq * (1.0f / 128.0f) + 1e-5f);
      sm.x1[t0 + i][e0 + 0] = d0 * rstd * g1[e0 + 0] + b1n[e0 + 0];
      sm.x1[t0 + i][e0 + 1] = d1 * rstd * g1[e0 + 1] + b1n[e0 + 1];
      sm.x1[t0 + i][e0 + 2] = d2 * rstd * g1[e0 + 2] + b1n[e0 + 2];
      sm.x1[t0 + i][e0 + 3] = d3 * rstd * g1[e0 + 3] + b1n[e0 + 3];
    }
  }
  __syncthreads();
  // ---- stage B: hid = relu(x1 @ W1 + b1f), 16x256 ----
  {
    const int tm = tid >> 6, tn = tid & 63;
    const int t0 = 4 * tm, e0 = 4 * tn;
    const int ar = tid >> 4, ak = tid & 15;
    const int bk = tid >> 4, be = (tid & 15) * 16;
    float acc[4][4] = {};
    for (int k0 = 0; k0 < 128; k0 += 16) {
      sm.Sa[ak][ar] = sm.x1[ar][k0 + ak];
      const float* bp = W1 + (size_t)(k0 + bk) * 256 + be;
      float4 b0v = *(const float4*)(bp + 0);
      float4 b1v = *(const float4*)(bp + 4);
      float4 b2v = *(const float4*)(bp + 8);
      float4 b3v = *(const float4*)(bp + 12);
      Bs1[bk][be + 0] = b0v.x;  Bs1[bk][be + 1] = b0v.y;  Bs1[bk][be + 2] = b0v.z;  Bs1[bk][be + 3] = b0v.w;
      Bs1[bk][be + 4] = b1v.x;  Bs1[bk][be + 5] = b1v.y;  Bs1[bk][be + 6] = b1v.z;  Bs1[bk][be + 7] = b1v.w;
      Bs1[bk][be + 8] = b2v.x;  Bs1[bk][be + 9] = b2v.y;  Bs1[bk][be + 10] = b2v.z; Bs1[bk][be + 11] = b2v.w;
      Bs1[bk][be + 12] = b3v.x; Bs1[bk][be + 13] = b3v.y; Bs1[bk][be + 14] = b3v.z; Bs1[bk][be + 15] = b3v.w;
      __syncthreads();
      #pragma unroll
      for (int kk = 0; kk < 16; kk++) {
        float4 a = *(const float4*)&sm.Sa[kk][t0];
        float4 b = *(const float4*)&Bs1[kk][e0];
        acc[0][0] += a.x * b.x; acc[0][1] += a.x * b.y; acc[0][2] += a.x * b.z; acc[0][3] += a.x * b.w;
        acc[1][0] += a.y * b.x; acc[1][1] += a.y * b.y; acc[1][2] += a.y * b.z; acc[1][3] += a.y * b.w;
        acc[2][0] += a.z * b.x; acc[2][1] += a.z * b.y; acc[2][2] += a.z * b.z; acc[2][3] += a.z * b.w;
        acc[3][0] += a.w * b.x; acc[3][1] += a.w * b.y; acc[3][2] += a.w * b.z; acc[3][3] += a.w * b.w;
      }
      __syncthreads();
    }
    #pragma unroll
    for (int i = 0; i < 4; i++) {
      float4 hv;
      hv.x = fmaxf(acc[i][0] + b1f[e0 + 0], 0.0f);
      hv.y = fmaxf(acc[i][1] + b1f[e0 + 1], 0.0f);
      hv.z = fmaxf(acc[i][2] + b1f[e0 + 2], 0.0f);
      hv.w = fmaxf(acc[i][3] + b1f[e0 + 3], 0.0f);
      *(float4*)&sm.hid[t0 + i][e0] = hv;
    }
  }
  __syncthreads();
  // ---- stage C: Out = LN(hid@W2 + b2f + x1) ----
  {
    const int tm = tid >> 5, tn = tid & 31;
    const int t0 = 2 * tm, e0 = 4 * tn;
    const int bk = tid >> 3, be = (tid & 7) * 16;
    float acc[2][4] = {};
    for (int k0 = 0; k0 < 256; k0 += 32) {
      const float* bp = W2 + (size_t)(k0 + bk) * 128 + be;
      float4 b0v = *(const float4*)(bp + 0);
      float4 b1v = *(const float4*)(bp + 4);
      float4 b2v = *(const float4*)(bp + 8);
      float4 b3v = *(const float4*)(bp + 12);
      Bs2[bk][be + 0] = b0v.x;  Bs2[bk][be + 1] = b0v.y;  Bs2[bk][be + 2] = b0v.z;  Bs2[bk][be + 3] = b0v.w;
      Bs2[bk][be + 4] = b1v.x;  Bs2[bk][be + 5] = b1v.y;  Bs2[bk][be + 6] = b1v.z;  Bs2[bk][be + 7] = b1v.w;
      Bs2[bk][be + 8] = b2v.x;  Bs2[bk][be + 9] = b2v.y;  Bs2[bk][be + 10] = b2v.z; Bs2[bk][be + 11] = b2v.w;
      Bs2[bk][be + 12] = b3v.x; Bs2[bk][be + 13] = b3v.y; Bs2[bk][be + 14] = b3v.z; Bs2[bk][be + 15] = b3v.w;
      __syncthreads();
      #pragma unroll
      for (int kk = 0; kk < 32; kk++) {
        float a0 = sm.hid[t0 + 0][k0 + kk];
        float a1 = sm.hid[t0 + 1][k0 + kk];
        float4 b = *(const float4*)&Bs2[kk][e0];
        acc[0][0] += a0 * b.x; acc[0][1] += a0 * b.y; acc[0][2] += a0 * b.z; acc[0][3] += a0 * b.w;
        acc[1][0] += a1 * b.x; acc[1][1] += a1 * b.y; acc[1][2] += a1 * b.z; acc[1][3] += a1 * b.w;
      }
      __syncthreads();
    }
    #pragma unroll
    for (int i = 0; i < 2; i++) {
      int r = row0 + t0 + i;
      float v0 = acc[i][0] + b2f[e0 + 0] + sm.x1[t0 + i][e0 + 0];
      float v1 = acc[i][1] + b2f[e0 + 1] + sm.x1[t0 + i][e0 + 1];
      float v2 = acc[i][2] + b2f[e0 + 2] + sm.x1[t0 + i][e0 + 2];
      float v3 = acc[i][3] + b2f[e0 + 3] + sm.x1[t0 + i][e0 + 3];
      float s = v0 + v1 + v2 + v3;
      #pragma unroll
      for (int o = 1; o < 32; o <<= 1) s += __shfl_xor(s, o);
      float mean = s * (1.0f / 128.0f);
      float d0 = v0 - mean, d1 = v1 - mean, d2 = v2 - mean, d3 = v3 - mean;
      float sq = d0 * d0 + d1 * d1 + d2 * d2 + d3 * d3;
      #pragma unroll
      for (int o = 1; o < 32; o <<= 1) sq += __shfl_xor(sq, o);
      float rstd = 1.0f / sqrtf(sq * (1.0f / 128.0f) + 1e-5f);
      float* cp = Out + (size_t)r * 128 + e0;
      cp[0] = d0 * rstd * g2[e0 + 0] + b2n[e0 + 0];
      cp[1] = d1 * rstd * g2[e0 + 1] + b2n[e0 + 1];
      cp[2] = d2 * rstd * g2[e0 + 2] + b2n[e0 + 2];
      cp[3] = d3 * rstd * g2[e0 + 3] + b2n[e0 + 3];
    }
  }
}

// ---------------------------------------------------------------- 2-row LayerNorm body (256 threads)
__device__ __forceinline__ void ln2_body(float* sred4, int r0,
    const float* __restrict__ x, const float* __restrict__ res,
    const float* __restrict__ g, const float* __restrict__ b, float* __restrict__ out)
{
  const int tid = threadIdx.x;
  const int e = tid & 127, half = tid >> 7;
  size_t idx = (size_t)(r0 + half) * 128 + e;
  float v = x[idx] + res[idx];
  float s = v;
  #pragma unroll
  for (int o = 1; o < 64; o <<= 1) s += __shfl_xor(s, o);
  if ((tid & 63) == 0) sred4[tid >> 6] = s;
  __syncthreads();
  float mean = (sred4[half * 2] + sred4[half * 2 + 1]) * (1.0f / 128.0f);
  __syncthreads();
  float d = v - mean;
  float s2 = d * d;
  #pragma unroll
  for (int o = 1; o < 64; o <<= 1) s2 += __shfl_xor(s2, o);
  if ((tid & 63) == 0) sred4[tid >> 6] = s2;
  __syncthreads();
  float var = (sred4[half * 2] + sred4[half * 2 + 1]) * (1.0f / 128.0f);
  out[idx] = (d / sqrtf(var + 1e-5f)) * g[e] + b[e];
}

// ---------------------------------------------------------------- K1: edge (1120) + seq qkv l0 (384)
__global__ __launch_bounds__(256) void edge_sqkv_k(
    int gCount,
    const float* cea, const float* sea, const int* cei, const int* sei,
    const float* h, const float* elw, const float* elb, float* aggr,
    const float* sxs, const float* sw, const float* sb, float* sout)
{
  __shared__ K1U u;
  int bx = blockIdx.x;
  if (bx < gCount) {
    edge_body(u.e, bx, cea, sea, cei, sei, h, elw, elb, aggr);
  } else {
    int i = bx - gCount;
    int z = i >> 7, rt = i & 127;
    gemm16_body(u.g, sxs, sw + z * 128, sb + z * 128, sout + z * 128, rt * 16, 384, 384);
  }
}

// ---------------------------------------------------------------- K2: ln (1280, 2 rows each) + seq attn l0 (256)
__global__ __launch_bounds__(256) void ln_sattn_k(
    int gCount,
    const float* x, const float* res, const float* g, const float* b, float* out,
    const float* qkv, float* so)
{
  __shared__ K2U u;
  int bx = blockIdx.x;
  if (bx < gCount) {
    ln2_body(u.sred4, bx * 2, x, res, g, b, out);
  } else {
    int i = bx - gCount;
    sattn_body(u.s, i >> 4, (i >> 2) & 3, i & 3, qkv, so);
  }
}

// ---------------------------------------------------------------- K3: graph qkv (480) + seq tail (128)
__global__ __launch_bounds__(256) void gqkv_stail_k(
    int gCount,
    const float* ghb, const float* gqw, const float* gkw, const float* gvw,
    const float* gqb, const float* gkb, const float* gvb, float* gout,
    const float* sA, const float* sWo, const float* sbo, const float* sres,
    const float* sg1, const float* sb1, const float* sW1, const float* sbf1,
    const float* sW2, const float* sbf2, const float* sg2, const float* sb2, float* sOut)
{
  __shared__ K3U u;
  int bx = blockIdx.x;
  if (bx < gCount) {
    int z = bx / 160, rt = bx % 160;
    const float* B = (z == 0) ? gqw : (z == 1) ? gkw : gvw;
    const float* bias = (z == 0) ? gqb : (z == 1) ? gkb : gvb;
    gemm16_body(u.g, ghb, B, bias, gout + (size_t)z * 327680, rt * 16, 128, 128);
  } else {
    tail_body(u.t, (bx - gCount) * 16, sA, sWo, sbo, sres, sg1, sb1, sW1, sbf1, sW2, sbf2, sg2, sb2, sOut);
  }
}

// ---------------------------------------------------------------- K4: graph attn (640) + seq qkv l+1 (384)
__global__ __launch_bounds__(256) void gattn_sqkv_k(
    int gCount,
    const float* q, const float* k, const float* v, const float* dist, float* go,
    const float* sxs, const float* sw, const float* sb, float* sout)
{
  __shared__ K4U u;
  int bx = blockIdx.x;
  if (bx < gCount) {
    gattn_body(u.a, bx >> 3, bx & 7, q, k, v, dist, go);
  } else {
    int i = bx - gCount;
    int z = i >> 7, rt = i & 127;
    gemm16_body(u.g, sxs, sw + z * 128, sb + z * 128, sout + z * 128, rt * 16, 384, 384);
  }
}

// ---------------------------------------------------------------- K5: graph tail (160) + seq attn l+1 (256)
__global__ __launch_bounds__(256) void gtail_sattn_k(
    int gCount,
    const float* gA, const float* gWo, const float* gbo, const float* gres,
    const float* gg1, const float* gb1, const float* gW1, const float* gbf1,
    const float* gW2, const float* gbf2, const float* gg2, const float* gb2, float* gOut,
    const float* qkv, float* so)
{
  __shared__ K5U u;
  int bx = blockIdx.x;
  if (bx < gCount) {
    tail_body(u.t, bx * 16, gA, gWo, gbo, gres, gg1, gb1, gW1, gbf1, gW2, gbf2, gg2, gb2, gOut);
  } else {
    int i = bx - gCount;
    sattn_body(u.s, i >> 4, (i >> 2) & 3, i & 3, qkv, so);
  }
}

// ---------------------------------------------------------------- pool + smean + fusion + cross-modal + head
__global__ __launch_bounds__(128) void head_k(
    const float* __restrict__ hb, const float* __restrict__ xs, const float* __restrict__ gfeat,
    const float* fg1w, const float* fg1b, const float* fg2w, const float* fg2b,
    const float* g2s_vw, const float* g2s_vb, const float* g2s_ow, const float* g2s_ob,
    const float* n1g, const float* n1b,
    const float* s2g_vw, const float* s2g_vb, const float* s2g_ow, const float* s2g_ob,
    const float* n2g, const float* n2b,
    const float* r1w, const float* r1b, const float* r2w, const float* r2b,
    float* __restrict__ out)
{
  __shared__ float T[128], S[128], G[128], Sm[128], t1[128], t2[128], gh[64], sred[2];
  int mol = blockIdx.x, e = threadIdx.x;
  {
    float cs = 0;
    for (int c = 0; c < 4; c++) {
      int g = mol * 4 + c;
      float s = 0;
      for (int i = 0; i < 32; i++) s += hb[((size_t)(g * 32 + i)) * 128 + e];
      cs += s * (1.0f / 32.0f);
    }
    cs *= 0.25f;
    float s2 = 0;
    int g = 64 + mol;
    for (int i = 0; i < 32; i++) s2 += hb[((size_t)(g * 32 + i)) * 128 + e];
    T[e] = cs + s2 * (1.0f / 32.0f);
    float ss = 0;
    for (int l = 0; l < 128; l++) ss += xs[((size_t)(mol * 128 + l)) * 128 + e];
    S[e] = ss * (1.0f / 128.0f);
  }
  __syncthreads();
  if (e < 64) {
    float a = fg1b[e];
    for (int f = 0; f < 128; f++) a += T[f] * fg1w[f * 64 + e];
    for (int f = 0; f < 128; f++) a += S[f] * fg1w[(128 + f) * 64 + e];
    gh[e] = fmaxf(a, 0.0f);
  }
  __syncthreads();
  {
    float a = fg2b[e];
    for (int j = 0; j < 64; j++) a += gh[j] * fg2w[j * 128 + e];
    float gate = 1.0f / (1.0f + expf(-a));
    float fu = gate * T[e] + (1.0f - gate) * S[e];
    G[e] = fu; Sm[e] = fu;
  }
  __syncthreads();
  for (int l = 0; l < 2; l++) {
    const float* vw = g2s_vw + (size_t)l * 16384; const float* vb = g2s_vb + l * 128;
    const float* ow = g2s_ow + (size_t)l * 16384; const float* ob = g2s_ob + l * 128;
    float a = vb[e];
    for (int f = 0; f < 128; f++) a += Sm[f] * vw[f * 128 + e];
    t1[e] = a;
    __syncthreads();
    a = ob[e];
    for (int f = 0; f < 128; f++) a += t1[f] * ow[f * 128 + e];
    float v = G[e] + a;
    {
      float s = v;
      #pragma unroll
      for (int o = 1; o < 64; o <<= 1) s += __shfl_xor(s, o);
      if ((e & 63) == 0) sred[e >> 6] = s;
      __syncthreads();
      float mean = (sred[0] + sred[1]) * (1.0f / 128.0f);
      __syncthreads();
      float d = v - mean;
      float s2 = d * d;
      #pragma unroll
      for (int o = 1; o < 64; o <<= 1) s2 += __shfl_xor(s2, o);
      if ((e & 63) == 0) sred[e >> 6] = s2;
      __syncthreads();
      float var = (sred[0] + sred[1]) * (1.0f / 128.0f);
      __syncthreads();
      G[e] = (d / sqrtf(var + 1e-5f)) * n1g[l * 128 + e] + n1b[l * 128 + e];
    }
    __syncthreads();
    const float* vw2 = s2g_vw + (size_t)l * 16384; const float* vb2 = s2g_vb + l * 128;
    const float* ow2 = s2g_ow + (size_t)l * 16384; const float* ob2 = s2g_ob + l * 128;
    a = vb2[e];
    for (int f = 0; f < 128; f++) a += G[f] * vw2[f * 128 + e];
    t1[e] = a;
    __syncthreads();
    a = ob2[e];
    for (int f = 0; f < 128; f++) a += t1[f] * ow2[f * 128 + e];
    float v2x = Sm[e] + a;
    {
      float s = v2x;
      #pragma unroll
      for (int o = 1; o < 64; o <<= 1) s += __shfl_xor(s, o);
      if ((e & 63) == 0) sred[e >> 6] = s;
      __syncthreads();
      float mean = (sred[0] + sred[1]) * (1.0f / 128.0f);
      __syncthreads();
      float d = v2x - mean;
      float s2 = d * d;
      #pragma unroll
      for (int o = 1; o < 64; o <<= 1) s2 += __shfl_xor(s2, o);
      if ((e & 63) == 0) sred[e >> 6] = s2;
      __syncthreads();
      float var = (sred[0] + sred[1]) * (1.0f / 128.0f);
      __syncthreads();
      Sm[e] = (d / sqrtf(var + 1e-5f)) * n2g[l * 128 + e] + n2b[l * 128 + e];
    }
    __syncthreads();
  }
  t2[e] = 0.5f * (G[e] + Sm[e]);
  __syncthreads();
  float a = r1b[e];
  for (int f = 0; f < 128; f++) a += t2[f] * r1w[f * 128 + e];
  for (int f = 0; f < 3; f++) a += gfeat[mol * 3 + f] * r1w[(128 + f) * 128 + e];
  a = fmaxf(a, 0.0f);
  float p = a * r2w[e];
  #pragma unroll
  for (int o = 1; o < 64; o <<= 1) p += __shfl_xor(p, o);
  if ((e & 63) == 0) sred[e >> 6] = p;
  __syncthreads();
  if (e == 0) out[mol] = sred[0] + sred[1] + r2b[0];
}

// ================================================================ host
extern "C" void kernel_launch(void* const* d_in, const int* in_sizes, int n_in,
                              void* d_out, int out_size, void* d_ws, size_t ws_size,
                              hipStream_t stream)
{
  (void)n_in; (void)out_size; (void)ws_size;
  const bool dict = (in_sizes[1] == 8192);
  auto IN = [&](int di, int si) { return d_in[dict ? di : si]; };

  const float* conf_x   = (const float*)IN(0, 0);
  const int*   conf_ei  = (const int*)  IN(1, 63);
  const float* conf_ea  = (const float*)IN(2, 1);
  const float* conf_pos = (const float*)IN(3, 2);
  const float* scaf_x   = (const float*)IN(4, 3);
  const int*   scaf_ei  = (const int*)  IN(5, 64);
  const float* scaf_ea  = (const float*)IN(6, 4);
  const float* scaf_pos = (const float*)IN(7, 5);
  const int*   tokens   = (const int*)  IN(8, 65);
  const float* gfeat    = (const float*)IN(9, 6);
  const float* gproj_w  = (const float*)IN(11, 7);
  const float* gproj_b  = (const float*)IN(12, 8);
  const float* elin_w   = (const float*)IN(13, 9);
  const float* elin_b   = (const float*)IN(14, 10);
  const float* eln_g    = (const float*)IN(15, 11);
  const float* eln_b    = (const float*)IN(16, 12);
  const float* gt_qw    = (const float*)IN(17, 13);
  const float* gt_qb    = (const float*)IN(18, 14);
  const float* gt_kw    = (const float*)IN(19, 15);
  const float* gt_kb    = (const float*)IN(20, 16);
  const float* gt_vw    = (const float*)IN(21, 17);
  const float* gt_vb    = (const float*)IN(22, 18);
  const float* gt_ow    = (const float*)IN(23, 19);
  const float* gt_ob    = (const float*)IN(24, 20);
  const float* gt_ln1g  = (const float*)IN(25, 21);
  const float* gt_ln1b  = (const float*)IN(26, 22);
  const float* gt_f1w   = (const float*)IN(27, 23);
  const float* gt_f1b   = (const float*)IN(28, 24);
  const float* gt_f2w   = (const float*)IN(29, 25);
  const float* gt_f2b   = (const float*)IN(30, 26);
  const float* gt_ln2g  = (const float*)IN(31, 27);
  const float* gt_ln2b  = (const float*)IN(32, 28);
  const float* tok_emb  = (const float*)IN(33, 29);
  const float* pos_emb  = (const float*)IN(34, 30);
  const float* se_inw   = (const float*)IN(35, 31);
  const float* se_inb   = (const float*)IN(36, 32);
  const float* se_ow    = (const float*)IN(37, 33);
  const float* se_ob    = (const float*)IN(38, 34);
  const float* se_ln1g  = (const float*)IN(39, 35);
  const float* se_ln1b  = (const float*)IN(40, 36);
  const float* se_f1w   = (const float*)IN(41, 37);
  const float* se_f1b   = (const float*)IN(42, 38);
  const float* se_f2w   = (const float*)IN(43, 39);
  const float* se_f2b   = (const float*)IN(44, 40);
  const float* se_ln2g  = (const float*)IN(45, 41);
  const float* se_ln2b  = (const float*)IN(46, 42);
  const float* fg1_w    = (const float*)IN(47, 43);
  const float* fg1_b    = (const float*)IN(48, 44);
  const float* fg2_w    = (const float*)IN(49, 45);
  const float* fg2_b    = (const float*)IN(50, 46);
  const float* cm_g2s_vw = (const float*)IN(51, 47);
  const float* cm_g2s_vb = (const float*)IN(52, 48);
  const float* cm_g2s_ow = (const float*)IN(53, 49);
  const float* cm_g2s_ob = (const float*)IN(54, 50);
  const float* cm_s2g_vw = (const float*)IN(55, 53);
  const float* cm_s2g_vb = (const float*)IN(56, 54);
  const float* cm_s2g_ow = (const float*)IN(57, 55);
  const float* cm_s2g_ob = (const float*)IN(58, 56);
  const float* cm_n1g   = (const float*)IN(59, 51);
  const float* cm_n1b   = (const float*)IN(60, 52);
  const float* cm_n2g   = (const float*)IN(61, 57);
  const float* cm_n2b   = (const float*)IN(62, 58);
  const float* r1_w     = (const float*)IN(63, 59);
  const float* r1_b     = (const float*)IN(64, 60);
  const float* r2_w     = (const float*)IN(65, 61);
  const float* r2_b     = (const float*)IN(66, 62);
  float* out = (float*)d_out;

  // ---- workspace (fp32) ----
  float* w = (float*)d_ws;
  size_t off = 0;
  auto alloc = [&](size_t n) { float* p = w + off; off += n; return p; };
  float* h     = alloc(2560 * 128);
  float* aggr  = alloc(2560 * 128);
  float* hb    = alloc(2560 * 128);
  float* distb = alloc(80 * 1024);
  float* qb    = alloc(3 * 327680);     // graph q/k/v
  float* atto  = alloc(327680);
  float* xs2   = alloc(2048 * 128);
  float* qkv3  = alloc(2048 * 384);
  float* satto = alloc(2048 * 128);
  float* xsfin = alloc(2048 * 128);

  // D1: front (node_proj + zero aggr + dist + embed)
  front_k<<<2384, 256, 0, stream>>>(conf_x, scaf_x, gproj_w, gproj_b, h, aggr,
                                    conf_pos, scaf_pos, distb,
                                    tokens, tok_emb, pos_emb, xs2);
  // D2: edge GEMM (64-edge x 14 chunks = 1120) + seq qkv layer 0
  edge_sqkv_k<<<1504, 256, 0, stream>>>(1120,
      conf_ea, scaf_ea, conf_ei, scaf_ei, h, elin_w, elin_b, aggr,
      xs2, se_inw, se_inb, qkv3);
  // D3: edge LN + seq attn layer 0
  ln_sattn_k<<<1536, 256, 0, stream>>>(1280, aggr, h, eln_g, eln_b, hb, qkv3, satto);

  // D4..D12: shifted pipeline
  for (int l = 0; l < 3; l++) {
    gqkv_stail_k<<<608, 256, 0, stream>>>(480,
        hb, gt_qw + (size_t)l * 16384, gt_kw + (size_t)l * 16384, gt_vw + (size_t)l * 16384,
        gt_qb + l * 128, gt_kb + l * 128, gt_vb + l * 128, qb,
        satto, se_ow + (size_t)l * 16384, se_ob + l * 128, xs2,
        se_ln1g + l * 128, se_ln1b + l * 128,
        se_f1w + (size_t)l * 32768, se_f1b + l * 256,
        se_f2w + (size_t)l * 32768, se_f2b + l * 128,
        se_ln2g + l * 128, se_ln2b + l * 128, xs2);
    gattn_sqkv_k<<<1024, 256, 0, stream>>>(640,
        qb, qb + 327680, qb + 655360, distb, atto,
        xs2, se_inw + (size_t)(l + 1) * 49152, se_inb + (l + 1) * 384, qkv3);
    gtail_sattn_k<<<416, 256, 0, stream>>>(160,
        atto, gt_ow + (size_t)l * 16384, gt_ob + l * 128, hb,
        gt_ln1g + l * 128, gt_ln1b + l * 128,
        gt_f1w + (size_t)l * 32768, gt_f1b + l * 256,
        gt_f2w + (size_t)l * 32768, gt_f2b + l * 128,
        gt_ln2g + l * 128, gt_ln2b + l * 128, hb,
        qkv3, satto);
  }

  // D13: seq tail layer 3 -> xsfin (graph part empty)
  gqkv_stail_k<<<128, 256, 0, stream>>>(0,
      hb, gt_qw, gt_kw, gt_vw, gt_qb, gt_kb, gt_vb, qb,
      satto, se_ow + (size_t)3 * 16384, se_ob + 3 * 128, xs2,
      se_ln1g + 3 * 128, se_ln1b + 3 * 128,
      se_f1w + (size_t)3 * 32768, se_f1b + 3 * 256,
      se_f2w + (size_t)3 * 32768, se_f2b + 3 * 128,
      se_ln2g + 3 * 128, se_ln2b + 3 * 128, xsfin);

  // D14: head
  head_k<<<16, 128, 0, stream>>>(hb, xsfin, gfeat,
                                 fg1_w, fg1_b, fg2_w, fg2_b,
                                 cm_g2s_vw, cm_g2s_vb, cm_g2s_ow, cm_g2s_ob, cm_n1g, cm_n1b,
                                 cm_s2g_vw, cm_s2g_vb, cm_s2g_ow, cm_s2g_ob, cm_n2g, cm_n2b,
                                 r1_w, r1_b, r2_w, r2_b, out);
}

// Round 12
// 757.401 us; speedup vs baseline: 1.0084x; 1.0084x over previous
//
#include <hip/hip_runtime.h>
#include <hip/hip_bf16.h>

// E=128 GH=8 GD=16 GL=3 | SH=4 SD=32 SL=4 | N=32 GC=64 GS=16 DEG=64 BMOL=16
// M_conf=4096 M_scaf=1024 M_tot=5120. All float tensors fp32.
// r8 schedule (best: 663us) + streaming (barrier-free) GEMM bodies for the small-M tail.

// ---------------------------------------------------------------- LN helper (block of 128 threads)
__device__ __forceinline__ float blk_norm(float v, int e, float* sred)
{
  float s = v;
  #pragma unroll
  for (int o = 1; o < 64; o <<= 1) s += __shfl_xor(s, o);
  if ((e & 63) == 0) sred[e >> 6] = s;
  __syncthreads();
  float mean = (sred[0] + sred[1]) * (1.0f / 128.0f);
  __syncthreads();
  float d = v - mean;
  float s2 = d * d;
  #pragma unroll
  for (int o = 1; o < 64; o <<= 1) s2 += __shfl_xor(s2, o);
  if ((e & 63) == 0) sred[e >> 6] = s2;
  __syncthreads();
  float var = (sred[0] + sred[1]) * (1.0f / 128.0f);
  __syncthreads();
  return d / sqrtf(var + 1e-5f);
}

// ---------------------------------------------------------------- merged front-end (r8, proven)
__global__ __launch_bounds__(256) void front_k(
    const float* __restrict__ cx, const float* __restrict__ sx,
    const float* __restrict__ w, const float* __restrict__ b,
    float* __restrict__ h, float* __restrict__ aggr,
    const float* __restrict__ cpos, const float* __restrict__ spos, float* __restrict__ dist,
    const int* __restrict__ tokens, const float* __restrict__ tok_emb,
    const float* __restrict__ pos_emb, float* __restrict__ xs)
{
  __shared__ float sP[128];
  const int bx = blockIdx.x, tid = threadIdx.x;
  if (bx < 1280) {
    int r = bx * 2 + (tid >> 7), e = tid & 127;
    const float* x = (r < 2048) ? (cx + (size_t)r * 64) : (sx + (size_t)(r - 2048) * 64);
    float* xrow = sP + (tid >> 7) * 64;
    if (e < 64) xrow[e] = x[e];
    __syncthreads();
    float acc = b[e];
    for (int a = 0; a < 64; a++) acc += xrow[a] * w[a * 128 + e];
    h[(size_t)r * 128 + e] = acc;
    aggr[(size_t)r * 128 + e] = 0.0f;
  } else if (bx < 1360) {
    int g = bx - 1280;
    const float* p = (g < 64) ? (cpos + (size_t)g * 96) : (spos + (size_t)(g - 64) * 96);
    if (tid < 96) sP[tid] = p[tid];
    __syncthreads();
    #pragma unroll
    for (int jj = 0; jj < 4; jj++) {
      int idx = tid * 4 + jj;
      int i = idx >> 5, j = idx & 31;
      float dx = sP[i * 3 + 0] - sP[j * 3 + 0];
      float dy = sP[i * 3 + 1] - sP[j * 3 + 1];
      float dz = sP[i * 3 + 2] - sP[j * 3 + 2];
      float d2 = dx * dx + dy * dy + dz * dz;
      dist[(size_t)g * 1024 + idx] = (d2 > 0.0f) ? sqrtf(d2) : 0.0f;
    }
  } else {
    int r = (bx - 1360) * 2 + (tid >> 7), e = tid & 127;
    int tk = tokens[r];
    xs[(size_t)r * 128 + e] = tok_emb[(size_t)tk * 128 + e] + pos_emb[(size_t)(r & 127) * 128 + e];
  }
}

// ---------------------------------------------------------------- EdgeNetwork GEMM (r8 exact, 163us proven)
// 32-edge tile x 28-kt chunk (7 c's), hd in registers. grid (160, 7).
__global__ __launch_bounds__(256) void edge_gemm_k(
    const float* __restrict__ cea, const float* __restrict__ sea,
    const int* __restrict__ cei, const int* __restrict__ sei,
    const float* __restrict__ h,
    const float* __restrict__ elw, const float* __restrict__ elb,
    float* __restrict__ aggr)
{
  __shared__ float efs[32][8];
  __shared__ float As[32][36];
  __shared__ float Bs[32][136];
  const int tid = threadIdx.x;
  const int m0 = blockIdx.x * 32;
  const int kt0 = blockIdx.y * 28;
  const int c0 = kt0 >> 2;
  {
    int t = tid >> 3, cc = tid & 7;
    if (cc < 7) {
      int c = c0 + cc;
      int m = m0 + t;
      const float* attr = (m < 4096) ? (cea + (size_t)m * 17) : (sea + (size_t)(m - 4096) * 17);
      float val;
      if (c < 16) val = attr[c];
      else if (c < 48) {
        float d = fminf(fmaxf(attr[16], 0.0f), 10.0f);
        float t2 = d - (float)((c - 16) * (5.0 / 31.0));
        val = expf(-38.44f * t2 * t2);           // gamma = (31/5)^2
      } else val = 1.0f;
      efs[t][cc] = val;
    }
  }
  const int gk = tid & 31, gt = (tid >> 5) * 4;
  float hreg[4][4];
  #pragma unroll
  for (int i = 0; i < 4; i++) {
    int m = m0 + gt + i;
    int dst = (m < 4096) ? cei[4096 + m] : (sei[1024 + (m - 4096)] + 2048);
    const float* hp = h + (size_t)dst * 128 + gk;
    hreg[i][0] = hp[0]; hreg[i][1] = hp[32]; hreg[i][2] = hp[64]; hreg[i][3] = hp[96];
  }
  const int tn = tid & 31, tm = tid >> 5;
  const int e0 = 4 * tn, t0 = 4 * tm;
  const int se = tid >> 1, sk = (tid & 1) * 16;
  float acc[4][4] = {};
  __syncthreads();
  #pragma unroll 1
  for (int kt = kt0; kt < kt0 + 28; kt++) {
    int c = kt >> 2, cc = c - c0, j = kt & 3;
    float4 av;
    av.x = efs[gt + 0][cc] * hreg[0][j];
    av.y = efs[gt + 1][cc] * hreg[1][j];
    av.z = efs[gt + 2][cc] * hreg[2][j];
    av.w = efs[gt + 3][cc] * hreg[3][j];
    *(float4*)&As[gk][gt] = av;
    const float* bp = ((c < 48) ? (elw + (size_t)c * 16384) : elb) + (size_t)se * 128 + j * 32 + sk;
    float4 w0 = *(const float4*)(bp + 0);
    float4 w1 = *(const float4*)(bp + 4);
    float4 w2 = *(const float4*)(bp + 8);
    float4 w3 = *(const float4*)(bp + 12);
    Bs[sk + 0][se] = w0.x;  Bs[sk + 1][se] = w0.y;  Bs[sk + 2][se] = w0.z;  Bs[sk + 3][se] = w0.w;
    Bs[sk + 4][se] = w1.x;  Bs[sk + 5][se] = w1.y;  Bs[sk + 6][se] = w1.z;  Bs[sk + 7][se] = w1.w;
    Bs[sk + 8][se] = w2.x;  Bs[sk + 9][se] = w2.y;  Bs[sk + 10][se] = w2.z; Bs[sk + 11][se] = w2.w;
    Bs[sk + 12][se] = w3.x; Bs[sk + 13][se] = w3.y; Bs[sk + 14][se] = w3.z; Bs[sk + 15][se] = w3.w;
    __syncthreads();
    #pragma unroll
    for (int kk = 0; kk < 32; kk++) {
      float4 a = *(const float4*)&As[kk][t0];
      float4 b = *(const float4*)&Bs[kk][e0];
      acc[0][0] += a.x * b.x; acc[0][1] += a.x * b.y; acc[0][2] += a.x * b.z; acc[0][3] += a.x * b.w;
      acc[1][0] += a.y * b.x; acc[1][1] += a.y * b.y; acc[1][2] += a.y * b.z; acc[1][3] += a.y * b.w;
      acc[2][0] += a.z * b.x; acc[2][1] += a.z * b.y; acc[2][2] += a.z * b.z; acc[2][3] += a.z * b.w;
      acc[3][0] += a.w * b.x; acc[3][1] += a.w * b.y; acc[3][2] += a.w * b.z; acc[3][3] += a.w * b.w;
    }
    __syncthreads();
  }
  #pragma unroll
  for (int i = 0; i < 4; i++) {
    int m = m0 + t0 + i;
    int src = (m < 4096) ? cei[m] : (sei[m - 4096] + 2048);
    float* dst = aggr + (size_t)src * 128 + e0;
    atomicAdd(dst + 0, acc[i][0]);
    atomicAdd(dst + 1, acc[i][1]);
    atomicAdd(dst + 2, acc[i][2]);
    atomicAdd(dst + 3, acc[i][3]);
  }
}

// ---------------------------------------------------------------- STREAMING GEMM16: 1 barrier.
// Stage A (16x128) in LDS; stream B column-wise from L2 (coalesced, weights shared by all blocks).
// Thread (c = tid&127, rg = tid>>7) owns 8 rows of column c. k ascends -> stable order.
__device__ __forceinline__ void sgemm16_body(float (*Al)[132],
    const float* __restrict__ A, const float* __restrict__ Bp,
    const float* __restrict__ biasp, float* __restrict__ Cp,
    int row0, int ldb, int ldc)
{
  const int tid = threadIdx.x;
  const int c = tid & 127, rg = tid >> 7;
  for (int i = tid; i < 512; i += 256) {
    int r = i >> 5, k4 = (i & 31) << 2;
    *(float4*)&Al[r][k4] = *(const float4*)(A + (size_t)(row0 + r) * 128 + k4);
  }
  __syncthreads();
  float acc[8] = {};
  const float* bp = Bp + c;
  #pragma unroll 4
  for (int k = 0; k < 128; k += 4) {
    float b0 = bp[(size_t)(k + 0) * ldb];
    float b1 = bp[(size_t)(k + 1) * ldb];
    float b2 = bp[(size_t)(k + 2) * ldb];
    float b3 = bp[(size_t)(k + 3) * ldb];
    #pragma unroll
    for (int i = 0; i < 8; i++) {
      float4 a = *(const float4*)&Al[rg * 8 + i][k];
      acc[i] += a.x * b0; acc[i] += a.y * b1; acc[i] += a.z * b2; acc[i] += a.w * b3;
    }
  }
  float bia = biasp[c];
  #pragma unroll
  for (int i = 0; i < 8; i++)
    Cp[(size_t)(row0 + rg * 8 + i) * ldc + c] = acc[i] + bia;
}

// ---------------------------------------------------------------- merged QKV: graph (3x160) + seq (3x128)
__global__ __launch_bounds__(256) void qkv_k(
    int gBlocks,
    const float* __restrict__ ghb,
    const float* gqw, const float* gkw, const float* gvw,
    const float* gqb, const float* gkb, const float* gvb, float* gout,
    const float* __restrict__ sxs, const float* sw, const float* sb, float* sout)
{
  __shared__ float Al[16][132];
  int bx = blockIdx.x;
  if (bx < gBlocks) {
    int z = bx / 160, rt = bx % 160;
    const float* B = (z == 0) ? gqw : (z == 1) ? gkw : gvw;
    const float* bias = (z == 0) ? gqb : (z == 1) ? gkb : gvb;
    sgemm16_body(Al, ghb, B, bias, gout + (size_t)z * 327680, rt * 16, 128, 128);
  } else {
    int i = bx - gBlocks;
    int z = i >> 7, rt = i & 127;
    sgemm16_body(Al, sxs, sw + z * 128, sb + z * 128, sout + z * 128, rt * 16, 384, 384);
  }
}

// ---------------------------------------------------------------- graph attention body (N=32, GD=16)
struct __align__(16) GAttnSm { float qs[32][17], ksh[32][17], vsh[32][17], ss[32][33], rs[32]; };
__device__ __forceinline__ void gattn_body(GAttnSm& sm, int g, int h,
    const float* __restrict__ q, const float* __restrict__ k,
    const float* __restrict__ v, const float* __restrict__ dist, float* __restrict__ o)
{
  const int tid = threadIdx.x;
  {
    int idx = tid * 2;
    int i = idx >> 4, d = idx & 15;
    size_t base = ((size_t)(g * 32 + i)) * 128 + h * 16 + d;
    sm.qs[i][d] = q[base];  sm.qs[i][d + 1] = q[base + 1];
    sm.ksh[i][d] = k[base]; sm.ksh[i][d + 1] = k[base + 1];
    sm.vsh[i][d] = v[base]; sm.vsh[i][d + 1] = v[base + 1];
  }
  __syncthreads();
  {
    int i = tid >> 3, j0 = (tid & 7) * 4;
    for (int j = j0; j < j0 + 4; j++) {
      float a = 0;
      #pragma unroll
      for (int d = 0; d < 16; d++) a += sm.qs[i][d] * sm.ksh[j][d];
      a = a * 0.25f + dist[(size_t)g * 1024 + i * 32 + j];
      sm.ss[i][j] = fminf(fmaxf(a, -10.0f), 10.0f);
    }
  }
  __syncthreads();
  if (tid < 32) {
    float m = -1e30f;
    for (int j = 0; j < 32; j++) m = fmaxf(m, sm.ss[tid][j]);
    float s = 0;
    for (int j = 0; j < 32; j++) { float ex = expf(sm.ss[tid][j] - m); sm.ss[tid][j] = ex; s += ex; }
    sm.rs[tid] = 1.0f / s;
  }
  __syncthreads();
  {
    int idx = tid * 2;
    int i = idx >> 4, d = idx & 15;
    float a0 = 0, a1 = 0;
    for (int j = 0; j < 32; j++) { float wj = sm.ss[i][j]; a0 += wj * sm.vsh[j][d]; a1 += wj * sm.vsh[j][d + 1]; }
    float r = sm.rs[i];
    size_t base = ((size_t)(g * 32 + i)) * 128 + h * 16 + d;
    o[base] = a0 * r; o[base + 1] = a1 * r;
  }
}

// ---------------------------------------------------------------- seq attention body (slim, K/V tiled; r11-verified)
struct __align__(16) SAttnSm { float kv[32][33], qs2[32][33], ss2[32][129], red[32][8], red2[32][8]; };
__device__ __forceinline__ void sattn_body(SAttnSm& sm, int b, int h, int qt,
    const float* __restrict__ qkv, float* __restrict__ o)
{
  const int tid = threadIdx.x;
  {
    int i = tid >> 3, d0 = (tid & 7) * 4;
    const float* qp = qkv + ((size_t)(b * 128 + qt * 32 + i)) * 384 + h * 32 + d0;
    sm.qs2[i][d0 + 0] = qp[0]; sm.qs2[i][d0 + 1] = qp[1];
    sm.qs2[i][d0 + 2] = qp[2]; sm.qs2[i][d0 + 3] = qp[3];
  }
  const int i = tid >> 3, sub = tid & 7;
  for (int jt = 0; jt < 4; jt++) {
    {
      int r = tid >> 3, dd = (tid & 7) * 4;
      const float* kp = qkv + ((size_t)(b * 128 + jt * 32 + r)) * 384 + 128 + h * 32 + dd;
      float4 kv4 = *(const float4*)kp;
      sm.kv[r][dd + 0] = kv4.x; sm.kv[r][dd + 1] = kv4.y;
      sm.kv[r][dd + 2] = kv4.z; sm.kv[r][dd + 3] = kv4.w;
    }
    __syncthreads();
    {
      int j0 = jt * 32 + sub * 4;
      for (int j = j0; j < j0 + 4; j++) {
        int jr = j - jt * 32;
        float a = 0;
        #pragma unroll
        for (int d = 0; d < 32; d++) a += sm.qs2[i][d] * sm.kv[jr][d];
        sm.ss2[i][j] = a * 0.17677669529663687f;
      }
    }
    __syncthreads();
  }
  float m = -1e30f;
  for (int j = sub; j < 128; j += 8) m = fmaxf(m, sm.ss2[i][j]);
  sm.red[i][sub] = m;
  __syncthreads();
  float mm = sm.red[i][0];
  #pragma unroll
  for (int t = 1; t < 8; t++) mm = fmaxf(mm, sm.red[i][t]);
  float ps = 0;
  for (int j = sub; j < 128; j += 8) { float ex = expf(sm.ss2[i][j] - mm); sm.ss2[i][j] = ex; ps += ex; }
  sm.red2[i][sub] = ps;
  __syncthreads();
  float s = 0;
  #pragma unroll
  for (int t = 0; t < 8; t++) s += sm.red2[i][t];
  float rinv = 1.0f / s;
  float a0 = 0, a1 = 0, a2 = 0, a3 = 0;
  const int d0 = sub * 4;
  for (int jt = 0; jt < 4; jt++) {
    __syncthreads();
    {
      int r = tid >> 3, dd = (tid & 7) * 4;
      const float* vp = qkv + ((size_t)(b * 128 + jt * 32 + r)) * 384 + 256 + h * 32 + dd;
      float4 vv = *(const float4*)vp;
      sm.kv[r][dd + 0] = vv.x; sm.kv[r][dd + 1] = vv.y;
      sm.kv[r][dd + 2] = vv.z; sm.kv[r][dd + 3] = vv.w;
    }
    __syncthreads();
    for (int jr = 0; jr < 32; jr++) {
      float wj = sm.ss2[i][jt * 32 + jr];
      a0 += wj * sm.kv[jr][d0 + 0]; a1 += wj * sm.kv[jr][d0 + 1];
      a2 += wj * sm.kv[jr][d0 + 2]; a3 += wj * sm.kv[jr][d0 + 3];
    }
  }
  float* op = o + ((size_t)(b * 128 + qt * 32 + i)) * 128 + h * 32 + d0;
  op[0] = a0 * rinv; op[1] = a1 * rinv; op[2] = a2 * rinv; op[3] = a3 * rinv;
}

// ---------------------------------------------------------------- merged attention: graph + seq
union AttnU { GAttnSm a; SAttnSm s; };
__global__ __launch_bounds__(256) void attn_k(
    int gBlocks, const float* q, const float* k, const float* v,
    const float* dist, float* go, const float* qkv, float* so)
{
  __shared__ AttnU u;
  int bx = blockIdx.x;
  if (bx < gBlocks) gattn_body(u.a, bx >> 3, bx & 7, q, k, v, dist, go);
  else { int i = bx - gBlocks; sattn_body(u.s, i >> 4, (i >> 2) & 3, i & 3, qkv, so); }
}

// ---------------------------------------------------------------- STREAMING layer tail: ~8 barriers, 25KB LDS.
// x1 = LN(A@Wo+bo+res); Out = LN(relu(x1@W1+b1)@W2+b2 + x1)
struct __align__(16) TailSm2 { float x1v[16][132]; float big[16][260]; };
__device__ __forceinline__ void tail_body(TailSm2& sm, int row0, const float* __restrict__ A,
    const float* __restrict__ Wo, const float* __restrict__ bo, const float* __restrict__ res,
    const float* __restrict__ g1, const float* __restrict__ b1n,
    const float* __restrict__ W1, const float* __restrict__ b1f,
    const float* __restrict__ W2, const float* __restrict__ b2f,
    const float* __restrict__ g2, const float* __restrict__ b2n,
    float* __restrict__ Out)
{
  const int tid = threadIdx.x;
  const int c = tid & 127, rg = tid >> 7;
  // ---- stage A: big <- A tile; stream Wo; v -> x1v ----
  for (int i = tid; i < 512; i += 256) {
    int r = i >> 5, k4 = (i & 31) << 2;
    *(float4*)&sm.big[r][k4] = *(const float4*)(A + (size_t)(row0 + r) * 128 + k4);
  }
  __syncthreads();
  {
    float acc[8] = {};
    const float* bp = Wo + c;
    #pragma unroll 4
    for (int k = 0; k < 128; k += 4) {
      float b0 = bp[(k + 0) * 128], b1 = bp[(k + 1) * 128];
      float b2 = bp[(k + 2) * 128], b3 = bp[(k + 3) * 128];
      #pragma unroll
      for (int i = 0; i < 8; i++) {
        float4 a = *(const float4*)&sm.big[rg * 8 + i][k];
        acc[i] += a.x * b0; acc[i] += a.y * b1; acc[i] += a.z * b2; acc[i] += a.w * b3;
      }
    }
    float bia = bo[c];
    #pragma unroll
    for (int i = 0; i < 8; i++) {
      int r = rg * 8 + i;
      sm.x1v[r][c] = acc[i] + bia + res[(size_t)(row0 + r) * 128 + c];
    }
  }
  __syncthreads();
  // ---- LN(x1v) in place ----
  {
    const int tm = tid >> 5, tn = tid & 31;
    const int t0 = 2 * tm, e0 = 4 * tn;
    #pragma unroll
    for (int i = 0; i < 2; i++) {
      int r = t0 + i;
      float v0 = sm.x1v[r][e0 + 0], v1 = sm.x1v[r][e0 + 1];
      float v2 = sm.x1v[r][e0 + 2], v3 = sm.x1v[r][e0 + 3];
      float s = v0 + v1 + v2 + v3;
      #pragma unroll
      for (int o = 1; o < 32; o <<= 1) s += __shfl_xor(s, o);
      float mean = s * (1.0f / 128.0f);
      float d0 = v0 - mean, d1 = v1 - mean, d2 = v2 - mean, d3 = v3 - mean;
      float sq = d0 * d0 + d1 * d1 + d2 * d2 + d3 * d3;
      #pragma unroll
      for (int o = 1; o < 32; o <<= 1) sq += __shfl_xor(sq, o);
      float rstd = 1.0f / sqrtf(sq * (1.0f / 128.0f) + 1e-5f);
      sm.x1v[r][e0 + 0] = d0 * rstd * g1[e0 + 0] + b1n[e0 + 0];
      sm.x1v[r][e0 + 1] = d1 * rstd * g1[e0 + 1] + b1n[e0 + 1];
      sm.x1v[r][e0 + 2] = d2 * rstd * g1[e0 + 2] + b1n[e0 + 2];
      sm.x1v[r][e0 + 3] = d3 * rstd * g1[e0 + 3] + b1n[e0 + 3];
    }
  }
  __syncthreads();
  // ---- stage B: hid = relu(x1 @ W1 + b1f) into big; thread owns col tid (256), 16 rows ----
  {
    float acc[16] = {};
    const float* bp = W1 + tid;
    #pragma unroll 2
    for (int k = 0; k < 128; k += 4) {
      float b0 = bp[(k + 0) * 256], b1 = bp[(k + 1) * 256];
      float b2 = bp[(k + 2) * 256], b3 = bp[(k + 3) * 256];
      #pragma unroll
      for (int i = 0; i < 16; i++) {
        float4 a = *(const float4*)&sm.x1v[i][k];
        acc[i] += a.x * b0; acc[i] += a.y * b1; acc[i] += a.z * b2; acc[i] += a.w * b3;
      }
    }
    float bia = b1f[tid];
    __syncthreads();
    #pragma unroll
    for (int i = 0; i < 16; i++)
      sm.big[i][tid] = fmaxf(acc[i] + bia, 0.0f);
  }
  __syncthreads();
  // ---- stage C: stream W2 (K=256); v = acc + b2f + x1 -> x1v; final LN -> global ----
  {
    float acc[8] = {};
    const float* bp = W2 + c;
    #pragma unroll 4
    for (int k = 0; k < 256; k += 4) {
      float b0 = bp[(k + 0) * 128], b1 = bp[(k + 1) * 128];
      float b2 = bp[(k + 2) * 128], b3 = bp[(k + 3) * 128];
      #pragma unroll
      for (int i = 0; i < 8; i++) {
        float4 a = *(const float4*)&sm.big[rg * 8 + i][k];
        acc[i] += a.x * b0; acc[i] += a.y * b1; acc[i] += a.z * b2; acc[i] += a.w * b3;
      }
    }
    float bia = b2f[c];
    float v[8];
    #pragma unroll
    for (int i = 0; i < 8; i++) v[i] = acc[i] + bia + sm.x1v[rg * 8 + i][c];
    __syncthreads();
    #pragma unroll
    for (int i = 0; i < 8; i++) sm.x1v[rg * 8 + i][c] = v[i];
  }
  __syncthreads();
  {
    const int tm = tid >> 5, tn = tid & 31;
    const int t0 = 2 * tm, e0 = 4 * tn;
    #pragma unroll
    for (int i = 0; i < 2; i++) {
      int r = t0 + i;
      float v0 = sm.x1v[r][e0 + 0], v1 = sm.x1v[r][e0 + 1];
      float v2 = sm.x1v[r][e0 + 2], v3 = sm.x1v[r][e0 + 3];
      float s = v0 + v1 + v2 + v3;
      #pragma unroll
      for (int o = 1; o < 32; o <<= 1) s += __shfl_xor(s, o);
      float mean = s * (1.0f / 128.0f);
      float d0 = v0 - mean, d1 = v1 - mean, d2 = v2 - mean, d3 = v3 - mean;
      float sq = d0 * d0 + d1 * d1 + d2 * d2 + d3 * d3;
      #pragma unroll
      for (int o = 1; o < 32; o <<= 1) sq += __shfl_xor(sq, o);
      float rstd = 1.0f / sqrtf(sq * (1.0f / 128.0f) + 1e-5f);
      float* cp = Out + (size_t)(row0 + r) * 128 + e0;
      cp[0] = d0 * rstd * g2[e0 + 0] + b2n[e0 + 0];
      cp[1] = d1 * rstd * g2[e0 + 1] + b2n[e0 + 1];
      cp[2] = d2 * rstd * g2[e0 + 2] + b2n[e0 + 2];
      cp[3] = d3 * rstd * g2[e0 + 3] + b2n[e0 + 3];
    }
  }
}

// ---------------------------------------------------------------- merged tail: graph + seq
__global__ __launch_bounds__(256) void tail_k(
    int gBlocks,
    const float* gA, const float* gWo, const float* gbo, const float* gres,
    const float* gg1, const float* gb1, const float* gW1, const float* gbf1,
    const float* gW2, const float* gbf2, const float* gg2, const float* gb2, float* gOut,
    const float* sA, const float* sWo, const float* sbo, const float* sres,
    const float* sg1, const float* sb1, const float* sW1, const float* sbf1,
    const float* sW2, const float* sbf2, const float* sg2, const float* sb2, float* sOut)
{
  __shared__ TailSm2 sm;
  int bx = blockIdx.x;
  if (bx < gBlocks)
    tail_body(sm, bx * 16, gA, gWo, gbo, gres, gg1, gb1, gW1, gbf1, gW2, gbf2, gg2, gb2, gOut);
  else
    tail_body(sm, (bx - gBlocks) * 16, sA, sWo, sbo, sres, sg1, sb1, sW1, sbf1, sW2, sbf2, sg2, sb2, sOut);
}

// ---------------------------------------------------------------- LayerNorm rows of 128 (after edge aggr)
__global__ __launch_bounds__(128) void ln_k(
    const float* __restrict__ x, const float* __restrict__ res,
    const float* __restrict__ g, const float* __restrict__ b, float* __restrict__ out)
{
  __shared__ float sred[2];
  int r = blockIdx.x, e = threadIdx.x;
  size_t idx = (size_t)r * 128 + e;
  float v = x[idx] + res[idx];
  float nv = blk_norm(v, e, sred);
  out[idx] = nv * g[e] + b[e];
}

// ---------------------------------------------------------------- pool + smean + fusion + cross-modal + head
__global__ __launch_bounds__(128) void head_k(
    const float* __restrict__ hb, const float* __restrict__ xs, const float* __restrict__ gfeat,
    const float* fg1w, const float* fg1b, const float* fg2w, const float* fg2b,
    const float* g2s_vw, const float* g2s_vb, const float* g2s_ow, const float* g2s_ob,
    const float* n1g, const float* n1b,
    const float* s2g_vw, const float* s2g_vb, const float* s2g_ow, const float* s2g_ob,
    const float* n2g, const float* n2b,
    const float* r1w, const float* r1b, const float* r2w, const float* r2b,
    float* __restrict__ out)
{
  __shared__ float T[128], S[128], G[128], Sm[128], t1[128], t2[128], gh[64], sred[2];
  int mol = blockIdx.x, e = threadIdx.x;
  {
    float cs = 0;
    for (int c = 0; c < 4; c++) {
      int g = mol * 4 + c;
      float s = 0;
      for (int i = 0; i < 32; i++) s += hb[((size_t)(g * 32 + i)) * 128 + e];
      cs += s * (1.0f / 32.0f);
    }
    cs *= 0.25f;
    float s2 = 0;
    int g = 64 + mol;
    for (int i = 0; i < 32; i++) s2 += hb[((size_t)(g * 32 + i)) * 128 + e];
    T[e] = cs + s2 * (1.0f / 32.0f);
    float ss = 0;
    for (int l = 0; l < 128; l++) ss += xs[((size_t)(mol * 128 + l)) * 128 + e];
    S[e] = ss * (1.0f / 128.0f);
  }
  __syncthreads();
  if (e < 64) {
    float a = fg1b[e];
    for (int f = 0; f < 128; f++) a += T[f] * fg1w[f * 64 + e];
    for (int f = 0; f < 128; f++) a += S[f] * fg1w[(128 + f) * 64 + e];
    gh[e] = fmaxf(a, 0.0f);
  }
  __syncthreads();
  {
    float a = fg2b[e];
    for (int j = 0; j < 64; j++) a += gh[j] * fg2w[j * 128 + e];
    float gate = 1.0f / (1.0f + expf(-a));
    float fu = gate * T[e] + (1.0f - gate) * S[e];
    G[e] = fu; Sm[e] = fu;
  }
  __syncthreads();
  for (int l = 0; l < 2; l++) {
    const float* vw = g2s_vw + (size_t)l * 16384; const float* vb = g2s_vb + l * 128;
    const float* ow = g2s_ow + (size_t)l * 16384; const float* ob = g2s_ob + l * 128;
    float a = vb[e];
    for (int f = 0; f < 128; f++) a += Sm[f] * vw[f * 128 + e];
    t1[e] = a;
    __syncthreads();
    a = ob[e];
    for (int f = 0; f < 128; f++) a += t1[f] * ow[f * 128 + e];
    float nv = blk_norm(G[e] + a, e, sred);
    G[e] = nv * n1g[l * 128 + e] + n1b[l * 128 + e];
    __syncthreads();
    const float* vw2 = s2g_vw + (size_t)l * 16384; const float* vb2 = s2g_vb + l * 128;
    const float* ow2 = s2g_ow + (size_t)l * 16384; const float* ob2 = s2g_ob + l * 128;
    a = vb2[e];
    for (int f = 0; f < 128; f++) a += G[f] * vw2[f * 128 + e];
    t1[e] = a;
    __syncthreads();
    a = ob2[e];
    for (int f = 0; f < 128; f++) a += t1[f] * ow2[f * 128 + e];
    nv = blk_norm(Sm[e] + a, e, sred);
    Sm[e] = nv * n2g[l * 128 + e] + n2b[l * 128 + e];
    __syncthreads();
  }
  t2[e] = 0.5f * (G[e] + Sm[e]);
  __syncthreads();
  float a = r1b[e];
  for (int f = 0; f < 128; f++) a += t2[f] * r1w[f * 128 + e];
  for (int f = 0; f < 3; f++) a += gfeat[mol * 3 + f] * r1w[(128 + f) * 128 + e];
  a = fmaxf(a, 0.0f);
  float p = a * r2w[e];
  #pragma unroll
  for (int o = 1; o < 64; o <<= 1) p += __shfl_xor(p, o);
  if ((e & 63) == 0) sred[e >> 6] = p;
  __syncthreads();
  if (e == 0) out[mol] = sred[0] + sred[1] + r2b[0];
}

// ================================================================ host
extern "C" void kernel_launch(void* const* d_in, const int* in_sizes, int n_in,
                              void* d_out, int out_size, void* d_ws, size_t ws_size,
                              hipStream_t stream)
{
  (void)n_in; (void)out_size; (void)ws_size;
  const bool dict = (in_sizes[1] == 8192);
  auto IN = [&](int di, int si) { return d_in[dict ? di : si]; };

  const float* conf_x   = (const float*)IN(0, 0);
  const int*   conf_ei  = (const int*)  IN(1, 63);
  const float* conf_ea  = (const float*)IN(2, 1);
  const float* conf_pos = (const float*)IN(3, 2);
  const float* scaf_x   = (const float*)IN(4, 3);
  const int*   scaf_ei  = (const int*)  IN(5, 64);
  const float* scaf_ea  = (const float*)IN(6, 4);
  const float* scaf_pos = (const float*)IN(7, 5);
  const int*   tokens   = (const int*)  IN(8, 65);
  const float* gfeat    = (const float*)IN(9, 6);
  const float* gproj_w  = (const float*)IN(11, 7);
  const float* gproj_b  = (const float*)IN(12, 8);
  const float* elin_w   = (const float*)IN(13, 9);
  const float* elin_b   = (const float*)IN(14, 10);
  const float* eln_g    = (const float*)IN(15, 11);
  const float* eln_b    = (const float*)IN(16, 12);
  const float* gt_qw    = (const float*)IN(17, 13);
  const float* gt_qb    = (const float*)IN(18, 14);
  const float* gt_kw    = (const float*)IN(19, 15);
  const float* gt_kb    = (const float*)IN(20, 16);
  const float* gt_vw    = (const float*)IN(21, 17);
  const float* gt_vb    = (const float*)IN(22, 18);
  const float* gt_ow    = (const float*)IN(23, 19);
  const float* gt_ob    = (const float*)IN(24, 20);
  const float* gt_ln1g  = (const float*)IN(25, 21);
  const float* gt_ln1b  = (const float*)IN(26, 22);
  const float* gt_f1w   = (const float*)IN(27, 23);
  const float* gt_f1b   = (const float*)IN(28, 24);
  const float* gt_f2w   = (const float*)IN(29, 25);
  const float* gt_f2b   = (const float*)IN(30, 26);
  const float* gt_ln2g  = (const float*)IN(31, 27);
  const float* gt_ln2b  = (const float*)IN(32, 28);
  const float* tok_emb  = (const float*)IN(33, 29);
  const float* pos_emb  = (const float*)IN(34, 30);
  const float* se_inw   = (const float*)IN(35, 31);
  const float* se_inb   = (const float*)IN(36, 32);
  const float* se_ow    = (const float*)IN(37, 33);
  const float* se_ob    = (const float*)IN(38, 34);
  const float* se_ln1g  = (const float*)IN(39, 35);
  const float* se_ln1b  = (const float*)IN(40, 36);
  const float* se_f1w   = (const float*)IN(41, 37);
  const float* se_f1b   = (const float*)IN(42, 38);
  const float* se_f2w   = (const float*)IN(43, 39);
  const float* se_f2b   = (const float*)IN(44, 40);
  const float* se_ln2g  = (const float*)IN(45, 41);
  const float* se_ln2b  = (const float*)IN(46, 42);
  const float* fg1_w    = (const float*)IN(47, 43);
  const float* fg1_b    = (const float*)IN(48, 44);
  const float* fg2_w    = (const float*)IN(49, 45);
  const float* fg2_b    = (const float*)IN(50, 46);
  const float* cm_g2s_vw = (const float*)IN(51, 47);
  const float* cm_g2s_vb = (const float*)IN(52, 48);
  const float* cm_g2s_ow = (const float*)IN(53, 49);
  const float* cm_g2s_ob = (const float*)IN(54, 50);
  const float* cm_s2g_vw = (const float*)IN(55, 53);
  const float* cm_s2g_vb = (const float*)IN(56, 54);
  const float* cm_s2g_ow = (const float*)IN(57, 55);
  const float* cm_s2g_ob = (const float*)IN(58, 56);
  const float* cm_n1g   = (const float*)IN(59, 51);
  const float* cm_n1b   = (const float*)IN(60, 52);
  const float* cm_n2g   = (const float*)IN(61, 57);
  const float* cm_n2b   = (const float*)IN(62, 58);
  const float* r1_w     = (const float*)IN(63, 59);
  const float* r1_b     = (const float*)IN(64, 60);
  const float* r2_w     = (const float*)IN(65, 61);
  const float* r2_b     = (const float*)IN(66, 62);
  float* out = (float*)d_out;

  // ---- workspace (fp32) ----
  float* w = (float*)d_ws;
  size_t off = 0;
  auto alloc = [&](size_t n) { float* p = w + off; off += n; return p; };
  float* h     = alloc(2560 * 128);
  float* aggr  = alloc(2560 * 128);
  float* hb    = alloc(2560 * 128);
  float* distb = alloc(80 * 1024);
  float* qb    = alloc(3 * 327680);     // graph q/k/v
  float* atto  = alloc(327680);
  float* xs2   = alloc(2048 * 128);
  float* qkv3  = alloc(2048 * 384);
  float* satto = alloc(2048 * 128);
  float* xsfin = alloc(2048 * 128);

  // front (node_proj + zero aggr + dist + embed)
  front_k<<<2384, 256, 0, stream>>>(conf_x, scaf_x, gproj_w, gproj_b, h, aggr,
                                    conf_pos, scaf_pos, distb,
                                    tokens, tok_emb, pos_emb, xs2);
  edge_gemm_k<<<dim3(160, 7), 256, 0, stream>>>(conf_ea, scaf_ea, conf_ei, scaf_ei, h, elin_w, elin_b, aggr);
  ln_k<<<2560, 128, 0, stream>>>(aggr, h, eln_g, eln_b, hb);

  // merged graph(3) + seq(4) transformer layers
  for (int l = 0; l < 4; l++) {
    const bool hasG = (l < 3);
    const int lg = hasG ? l : 0;
    const int gq = hasG ? 480 : 0;
    const int ga = hasG ? 640 : 0;
    const int gt = hasG ? 160 : 0;
    float* sOut = (l == 3) ? xsfin : xs2;
    qkv_k<<<gq + 384, 256, 0, stream>>>(gq,
        hb, gt_qw + (size_t)lg * 16384, gt_kw + (size_t)lg * 16384, gt_vw + (size_t)lg * 16384,
        gt_qb + lg * 128, gt_kb + lg * 128, gt_vb + lg * 128, qb,
        xs2, se_inw + (size_t)l * 49152, se_inb + l * 384, qkv3);
    attn_k<<<ga + 256, 256, 0, stream>>>(ga, qb, qb + 327680, qb + 655360, distb, atto, qkv3, satto);
    tail_k<<<gt + 128, 256, 0, stream>>>(gt,
        atto, gt_ow + (size_t)lg * 16384, gt_ob + lg * 128, hb,
        gt_ln1g + lg * 128, gt_ln1b + lg * 128,
        gt_f1w + (size_t)lg * 32768, gt_f1b + lg * 256,
        gt_f2w + (size_t)lg * 32768, gt_f2b + lg * 128,
        gt_ln2g + lg * 128, gt_ln2b + lg * 128, hb,
        satto, se_ow + (size_t)l * 16384, se_ob + l * 128, xs2,
        se_ln1g + l * 128, se_ln1b + l * 128,
        se_f1w + (size_t)l * 32768, se_f1b + l * 256,
        se_f2w + (size_t)l * 32768, se_f2b + l * 128,
        se_ln2g + l * 128, se_ln2b + l * 128, sOut);
  }

  // head
  head_k<<<16, 128, 0, stream>>>(hb, xsfin, gfeat,
                                 fg1_w, fg1_b, fg2_w, fg2_b,
                                 cm_g2s_vw, cm_g2s_vb, cm_g2s_ow, cm_g2s_ob, cm_n1g, cm_n1b,
                                 cm_s2g_vw, cm_s2g_vb, cm_s2g_ow, cm_s2g_ob, cm_n2g, cm_n2b,
                                 r1_w, r1_b, r2_w, r2_b, out);
}

// Round 13
// 628.591 us; speedup vs baseline: 1.2151x; 1.2049x over previous
//
#include <hip/hip_runtime.h>
#include <hip/hip_bf16.h>

// E=128 GH=8 GD=16 GL=3 | SH=4 SD=32 SL=4 | N=32 GC=64 GS=16 DEG=64 BMOL=16
// M_conf=4096 M_scaf=1024 M_tot=5120. All float tensors fp32.
// Composition of best-verified pieces: r8 front/edge/ln/qkv/tail/schedule + r12 union-slim attn.

// ---------------------------------------------------------------- shared-mem structs
struct __align__(16) G16Sm   { float Sa[32][20]; float Bs[32][136]; };
struct __align__(16) GAttnSm { float qs[32][17], ksh[32][17], vsh[32][17], ss[32][33], rs[32]; };
struct __align__(16) SAttnSm { float kv[32][33], qs2[32][33], ss2[32][129], red[32][8], red2[32][8]; };
struct __align__(16) TailSm  { float x1[16][132]; float hid[16][260]; float sbuf[4352]; float Sa[32][20]; };
union AttnU { GAttnSm a; SAttnSm s; };

// ---------------------------------------------------------------- LN helper (block of 128 threads)
__device__ __forceinline__ float blk_norm(float v, int e, float* sred)
{
  float s = v;
  #pragma unroll
  for (int o = 1; o < 64; o <<= 1) s += __shfl_xor(s, o);
  if ((e & 63) == 0) sred[e >> 6] = s;
  __syncthreads();
  float mean = (sred[0] + sred[1]) * (1.0f / 128.0f);
  __syncthreads();
  float d = v - mean;
  float s2 = d * d;
  #pragma unroll
  for (int o = 1; o < 64; o <<= 1) s2 += __shfl_xor(s2, o);
  if ((e & 63) == 0) sred[e >> 6] = s2;
  __syncthreads();
  float var = (sred[0] + sred[1]) * (1.0f / 128.0f);
  __syncthreads();
  return d / sqrtf(var + 1e-5f);
}

// ---------------------------------------------------------------- merged front-end (r8, proven)
__global__ __launch_bounds__(256) void front_k(
    const float* __restrict__ cx, const float* __restrict__ sx,
    const float* __restrict__ w, const float* __restrict__ b,
    float* __restrict__ h, float* __restrict__ aggr,
    const float* __restrict__ cpos, const float* __restrict__ spos, float* __restrict__ dist,
    const int* __restrict__ tokens, const float* __restrict__ tok_emb,
    const float* __restrict__ pos_emb, float* __restrict__ xs)
{
  __shared__ float sP[128];
  const int bx = blockIdx.x, tid = threadIdx.x;
  if (bx < 1280) {
    int r = bx * 2 + (tid >> 7), e = tid & 127;
    const float* x = (r < 2048) ? (cx + (size_t)r * 64) : (sx + (size_t)(r - 2048) * 64);
    float* xrow = sP + (tid >> 7) * 64;
    if (e < 64) xrow[e] = x[e];
    __syncthreads();
    float acc = b[e];
    for (int a = 0; a < 64; a++) acc += xrow[a] * w[a * 128 + e];
    h[(size_t)r * 128 + e] = acc;
    aggr[(size_t)r * 128 + e] = 0.0f;
  } else if (bx < 1360) {
    int g = bx - 1280;
    const float* p = (g < 64) ? (cpos + (size_t)g * 96) : (spos + (size_t)(g - 64) * 96);
    if (tid < 96) sP[tid] = p[tid];
    __syncthreads();
    #pragma unroll
    for (int jj = 0; jj < 4; jj++) {
      int idx = tid * 4 + jj;
      int i = idx >> 5, j = idx & 31;
      float dx = sP[i * 3 + 0] - sP[j * 3 + 0];
      float dy = sP[i * 3 + 1] - sP[j * 3 + 1];
      float dz = sP[i * 3 + 2] - sP[j * 3 + 2];
      float d2 = dx * dx + dy * dy + dz * dz;
      dist[(size_t)g * 1024 + idx] = (d2 > 0.0f) ? sqrtf(d2) : 0.0f;
    }
  } else {
    int r = (bx - 1360) * 2 + (tid >> 7), e = tid & 127;
    int tk = tokens[r];
    xs[(size_t)r * 128 + e] = tok_emb[(size_t)tk * 128 + e] + pos_emb[(size_t)(r & 127) * 128 + e];
  }
}

// ---------------------------------------------------------------- EdgeNetwork GEMM (r8 exact, 163us proven)
__global__ __launch_bounds__(256) void edge_gemm_k(
    const float* __restrict__ cea, const float* __restrict__ sea,
    const int* __restrict__ cei, const int* __restrict__ sei,
    const float* __restrict__ h,
    const float* __restrict__ elw, const float* __restrict__ elb,
    float* __restrict__ aggr)
{
  __shared__ float efs[32][8];
  __shared__ float As[32][36];
  __shared__ float Bs[32][136];
  const int tid = threadIdx.x;
  const int m0 = blockIdx.x * 32;
  const int kt0 = blockIdx.y * 28;
  const int c0 = kt0 >> 2;
  {
    int t = tid >> 3, cc = tid & 7;
    if (cc < 7) {
      int c = c0 + cc;
      int m = m0 + t;
      const float* attr = (m < 4096) ? (cea + (size_t)m * 17) : (sea + (size_t)(m - 4096) * 17);
      float val;
      if (c < 16) val = attr[c];
      else if (c < 48) {
        float d = fminf(fmaxf(attr[16], 0.0f), 10.0f);
        float t2 = d - (float)((c - 16) * (5.0 / 31.0));
        val = expf(-38.44f * t2 * t2);           // gamma = (31/5)^2
      } else val = 1.0f;
      efs[t][cc] = val;
    }
  }
  const int gk = tid & 31, gt = (tid >> 5) * 4;
  float hreg[4][4];
  #pragma unroll
  for (int i = 0; i < 4; i++) {
    int m = m0 + gt + i;
    int dst = (m < 4096) ? cei[4096 + m] : (sei[1024 + (m - 4096)] + 2048);
    const float* hp = h + (size_t)dst * 128 + gk;
    hreg[i][0] = hp[0]; hreg[i][1] = hp[32]; hreg[i][2] = hp[64]; hreg[i][3] = hp[96];
  }
  const int tn = tid & 31, tm = tid >> 5;
  const int e0 = 4 * tn, t0 = 4 * tm;
  const int se = tid >> 1, sk = (tid & 1) * 16;
  float acc[4][4] = {};
  __syncthreads();
  #pragma unroll 1
  for (int kt = kt0; kt < kt0 + 28; kt++) {
    int c = kt >> 2, cc = c - c0, j = kt & 3;
    float4 av;
    av.x = efs[gt + 0][cc] * hreg[0][j];
    av.y = efs[gt + 1][cc] * hreg[1][j];
    av.z = efs[gt + 2][cc] * hreg[2][j];
    av.w = efs[gt + 3][cc] * hreg[3][j];
    *(float4*)&As[gk][gt] = av;
    const float* bp = ((c < 48) ? (elw + (size_t)c * 16384) : elb) + (size_t)se * 128 + j * 32 + sk;
    float4 w0 = *(const float4*)(bp + 0);
    float4 w1 = *(const float4*)(bp + 4);
    float4 w2 = *(const float4*)(bp + 8);
    float4 w3 = *(const float4*)(bp + 12);
    Bs[sk + 0][se] = w0.x;  Bs[sk + 1][se] = w0.y;  Bs[sk + 2][se] = w0.z;  Bs[sk + 3][se] = w0.w;
    Bs[sk + 4][se] = w1.x;  Bs[sk + 5][se] = w1.y;  Bs[sk + 6][se] = w1.z;  Bs[sk + 7][se] = w1.w;
    Bs[sk + 8][se] = w2.x;  Bs[sk + 9][se] = w2.y;  Bs[sk + 10][se] = w2.z; Bs[sk + 11][se] = w2.w;
    Bs[sk + 12][se] = w3.x; Bs[sk + 13][se] = w3.y; Bs[sk + 14][se] = w3.z; Bs[sk + 15][se] = w3.w;
    __syncthreads();
    #pragma unroll
    for (int kk = 0; kk < 32; kk++) {
      float4 a = *(const float4*)&As[kk][t0];
      float4 b = *(const float4*)&Bs[kk][e0];
      acc[0][0] += a.x * b.x; acc[0][1] += a.x * b.y; acc[0][2] += a.x * b.z; acc[0][3] += a.x * b.w;
      acc[1][0] += a.y * b.x; acc[1][1] += a.y * b.y; acc[1][2] += a.y * b.z; acc[1][3] += a.y * b.w;
      acc[2][0] += a.z * b.x; acc[2][1] += a.z * b.y; acc[2][2] += a.z * b.z; acc[2][3] += a.z * b.w;
      acc[3][0] += a.w * b.x; acc[3][1] += a.w * b.y; acc[3][2] += a.w * b.z; acc[3][3] += a.w * b.w;
    }
    __syncthreads();
  }
  #pragma unroll
  for (int i = 0; i < 4; i++) {
    int m = m0 + t0 + i;
    int src = (m < 4096) ? cei[m] : (sei[m - 4096] + 2048);
    float* dst = aggr + (size_t)src * 128 + e0;
    atomicAdd(dst + 0, acc[i][0]);
    atomicAdd(dst + 1, acc[i][1]);
    atomicAdd(dst + 2, acc[i][2]);
    atomicAdd(dst + 3, acc[i][3]);
  }
}

// ---------------------------------------------------------------- BM=16 GEMM body (K=128), barrier-staged (r8-style)
__device__ __forceinline__ void gemm16_body(G16Sm& sm,
    const float* __restrict__ A, const float* __restrict__ Bp,
    const float* __restrict__ biasp, float* __restrict__ Cp,
    int row0, int ldb, int ldc)
{
  const int tid = threadIdx.x;
  const int tm = tid >> 5, tn = tid & 31;
  const int t0 = 2 * tm, e0 = 4 * tn;
  const int ar = tid >> 4, ak = (tid & 15) * 2;
  const int bk = tid >> 3, be = (tid & 7) * 16;
  float acc[2][4] = {};
  for (int k0 = 0; k0 < 128; k0 += 32) {
    float2 av = *(const float2*)(A + (size_t)(row0 + ar) * 128 + k0 + ak);
    sm.Sa[ak][ar] = av.x; sm.Sa[ak + 1][ar] = av.y;
    const float* bp = Bp + (size_t)(k0 + bk) * ldb + be;
    float4 b0v = *(const float4*)(bp + 0);
    float4 b1v = *(const float4*)(bp + 4);
    float4 b2v = *(const float4*)(bp + 8);
    float4 b3v = *(const float4*)(bp + 12);
    sm.Bs[bk][be + 0] = b0v.x;  sm.Bs[bk][be + 1] = b0v.y;  sm.Bs[bk][be + 2] = b0v.z;  sm.Bs[bk][be + 3] = b0v.w;
    sm.Bs[bk][be + 4] = b1v.x;  sm.Bs[bk][be + 5] = b1v.y;  sm.Bs[bk][be + 6] = b1v.z;  sm.Bs[bk][be + 7] = b1v.w;
    sm.Bs[bk][be + 8] = b2v.x;  sm.Bs[bk][be + 9] = b2v.y;  sm.Bs[bk][be + 10] = b2v.z; sm.Bs[bk][be + 11] = b2v.w;
    sm.Bs[bk][be + 12] = b3v.x; sm.Bs[bk][be + 13] = b3v.y; sm.Bs[bk][be + 14] = b3v.z; sm.Bs[bk][be + 15] = b3v.w;
    __syncthreads();
    #pragma unroll
    for (int kk = 0; kk < 32; kk++) {
      float2 a = *(const float2*)&sm.Sa[kk][t0];
      float4 b = *(const float4*)&sm.Bs[kk][e0];
      acc[0][0] += a.x * b.x; acc[0][1] += a.x * b.y; acc[0][2] += a.x * b.z; acc[0][3] += a.x * b.w;
      acc[1][0] += a.y * b.x; acc[1][1] += a.y * b.y; acc[1][2] += a.y * b.z; acc[1][3] += a.y * b.w;
    }
    __syncthreads();
  }
  #pragma unroll
  for (int i = 0; i < 2; i++) {
    float* cp = Cp + (size_t)(row0 + t0 + i) * ldc + e0;
    #pragma unroll
    for (int j = 0; j < 4; j++) cp[j] = acc[i][j] + biasp[e0 + j];
  }
}

// ---------------------------------------------------------------- merged QKV: graph (3x160) + seq (3x128)
__global__ __launch_bounds__(256) void qkv_k(
    int gBlocks,
    const float* __restrict__ ghb,
    const float* gqw, const float* gkw, const float* gvw,
    const float* gqb, const float* gkb, const float* gvb, float* gout,
    const float* __restrict__ sxs, const float* sw, const float* sb, float* sout)
{
  __shared__ G16Sm sm;
  int bx = blockIdx.x;
  if (bx < gBlocks) {
    int z = bx / 160, rt = bx % 160;
    const float* B = (z == 0) ? gqw : (z == 1) ? gkw : gvw;
    const float* bias = (z == 0) ? gqb : (z == 1) ? gkb : gvb;
    gemm16_body(sm, ghb, B, bias, gout + (size_t)z * 327680, rt * 16, 128, 128);
  } else {
    int i = bx - gBlocks;
    int z = i >> 7, rt = i & 127;
    gemm16_body(sm, sxs, sw + z * 128, sb + z * 128, sout + z * 128, rt * 16, 384, 384);
  }
}

// ---------------------------------------------------------------- graph attention body (N=32, GD=16)
__device__ __forceinline__ void gattn_body(GAttnSm& sm, int g, int h,
    const float* __restrict__ q, const float* __restrict__ k,
    const float* __restrict__ v, const float* __restrict__ dist, float* __restrict__ o)
{
  const int tid = threadIdx.x;
  {
    int idx = tid * 2;
    int i = idx >> 4, d = idx & 15;
    size_t base = ((size_t)(g * 32 + i)) * 128 + h * 16 + d;
    sm.qs[i][d] = q[base];  sm.qs[i][d + 1] = q[base + 1];
    sm.ksh[i][d] = k[base]; sm.ksh[i][d + 1] = k[base + 1];
    sm.vsh[i][d] = v[base]; sm.vsh[i][d + 1] = v[base + 1];
  }
  __syncthreads();
  {
    int i = tid >> 3, j0 = (tid & 7) * 4;
    for (int j = j0; j < j0 + 4; j++) {
      float a = 0;
      #pragma unroll
      for (int d = 0; d < 16; d++) a += sm.qs[i][d] * sm.ksh[j][d];
      a = a * 0.25f + dist[(size_t)g * 1024 + i * 32 + j];
      sm.ss[i][j] = fminf(fmaxf(a, -10.0f), 10.0f);
    }
  }
  __syncthreads();
  if (tid < 32) {
    float m = -1e30f;
    for (int j = 0; j < 32; j++) m = fmaxf(m, sm.ss[tid][j]);
    float s = 0;
    for (int j = 0; j < 32; j++) { float ex = expf(sm.ss[tid][j] - m); sm.ss[tid][j] = ex; s += ex; }
    sm.rs[tid] = 1.0f / s;
  }
  __syncthreads();
  {
    int idx = tid * 2;
    int i = idx >> 4, d = idx & 15;
    float a0 = 0, a1 = 0;
    for (int j = 0; j < 32; j++) { float wj = sm.ss[i][j]; a0 += wj * sm.vsh[j][d]; a1 += wj * sm.vsh[j][d + 1]; }
    float r = sm.rs[i];
    size_t base = ((size_t)(g * 32 + i)) * 128 + h * 16 + d;
    o[base] = a0 * r; o[base + 1] = a1 * r;
  }
}

// ---------------------------------------------------------------- seq attention body (slim, K/V tiled; r12-verified)
__device__ __forceinline__ void sattn_body(SAttnSm& sm, int b, int h, int qt,
    const float* __restrict__ qkv, float* __restrict__ o)
{
  const int tid = threadIdx.x;
  {
    int i = tid >> 3, d0 = (tid & 7) * 4;
    const float* qp = qkv + ((size_t)(b * 128 + qt * 32 + i)) * 384 + h * 32 + d0;
    sm.qs2[i][d0 + 0] = qp[0]; sm.qs2[i][d0 + 1] = qp[1];
    sm.qs2[i][d0 + 2] = qp[2]; sm.qs2[i][d0 + 3] = qp[3];
  }
  const int i = tid >> 3, sub = tid & 7;
  for (int jt = 0; jt < 4; jt++) {
    {
      int r = tid >> 3, dd = (tid & 7) * 4;
      const float* kp = qkv + ((size_t)(b * 128 + jt * 32 + r)) * 384 + 128 + h * 32 + dd;
      float4 kv4 = *(const float4*)kp;
      sm.kv[r][dd + 0] = kv4.x; sm.kv[r][dd + 1] = kv4.y;
      sm.kv[r][dd + 2] = kv4.z; sm.kv[r][dd + 3] = kv4.w;
    }
    __syncthreads();
    {
      int j0 = jt * 32 + sub * 4;
      for (int j = j0; j < j0 + 4; j++) {
        int jr = j - jt * 32;
        float a = 0;
        #pragma unroll
        for (int d = 0; d < 32; d++) a += sm.qs2[i][d] * sm.kv[jr][d];
        sm.ss2[i][j] = a * 0.17677669529663687f;
      }
    }
    __syncthreads();
  }
  float m = -1e30f;
  for (int j = sub; j < 128; j += 8) m = fmaxf(m, sm.ss2[i][j]);
  sm.red[i][sub] = m;
  __syncthreads();
  float mm = sm.red[i][0];
  #pragma unroll
  for (int t = 1; t < 8; t++) mm = fmaxf(mm, sm.red[i][t]);
  float ps = 0;
  for (int j = sub; j < 128; j += 8) { float ex = expf(sm.ss2[i][j] - mm); sm.ss2[i][j] = ex; ps += ex; }
  sm.red2[i][sub] = ps;
  __syncthreads();
  float s = 0;
  #pragma unroll
  for (int t = 0; t < 8; t++) s += sm.red2[i][t];
  float rinv = 1.0f / s;
  float a0 = 0, a1 = 0, a2 = 0, a3 = 0;
  const int d0 = sub * 4;
  for (int jt = 0; jt < 4; jt++) {
    __syncthreads();
    {
      int r = tid >> 3, dd = (tid & 7) * 4;
      const float* vp = qkv + ((size_t)(b * 128 + jt * 32 + r)) * 384 + 256 + h * 32 + dd;
      float4 vv = *(const float4*)vp;
      sm.kv[r][dd + 0] = vv.x; sm.kv[r][dd + 1] = vv.y;
      sm.kv[r][dd + 2] = vv.z; sm.kv[r][dd + 3] = vv.w;
    }
    __syncthreads();
    for (int jr = 0; jr < 32; jr++) {
      float wj = sm.ss2[i][jt * 32 + jr];
      a0 += wj * sm.kv[jr][d0 + 0]; a1 += wj * sm.kv[jr][d0 + 1];
      a2 += wj * sm.kv[jr][d0 + 2]; a3 += wj * sm.kv[jr][d0 + 3];
    }
  }
  float* op = o + ((size_t)(b * 128 + qt * 32 + i)) * 128 + h * 32 + d0;
  op[0] = a0 * rinv; op[1] = a1 * rinv; op[2] = a2 * rinv; op[3] = a3 * rinv;
}

// ---------------------------------------------------------------- merged attention: graph + seq (union LDS)
__global__ __launch_bounds__(256) void attn_k(
    int gBlocks, const float* q, const float* k, const float* v,
    const float* dist, float* go, const float* qkv, float* so)
{
  __shared__ AttnU u;
  int bx = blockIdx.x;
  if (bx < gBlocks) gattn_body(u.a, bx >> 3, bx & 7, q, k, v, dist, go);
  else { int i = bx - gBlocks; sattn_body(u.s, i >> 4, (i >> 2) & 3, i & 3, qkv, so); }
}

// ---------------------------------------------------------------- layer tail body (r11-verified barrier-staged)
__device__ __forceinline__ void tail_body(TailSm& sm, int row0, const float* __restrict__ A,
    const float* __restrict__ Wo, const float* __restrict__ bo, const float* __restrict__ res,
    const float* __restrict__ g1, const float* __restrict__ b1n,
    const float* __restrict__ W1, const float* __restrict__ b1f,
    const float* __restrict__ W2, const float* __restrict__ b2f,
    const float* __restrict__ g2, const float* __restrict__ b2n,
    float* __restrict__ Out)
{
  float (*BsA)[136] = (float(*)[136])sm.sbuf;
  float (*Bs1)[260] = (float(*)[260])sm.sbuf;
  float (*Bs2)[136] = (float(*)[136])sm.sbuf;
  const int tid = threadIdx.x;
  // ---- stage A: x1 = LN(A@Wo + bo + res) ----
  {
    const int tm = tid >> 5, tn = tid & 31;
    const int t0 = 2 * tm, e0 = 4 * tn;
    const int ar = tid >> 4, ak = (tid & 15) * 2;
    const int bk = tid >> 3, be = (tid & 7) * 16;
    float acc[2][4] = {};
    for (int k0 = 0; k0 < 128; k0 += 32) {
      float2 av = *(const float2*)(A + (size_t)(row0 + ar) * 128 + k0 + ak);
      sm.Sa[ak][ar] = av.x; sm.Sa[ak + 1][ar] = av.y;
      const float* bp = Wo + (size_t)(k0 + bk) * 128 + be;
      float4 b0v = *(const float4*)(bp + 0);
      float4 b1v = *(const float4*)(bp + 4);
      float4 b2v = *(const float4*)(bp + 8);
      float4 b3v = *(const float4*)(bp + 12);
      BsA[bk][be + 0] = b0v.x;  BsA[bk][be + 1] = b0v.y;  BsA[bk][be + 2] = b0v.z;  BsA[bk][be + 3] = b0v.w;
      BsA[bk][be + 4] = b1v.x;  BsA[bk][be + 5] = b1v.y;  BsA[bk][be + 6] = b1v.z;  BsA[bk][be + 7] = b1v.w;
      BsA[bk][be + 8] = b2v.x;  BsA[bk][be + 9] = b2v.y;  BsA[bk][be + 10] = b2v.z; BsA[bk][be + 11] = b2v.w;
      BsA[bk][be + 12] = b3v.x; BsA[bk][be + 13] = b3v.y; BsA[bk][be + 14] = b3v.z; BsA[bk][be + 15] = b3v.w;
      __syncthreads();
      #pragma unroll
      for (int kk = 0; kk < 32; kk++) {
        float2 a = *(const float2*)&sm.Sa[kk][t0];
        float4 b = *(const float4*)&BsA[kk][e0];
        acc[0][0] += a.x * b.x; acc[0][1] += a.x * b.y; acc[0][2] += a.x * b.z; acc[0][3] += a.x * b.w;
        acc[1][0] += a.y * b.x; acc[1][1] += a.y * b.y; acc[1][2] += a.y * b.z; acc[1][3] += a.y * b.w;
      }
      __syncthreads();
    }
    #pragma unroll
    for (int i = 0; i < 2; i++) {
      int r = row0 + t0 + i;
      float v0 = acc[i][0] + bo[e0 + 0] + res[(size_t)r * 128 + e0 + 0];
      float v1 = acc[i][1] + bo[e0 + 1] + res[(size_t)r * 128 + e0 + 1];
      float v2 = acc[i][2] + bo[e0 + 2] + res[(size_t)r * 128 + e0 + 2];
      float v3 = acc[i][3] + bo[e0 + 3] + res[(size_t)r * 128 + e0 + 3];
      float s = v0 + v1 + v2 + v3;
      #pragma unroll
      for (int o = 1; o < 32; o <<= 1) s += __shfl_xor(s, o);
      float mean = s * (1.0f / 128.0f);
      float d0 = v0 - mean, d1 = v1 - mean, d2 = v2 - mean, d3 = v3 - mean;
      float sq = d0 * d0 + d1 * d1 + d2 * d2 + d3 * d3;
      #pragma unroll
      for (int o = 1; o < 32; o <<= 1) sq += __shfl_xor(sq, o);
      float rstd = 1.0f / sqrtf(sq * (1.0f / 128.0f) + 1e-5f);
      sm.x1[t0 + i][e0 + 0] = d0 * rstd * g1[e0 + 0] + b1n[e0 + 0];
      sm.x1[t0 + i][e0 + 1] = d1 * rstd * g1[e0 + 1] + b1n[e0 + 1];
      sm.x1[t0 + i][e0 + 2] = d2 * rstd * g1[e0 + 2] + b1n[e0 + 2];
      sm.x1[t0 + i][e0 + 3] = d3 * rstd * g1[e0 + 3] + b1n[e0 + 3];
    }
  }
  __syncthreads();
  // ---- stage B: hid = relu(x1 @ W1 + b1f), 16x256 ----
  {
    const int tm = tid >> 6, tn = tid & 63;
    const int t0 = 4 * tm, e0 = 4 * tn;
    const int ar = tid >> 4, ak = tid & 15;
    const int bk = tid >> 4, be = (tid & 15) * 16;
    float acc[4][4] = {};
    for (int k0 = 0; k0 < 128; k0 += 16) {
      sm.Sa[ak][ar] = sm.x1[ar][k0 + ak];
      const float* bp = W1 + (size_t)(k0 + bk) * 256 + be;
      float4 b0v = *(const float4*)(bp + 0);
      float4 b1v = *(const float4*)(bp + 4);
      float4 b2v = *(const float4*)(bp + 8);
      float4 b3v = *(const float4*)(bp + 12);
      Bs1[bk][be + 0] = b0v.x;  Bs1[bk][be + 1] = b0v.y;  Bs1[bk][be + 2] = b0v.z;  Bs1[bk][be + 3] = b0v.w;
      Bs1[bk][be + 4] = b1v.x;  Bs1[bk][be + 5] = b1v.y;  Bs1[bk][be + 6] = b1v.z;  Bs1[bk][be + 7] = b1v.w;
      Bs1[bk][be + 8] = b2v.x;  Bs1[bk][be + 9] = b2v.y;  Bs1[bk][be + 10] = b2v.z; Bs1[bk][be + 11] = b2v.w;
      Bs1[bk][be + 12] = b3v.x; Bs1[bk][be + 13] = b3v.y; Bs1[bk][be + 14] = b3v.z; Bs1[bk][be + 15] = b3v.w;
      __syncthreads();
      #pragma unroll
      for (int kk = 0; kk < 16; kk++) {
        float4 a = *(const float4*)&sm.Sa[kk][t0];
        float4 b = *(const float4*)&Bs1[kk][e0];
        acc[0][0] += a.x * b.x; acc[0][1] += a.x * b.y; acc[0][2] += a.x * b.z; acc[0][3] += a.x * b.w;
        acc[1][0] += a.y * b.x; acc[1][1] += a.y * b.y; acc[1][2] += a.y * b.z; acc[1][3] += a.y * b.w;
        acc[2][0] += a.z * b.x; acc[2][1] += a.z * b.y; acc[2][2] += a.z * b.z; acc[2][3] += a.z * b.w;
        acc[3][0] += a.w * b.x; acc[3][1] += a.w * b.y; acc[3][2] += a.w * b.z; acc[3][3] += a.w * b.w;
      }
      __syncthreads();
    }
    #pragma unroll
    for (int i = 0; i < 4; i++) {
      float4 hv;
      hv.x = fmaxf(acc[i][0] + b1f[e0 + 0], 0.0f);
      hv.y = fmaxf(acc[i][1] + b1f[e0 + 1], 0.0f);
      hv.z = fmaxf(acc[i][2] + b1f[e0 + 2], 0.0f);
      hv.w = fmaxf(acc[i][3] + b1f[e0 + 3], 0.0f);
      *(float4*)&sm.hid[t0 + i][e0] = hv;
    }
  }
  __syncthreads();
  // ---- stage C: Out = LN(hid@W2 + b2f + x1) ----
  {
    const int tm = tid >> 5, tn = tid & 31;
    const int t0 = 2 * tm, e0 = 4 * tn;
    const int bk = tid >> 3, be = (tid & 7) * 16;
    float acc[2][4] = {};
    for (int k0 = 0; k0 < 256; k0 += 32) {
      const float* bp = W2 + (size_t)(k0 + bk) * 128 + be;
      float4 b0v = *(const float4*)(bp + 0);
      float4 b1v = *(const float4*)(bp + 4);
      float4 b2v = *(const float4*)(bp + 8);
      float4 b3v = *(const float4*)(bp + 12);
      Bs2[bk][be + 0] = b0v.x;  Bs2[bk][be + 1] = b0v.y;  Bs2[bk][be + 2] = b0v.z;  Bs2[bk][be + 3] = b0v.w;
      Bs2[bk][be + 4] = b1v.x;  Bs2[bk][be + 5] = b1v.y;  Bs2[bk][be + 6] = b1v.z;  Bs2[bk][be + 7] = b1v.w;
      Bs2[bk][be + 8] = b2v.x;  Bs2[bk][be + 9] = b2v.y;  Bs2[bk][be + 10] = b2v.z; Bs2[bk][be + 11] = b2v.w;
      Bs2[bk][be + 12] = b3v.x; Bs2[bk][be + 13] = b3v.y; Bs2[bk][be + 14] = b3v.z; Bs2[bk][be + 15] = b3v.w;
      __syncthreads();
      #pragma unroll
      for (int kk = 0; kk < 32; kk++) {
        float a0 = sm.hid[t0 + 0][k0 + kk];
        float a1 = sm.hid[t0 + 1][k0 + kk];
        float4 b = *(const float4*)&Bs2[kk][e0];
        acc[0][0] += a0 * b.x; acc[0][1] += a0 * b.y; acc[0][2] += a0 * b.z; acc[0][3] += a0 * b.w;
        acc[1][0] += a1 * b.x; acc[1][1] += a1 * b.y; acc[1][2] += a1 * b.z; acc[1][3] += a1 * b.w;
      }
      __syncthreads();
    }
    #pragma unroll
    for (int i = 0; i < 2; i++) {
      int r = row0 + t0 + i;
      float v0 = acc[i][0] + b2f[e0 + 0] + sm.x1[t0 + i][e0 + 0];
      float v1 = acc[i][1] + b2f[e0 + 1] + sm.x1[t0 + i][e0 + 1];
      float v2 = acc[i][2] + b2f[e0 + 2] + sm.x1[t0 + i][e0 + 2];
      float v3 = acc[i][3] + b2f[e0 + 3] + sm.x1[t0 + i][e0 + 3];
      float s = v0 + v1 + v2 + v3;
      #pragma unroll
      for (int o = 1; o < 32; o <<= 1) s += __shfl_xor(s, o);
      float mean = s * (1.0f / 128.0f);
      float d0 = v0 - mean, d1 = v1 - mean, d2 = v2 - mean, d3 = v3 - mean;
      float sq = d0 * d0 + d1 * d1 + d2 * d2 + d3 * d3;
      #pragma unroll
      for (int o = 1; o < 32; o <<= 1) sq += __shfl_xor(sq, o);
      float rstd = 1.0f / sqrtf(sq * (1.0f / 128.0f) + 1e-5f);
      float* cp = Out + (size_t)r * 128 + e0;
      cp[0] = d0 * rstd * g2[e0 + 0] + b2n[e0 + 0];
      cp[1] = d1 * rstd * g2[e0 + 1] + b2n[e0 + 1];
      cp[2] = d2 * rstd * g2[e0 + 2] + b2n[e0 + 2];
      cp[3] = d3 * rstd * g2[e0 + 3] + b2n[e0 + 3];
    }
  }
}

// ---------------------------------------------------------------- merged tail: graph + seq
__global__ __launch_bounds__(256) void tail_k(
    int gBlocks,
    const float* gA, const float* gWo, const float* gbo, const float* gres,
    const float* gg1, const float* gb1, const float* gW1, const float* gbf1,
    const float* gW2, const float* gbf2, const float* gg2, const float* gb2, float* gOut,
    const float* sA, const float* sWo, const float* sbo, const float* sres,
    const float* sg1, const float* sb1, const float* sW1, const float* sbf1,
    const float* sW2, const float* sbf2, const float* sg2, const float* sb2, float* sOut)
{
  __shared__ TailSm sm;
  int bx = blockIdx.x;
  if (bx < gBlocks)
    tail_body(sm, bx * 16, gA, gWo, gbo, gres, gg1, gb1, gW1, gbf1, gW2, gbf2, gg2, gb2, gOut);
  else
    tail_body(sm, (bx - gBlocks) * 16, sA, sWo, sbo, sres, sg1, sb1, sW1, sbf1, sW2, sbf2, sg2, sb2, sOut);
}

// ---------------------------------------------------------------- LayerNorm rows of 128 (after edge aggr)
__global__ __launch_bounds__(128) void ln_k(
    const float* __restrict__ x, const float* __restrict__ res,
    const float* __restrict__ g, const float* __restrict__ b, float* __restrict__ out)
{
  __shared__ float sred[2];
  int r = blockIdx.x, e = threadIdx.x;
  size_t idx = (size_t)r * 128 + e;
  float v = x[idx] + res[idx];
  float nv = blk_norm(v, e, sred);
  out[idx] = nv * g[e] + b[e];
}

// ---------------------------------------------------------------- pool + smean + fusion + cross-modal + head
__global__ __launch_bounds__(128) void head_k(
    const float* __restrict__ hb, const float* __restrict__ xs, const float* __restrict__ gfeat,
    const float* fg1w, const float* fg1b, const float* fg2w, const float* fg2b,
    const float* g2s_vw, const float* g2s_vb, const float* g2s_ow, const float* g2s_ob,
    const float* n1g, const float* n1b,
    const float* s2g_vw, const float* s2g_vb, const float* s2g_ow, const float* s2g_ob,
    const float* n2g, const float* n2b,
    const float* r1w, const float* r1b, const float* r2w, const float* r2b,
    float* __restrict__ out)
{
  __shared__ float T[128], S[128], G[128], Sm[128], t1[128], t2[128], gh[64], sred[2];
  int mol = blockIdx.x, e = threadIdx.x;
  {
    float cs = 0;
    for (int c = 0; c < 4; c++) {
      int g = mol * 4 + c;
      float s = 0;
      for (int i = 0; i < 32; i++) s += hb[((size_t)(g * 32 + i)) * 128 + e];
      cs += s * (1.0f / 32.0f);
    }
    cs *= 0.25f;
    float s2 = 0;
    int g = 64 + mol;
    for (int i = 0; i < 32; i++) s2 += hb[((size_t)(g * 32 + i)) * 128 + e];
    T[e] = cs + s2 * (1.0f / 32.0f);
    float ss = 0;
    for (int l = 0; l < 128; l++) ss += xs[((size_t)(mol * 128 + l)) * 128 + e];
    S[e] = ss * (1.0f / 128.0f);
  }
  __syncthreads();
  if (e < 64) {
    float a = fg1b[e];
    for (int f = 0; f < 128; f++) a += T[f] * fg1w[f * 64 + e];
    for (int f = 0; f < 128; f++) a += S[f] * fg1w[(128 + f) * 64 + e];
    gh[e] = fmaxf(a, 0.0f);
  }
  __syncthreads();
  {
    float a = fg2b[e];
    for (int j = 0; j < 64; j++) a += gh[j] * fg2w[j * 128 + e];
    float gate = 1.0f / (1.0f + expf(-a));
    float fu = gate * T[e] + (1.0f - gate) * S[e];
    G[e] = fu; Sm[e] = fu;
  }
  __syncthreads();
  for (int l = 0; l < 2; l++) {
    const float* vw = g2s_vw + (size_t)l * 16384; const float* vb = g2s_vb + l * 128;
    const float* ow = g2s_ow + (size_t)l * 16384; const float* ob = g2s_ob + l * 128;
    float a = vb[e];
    for (int f = 0; f < 128; f++) a += Sm[f] * vw[f * 128 + e];
    t1[e] = a;
    __syncthreads();
    a = ob[e];
    for (int f = 0; f < 128; f++) a += t1[f] * ow[f * 128 + e];
    float nv = blk_norm(G[e] + a, e, sred);
    G[e] = nv * n1g[l * 128 + e] + n1b[l * 128 + e];
    __syncthreads();
    const float* vw2 = s2g_vw + (size_t)l * 16384; const float* vb2 = s2g_vb + l * 128;
    const float* ow2 = s2g_ow + (size_t)l * 16384; const float* ob2 = s2g_ob + l * 128;
    a = vb2[e];
    for (int f = 0; f < 128; f++) a += G[f] * vw2[f * 128 + e];
    t1[e] = a;
    __syncthreads();
    a = ob2[e];
    for (int f = 0; f < 128; f++) a += t1[f] * ow2[f * 128 + e];
    nv = blk_norm(Sm[e] + a, e, sred);
    Sm[e] = nv * n2g[l * 128 + e] + n2b[l * 128 + e];
    __syncthreads();
  }
  t2[e] = 0.5f * (G[e] + Sm[e]);
  __syncthreads();
  float a = r1b[e];
  for (int f = 0; f < 128; f++) a += t2[f] * r1w[f * 128 + e];
  for (int f = 0; f < 3; f++) a += gfeat[mol * 3 + f] * r1w[(128 + f) * 128 + e];
  a = fmaxf(a, 0.0f);
  float p = a * r2w[e];
  #pragma unroll
  for (int o = 1; o < 64; o <<= 1) p += __shfl_xor(p, o);
  if ((e & 63) == 0) sred[e >> 6] = p;
  __syncthreads();
  if (e == 0) out[mol] = sred[0] + sred[1] + r2b[0];
}

// ================================================================ host
extern "C" void kernel_launch(void* const* d_in, const int* in_sizes, int n_in,
                              void* d_out, int out_size, void* d_ws, size_t ws_size,
                              hipStream_t stream)
{
  (void)n_in; (void)out_size; (void)ws_size;
  const bool dict = (in_sizes[1] == 8192);
  auto IN = [&](int di, int si) { return d_in[dict ? di : si]; };

  const float* conf_x   = (const float*)IN(0, 0);
  const int*   conf_ei  = (const int*)  IN(1, 63);
  const float* conf_ea  = (const float*)IN(2, 1);
  const float* conf_pos = (const float*)IN(3, 2);
  const float* scaf_x   = (const float*)IN(4, 3);
  const int*   scaf_ei  = (const int*)  IN(5, 64);
  const float* scaf_ea  = (const float*)IN(6, 4);
  const float* scaf_pos = (const float*)IN(7, 5);
  const int*   tokens   = (const int*)  IN(8, 65);
  const float* gfeat    = (const float*)IN(9, 6);
  const float* gproj_w  = (const float*)IN(11, 7);
  const float* gproj_b  = (const float*)IN(12, 8);
  const float* elin_w   = (const float*)IN(13, 9);
  const float* elin_b   = (const float*)IN(14, 10);
  const float* eln_g    = (const float*)IN(15, 11);
  const float* eln_b    = (const float*)IN(16, 12);
  const float* gt_qw    = (const float*)IN(17, 13);
  const float* gt_qb    = (const float*)IN(18, 14);
  const float* gt_kw    = (const float*)IN(19, 15);
  const float* gt_kb    = (const float*)IN(20, 16);
  const float* gt_vw    = (const float*)IN(21, 17);
  const float* gt_vb    = (const float*)IN(22, 18);
  const float* gt_ow    = (const float*)IN(23, 19);
  const float* gt_ob    = (const float*)IN(24, 20);
  const float* gt_ln1g  = (const float*)IN(25, 21);
  const float* gt_ln1b  = (const float*)IN(26, 22);
  const float* gt_f1w   = (const float*)IN(27, 23);
  const float* gt_f1b   = (const float*)IN(28, 24);
  const float* gt_f2w   = (const float*)IN(29, 25);
  const float* gt_f2b   = (const float*)IN(30, 26);
  const float* gt_ln2g  = (const float*)IN(31, 27);
  const float* gt_ln2b  = (const float*)IN(32, 28);
  const float* tok_emb  = (const float*)IN(33, 29);
  const float* pos_emb  = (const float*)IN(34, 30);
  const float* se_inw   = (const float*)IN(35, 31);
  const float* se_inb   = (const float*)IN(36, 32);
  const float* se_ow    = (const float*)IN(37, 33);
  const float* se_ob    = (const float*)IN(38, 34);
  const float* se_ln1g  = (const float*)IN(39, 35);
  const float* se_ln1b  = (const float*)IN(40, 36);
  const float* se_f1w   = (const float*)IN(41, 37);
  const float* se_f1b   = (const float*)IN(42, 38);
  const float* se_f2w   = (const float*)IN(43, 39);
  const float* se_f2b   = (const float*)IN(44, 40);
  const float* se_ln2g  = (const float*)IN(45, 41);
  const float* se_ln2b  = (const float*)IN(46, 42);
  const float* fg1_w    = (const float*)IN(47, 43);
  const float* fg1_b    = (const float*)IN(48, 44);
  const float* fg2_w    = (const float*)IN(49, 45);
  const float* fg2_b    = (const float*)IN(50, 46);
  const float* cm_g2s_vw = (const float*)IN(51, 47);
  const float* cm_g2s_vb = (const float*)IN(52, 48);
  const float* cm_g2s_ow = (const float*)IN(53, 49);
  const float* cm_g2s_ob = (const float*)IN(54, 50);
  const float* cm_s2g_vw = (const float*)IN(55, 53);
  const float* cm_s2g_vb = (const float*)IN(56, 54);
  const float* cm_s2g_ow = (const float*)IN(57, 55);
  const float* cm_s2g_ob = (const float*)IN(58, 56);
  const float* cm_n1g   = (const float*)IN(59, 51);
  const float* cm_n1b   = (const float*)IN(60, 52);
  const float* cm_n2g   = (const float*)IN(61, 57);
  const float* cm_n2b   = (const float*)IN(62, 58);
  const float* r1_w     = (const float*)IN(63, 59);
  const float* r1_b     = (const float*)IN(64, 60);
  const float* r2_w     = (const float*)IN(65, 61);
  const float* r2_b     = (const float*)IN(66, 62);
  float* out = (float*)d_out;

  // ---- workspace (fp32) ----
  float* w = (float*)d_ws;
  size_t off = 0;
  auto alloc = [&](size_t n) { float* p = w + off; off += n; return p; };
  float* h     = alloc(2560 * 128);
  float* aggr  = alloc(2560 * 128);
  float* hb    = alloc(2560 * 128);
  float* distb = alloc(80 * 1024);
  float* qb    = alloc(3 * 327680);     // graph q/k/v
  float* atto  = alloc(327680);
  float* xs2   = alloc(2048 * 128);
  float* qkv3  = alloc(2048 * 384);
  float* satto = alloc(2048 * 128);
  float* xsfin = alloc(2048 * 128);

  // front (node_proj + zero aggr + dist + embed)
  front_k<<<2384, 256, 0, stream>>>(conf_x, scaf_x, gproj_w, gproj_b, h, aggr,
                                    conf_pos, scaf_pos, distb,
                                    tokens, tok_emb, pos_emb, xs2);
  edge_gemm_k<<<dim3(160, 7), 256, 0, stream>>>(conf_ea, scaf_ea, conf_ei, scaf_ei, h, elin_w, elin_b, aggr);
  ln_k<<<2560, 128, 0, stream>>>(aggr, h, eln_g, eln_b, hb);

  // merged graph(3) + seq(4) transformer layers
  for (int l = 0; l < 4; l++) {
    const bool hasG = (l < 3);
    const int lg = hasG ? l : 0;
    const int gq = hasG ? 480 : 0;
    const int ga = hasG ? 640 : 0;
    const int gt = hasG ? 160 : 0;
    float* sOut = (l == 3) ? xsfin : xs2;
    qkv_k<<<gq + 384, 256, 0, stream>>>(gq,
        hb, gt_qw + (size_t)lg * 16384, gt_kw + (size_t)lg * 16384, gt_vw + (size_t)lg * 16384,
        gt_qb + lg * 128, gt_kb + lg * 128, gt_vb + lg * 128, qb,
        xs2, se_inw + (size_t)l * 49152, se_inb + l * 384, qkv3);
    attn_k<<<ga + 256, 256, 0, stream>>>(ga, qb, qb + 327680, qb + 655360, distb, atto, qkv3, satto);
    tail_k<<<gt + 128, 256, 0, stream>>>(gt,
        atto, gt_ow + (size_t)lg * 16384, gt_ob + lg * 128, hb,
        gt_ln1g + lg * 128, gt_ln1b + lg * 128,
        gt_f1w + (size_t)lg * 32768, gt_f1b + lg * 256,
        gt_f2w + (size_t)lg * 32768, gt_f2b + lg * 128,
        gt_ln2g + lg * 128, gt_ln2b + lg * 128, hb,
        satto, se_ow + (size_t)l * 16384, se_ob + l * 128, xs2,
        se_ln1g + l * 128, se_ln1b + l * 128,
        se_f1w + (size_t)l * 32768, se_f1b + l * 256,
        se_f2w + (size_t)l * 32768, se_f2b + l * 128,
        se_ln2g + l * 128, se_ln2b + l * 128, sOut);
  }

  // head
  head_k<<<16, 128, 0, stream>>>(hb, xsfin, gfeat,
                                 fg1_w, fg1_b, fg2_w, fg2_b,
                                 cm_g2s_vw, cm_g2s_vb, cm_g2s_ow, cm_g2s_ob, cm_n1g, cm_n1b,
                                 cm_s2g_vw, cm_s2g_vb, cm_s2g_ow, cm_s2g_ob, cm_n2g, cm_n2b,
                                 r1_w, r1_b, r2_w, r2_b, out);
}

// Round 14
// 554.432 us; speedup vs baseline: 1.3776x; 1.1338x over previous
//
#include <hip/hip_runtime.h>
#include <hip/hip_bf16.h>

// E=128 GH=8 GD=16 GL=3 | SH=4 SD=32 SL=4 | N=32 GC=64 GS=16 DEG=64 BMOL=16
// M_conf=4096 M_scaf=1024 M_tot=5120. All float tensors fp32.
// r13 base (628us) + factorized edge path: G[n] = W_all @ h[n] (half FLOPs) + rank-49 combine.
// Factorized path needs 64MB extra ws; falls back to r8 edge kernel if ws_size too small.

// ---------------------------------------------------------------- shared-mem structs
struct __align__(16) G16Sm   { float Sa[32][20]; float Bs[32][136]; };
struct __align__(16) GAttnSm { float qs[32][17], ksh[32][17], vsh[32][17], ss[32][33], rs[32]; };
struct __align__(16) SAttnSm { float kv[32][33], qs2[32][33], ss2[32][129], red[32][8], red2[32][8]; };
struct __align__(16) TailSm  { float x1[16][132]; float hid[16][260]; float sbuf[4352]; float Sa[32][20]; };
union AttnU { GAttnSm a; SAttnSm s; };

// ---------------------------------------------------------------- LN helper (block of 128 threads)
__device__ __forceinline__ float blk_norm(float v, int e, float* sred)
{
  float s = v;
  #pragma unroll
  for (int o = 1; o < 64; o <<= 1) s += __shfl_xor(s, o);
  if ((e & 63) == 0) sred[e >> 6] = s;
  __syncthreads();
  float mean = (sred[0] + sred[1]) * (1.0f / 128.0f);
  __syncthreads();
  float d = v - mean;
  float s2 = d * d;
  #pragma unroll
  for (int o = 1; o < 64; o <<= 1) s2 += __shfl_xor(s2, o);
  if ((e & 63) == 0) sred[e >> 6] = s2;
  __syncthreads();
  float var = (sred[0] + sred[1]) * (1.0f / 128.0f);
  __syncthreads();
  return d / sqrtf(var + 1e-5f);
}

// ---------------------------------------------------------------- merged front-end (r8, proven)
__global__ __launch_bounds__(256) void front_k(
    const float* __restrict__ cx, const float* __restrict__ sx,
    const float* __restrict__ w, const float* __restrict__ b,
    float* __restrict__ h, float* __restrict__ aggr,
    const float* __restrict__ cpos, const float* __restrict__ spos, float* __restrict__ dist,
    const int* __restrict__ tokens, const float* __restrict__ tok_emb,
    const float* __restrict__ pos_emb, float* __restrict__ xs)
{
  __shared__ float sP[128];
  const int bx = blockIdx.x, tid = threadIdx.x;
  if (bx < 1280) {
    int r = bx * 2 + (tid >> 7), e = tid & 127;
    const float* x = (r < 2048) ? (cx + (size_t)r * 64) : (sx + (size_t)(r - 2048) * 64);
    float* xrow = sP + (tid >> 7) * 64;
    if (e < 64) xrow[e] = x[e];
    __syncthreads();
    float acc = b[e];
    for (int a = 0; a < 64; a++) acc += xrow[a] * w[a * 128 + e];
    h[(size_t)r * 128 + e] = acc;
    aggr[(size_t)r * 128 + e] = 0.0f;
  } else if (bx < 1360) {
    int g = bx - 1280;
    const float* p = (g < 64) ? (cpos + (size_t)g * 96) : (spos + (size_t)(g - 64) * 96);
    if (tid < 96) sP[tid] = p[tid];
    __syncthreads();
    #pragma unroll
    for (int jj = 0; jj < 4; jj++) {
      int idx = tid * 4 + jj;
      int i = idx >> 5, j = idx & 31;
      float dx = sP[i * 3 + 0] - sP[j * 3 + 0];
      float dy = sP[i * 3 + 1] - sP[j * 3 + 1];
      float dz = sP[i * 3 + 2] - sP[j * 3 + 2];
      float d2 = dx * dx + dy * dy + dz * dz;
      dist[(size_t)g * 1024 + idx] = (d2 > 0.0f) ? sqrtf(d2) : 0.0f;
    }
  } else {
    int r = (bx - 1360) * 2 + (tid >> 7), e = tid & 127;
    int tk = tokens[r];
    xs[(size_t)r * 128 + e] = tok_emb[(size_t)tk * 128 + e] + pos_emb[(size_t)(r & 127) * 128 + e];
  }
}

// ---------------------------------------------------------------- EdgeNetwork GEMM (r8 exact — fallback path)
__global__ __launch_bounds__(256) void edge_gemm_k(
    const float* __restrict__ cea, const float* __restrict__ sea,
    const int* __restrict__ cei, const int* __restrict__ sei,
    const float* __restrict__ h,
    const float* __restrict__ elw, const float* __restrict__ elb,
    float* __restrict__ aggr)
{
  __shared__ float efs[32][8];
  __shared__ float As[32][36];
  __shared__ float Bs[32][136];
  const int tid = threadIdx.x;
  const int m0 = blockIdx.x * 32;
  const int kt0 = blockIdx.y * 28;
  const int c0 = kt0 >> 2;
  {
    int t = tid >> 3, cc = tid & 7;
    if (cc < 7) {
      int c = c0 + cc;
      int m = m0 + t;
      const float* attr = (m < 4096) ? (cea + (size_t)m * 17) : (sea + (size_t)(m - 4096) * 17);
      float val;
      if (c < 16) val = attr[c];
      else if (c < 48) {
        float d = fminf(fmaxf(attr[16], 0.0f), 10.0f);
        float t2 = d - (float)((c - 16) * (5.0 / 31.0));
        val = expf(-38.44f * t2 * t2);           // gamma = (31/5)^2
      } else val = 1.0f;
      efs[t][cc] = val;
    }
  }
  const int gk = tid & 31, gt = (tid >> 5) * 4;
  float hreg[4][4];
  #pragma unroll
  for (int i = 0; i < 4; i++) {
    int m = m0 + gt + i;
    int dst = (m < 4096) ? cei[4096 + m] : (sei[1024 + (m - 4096)] + 2048);
    const float* hp = h + (size_t)dst * 128 + gk;
    hreg[i][0] = hp[0]; hreg[i][1] = hp[32]; hreg[i][2] = hp[64]; hreg[i][3] = hp[96];
  }
  const int tn = tid & 31, tm = tid >> 5;
  const int e0 = 4 * tn, t0 = 4 * tm;
  const int se = tid >> 1, sk = (tid & 1) * 16;
  float acc[4][4] = {};
  __syncthreads();
  #pragma unroll 1
  for (int kt = kt0; kt < kt0 + 28; kt++) {
    int c = kt >> 2, cc = c - c0, j = kt & 3;
    float4 av;
    av.x = efs[gt + 0][cc] * hreg[0][j];
    av.y = efs[gt + 1][cc] * hreg[1][j];
    av.z = efs[gt + 2][cc] * hreg[2][j];
    av.w = efs[gt + 3][cc] * hreg[3][j];
    *(float4*)&As[gk][gt] = av;
    const float* bp = ((c < 48) ? (elw + (size_t)c * 16384) : elb) + (size_t)se * 128 + j * 32 + sk;
    float4 w0 = *(const float4*)(bp + 0);
    float4 w1 = *(const float4*)(bp + 4);
    float4 w2 = *(const float4*)(bp + 8);
    float4 w3 = *(const float4*)(bp + 12);
    Bs[sk + 0][se] = w0.x;  Bs[sk + 1][se] = w0.y;  Bs[sk + 2][se] = w0.z;  Bs[sk + 3][se] = w0.w;
    Bs[sk + 4][se] = w1.x;  Bs[sk + 5][se] = w1.y;  Bs[sk + 6][se] = w1.z;  Bs[sk + 7][se] = w1.w;
    Bs[sk + 8][se] = w2.x;  Bs[sk + 9][se] = w2.y;  Bs[sk + 10][se] = w2.z; Bs[sk + 11][se] = w2.w;
    Bs[sk + 12][se] = w3.x; Bs[sk + 13][se] = w3.y; Bs[sk + 14][se] = w3.z; Bs[sk + 15][se] = w3.w;
    __syncthreads();
    #pragma unroll
    for (int kk = 0; kk < 32; kk++) {
      float4 a = *(const float4*)&As[kk][t0];
      float4 b = *(const float4*)&Bs[kk][e0];
      acc[0][0] += a.x * b.x; acc[0][1] += a.x * b.y; acc[0][2] += a.x * b.z; acc[0][3] += a.x * b.w;
      acc[1][0] += a.y * b.x; acc[1][1] += a.y * b.y; acc[1][2] += a.y * b.z; acc[1][3] += a.y * b.w;
      acc[2][0] += a.z * b.x; acc[2][1] += a.z * b.y; acc[2][2] += a.z * b.z; acc[2][3] += a.z * b.w;
      acc[3][0] += a.w * b.x; acc[3][1] += a.w * b.y; acc[3][2] += a.w * b.z; acc[3][3] += a.w * b.w;
    }
    __syncthreads();
  }
  #pragma unroll
  for (int i = 0; i < 4; i++) {
    int m = m0 + t0 + i;
    int src = (m < 4096) ? cei[m] : (sei[m - 4096] + 2048);
    float* dst = aggr + (size_t)src * 128 + e0;
    atomicAdd(dst + 0, acc[i][0]);
    atomicAdd(dst + 1, acc[i][1]);
    atomicAdd(dst + 2, acc[i][2]);
    atomicAdd(dst + 3, acc[i][3]);
  }
}

// ---------------------------------------------------------------- node GEMM: G[n][c*128+e] = sum_f W_c[e][f] h[n][f]
// W_48 = elb. grid (80, 49). Same proven inner loop as edge, minus ef/gather.
__global__ __launch_bounds__(256) void node_gemm_k(
    const float* __restrict__ h, const float* __restrict__ elw, const float* __restrict__ elb,
    float* __restrict__ G)
{
  __shared__ float As[32][36];
  __shared__ float Bs[32][136];
  const int tid = threadIdx.x;
  const int n0 = blockIdx.x * 32;
  const int c = blockIdx.y;
  const float* W = (c < 48) ? (elw + (size_t)c * 16384) : elb;
  const int gk = tid & 31, gt = (tid >> 5) * 4;
  float hreg[4][4];
  #pragma unroll
  for (int i = 0; i < 4; i++) {
    const float* hp = h + (size_t)(n0 + gt + i) * 128 + gk;
    hreg[i][0] = hp[0]; hreg[i][1] = hp[32]; hreg[i][2] = hp[64]; hreg[i][3] = hp[96];
  }
  const int tn = tid & 31, tm = tid >> 5;
  const int e0 = 4 * tn, t0 = 4 * tm;
  const int se = tid >> 1, sk = (tid & 1) * 16;
  float acc[4][4] = {};
  #pragma unroll 1
  for (int j = 0; j < 4; j++) {
    float4 av;
    av.x = hreg[0][j]; av.y = hreg[1][j]; av.z = hreg[2][j]; av.w = hreg[3][j];
    *(float4*)&As[gk][gt] = av;
    const float* bp = W + (size_t)se * 128 + j * 32 + sk;
    float4 w0 = *(const float4*)(bp + 0);
    float4 w1 = *(const float4*)(bp + 4);
    float4 w2 = *(const float4*)(bp + 8);
    float4 w3 = *(const float4*)(bp + 12);
    Bs[sk + 0][se] = w0.x;  Bs[sk + 1][se] = w0.y;  Bs[sk + 2][se] = w0.z;  Bs[sk + 3][se] = w0.w;
    Bs[sk + 4][se] = w1.x;  Bs[sk + 5][se] = w1.y;  Bs[sk + 6][se] = w1.z;  Bs[sk + 7][se] = w1.w;
    Bs[sk + 8][se] = w2.x;  Bs[sk + 9][se] = w2.y;  Bs[sk + 10][se] = w2.z; Bs[sk + 11][se] = w2.w;
    Bs[sk + 12][se] = w3.x; Bs[sk + 13][se] = w3.y; Bs[sk + 14][se] = w3.z; Bs[sk + 15][se] = w3.w;
    __syncthreads();
    #pragma unroll
    for (int kk = 0; kk < 32; kk++) {
      float4 a = *(const float4*)&As[kk][t0];
      float4 b = *(const float4*)&Bs[kk][e0];
      acc[0][0] += a.x * b.x; acc[0][1] += a.x * b.y; acc[0][2] += a.x * b.z; acc[0][3] += a.x * b.w;
      acc[1][0] += a.y * b.x; acc[1][1] += a.y * b.y; acc[1][2] += a.y * b.z; acc[1][3] += a.y * b.w;
      acc[2][0] += a.z * b.x; acc[2][1] += a.z * b.y; acc[2][2] += a.z * b.z; acc[2][3] += a.z * b.w;
      acc[3][0] += a.w * b.x; acc[3][1] += a.w * b.y; acc[3][2] += a.w * b.z; acc[3][3] += a.w * b.w;
    }
    __syncthreads();
  }
  #pragma unroll
  for (int i = 0; i < 4; i++) {
    float4 cv;
    cv.x = acc[i][0]; cv.y = acc[i][1]; cv.z = acc[i][2]; cv.w = acc[i][3];
    *(float4*)(G + (size_t)(n0 + t0 + i) * 6272 + c * 128 + e0) = cv;
  }
}

// ---------------------------------------------------------------- combine: msg[m,e] = sum_c ef[m,c]*G[dst[m]][c*128+e]
// -> atomicAdd aggr[src[m]]. grid 1280, 4 edges/block, thread (e, half) does 2 edges.
__global__ __launch_bounds__(256) void combine_k(
    const float* __restrict__ cea, const float* __restrict__ sea,
    const int* __restrict__ cei, const int* __restrict__ sei,
    const float* __restrict__ G, float* __restrict__ aggr)
{
  __shared__ float efs[4][52];
  __shared__ int srcs[4], dsts[4];
  const int tid = threadIdx.x;
  const int m0 = blockIdx.x * 4;
  if (tid < 4) {
    int m = m0 + tid;
    int src, dst;
    if (m < 4096) { src = cei[m]; dst = cei[4096 + m]; }
    else { src = sei[m - 4096] + 2048; dst = sei[1024 + (m - 4096)] + 2048; }
    srcs[tid] = src; dsts[tid] = dst;
  }
  if (tid < 196) {
    int t = tid / 49, cc = tid - t * 49;
    int m = m0 + t;
    const float* attr = (m < 4096) ? (cea + (size_t)m * 17) : (sea + (size_t)(m - 4096) * 17);
    float val;
    if (cc < 16) val = attr[cc];
    else if (cc < 48) {
      float d = fminf(fmaxf(attr[16], 0.0f), 10.0f);
      float t2 = d - (float)((cc - 16) * (5.0 / 31.0));
      val = expf(-38.44f * t2 * t2);
    } else val = 1.0f;
    efs[t][cc] = val;
  }
  __syncthreads();
  const int e = tid & 127, half = tid >> 7;
  #pragma unroll
  for (int tt = 0; tt < 2; tt++) {
    int t = half * 2 + tt;
    const float* gp = G + (size_t)dsts[t] * 6272 + e;
    float acc = 0;
    #pragma unroll 7
    for (int c = 0; c < 49; c++) acc += efs[t][c] * gp[(size_t)c * 128];
    atomicAdd(aggr + (size_t)srcs[t] * 128 + e, acc);
  }
}

// ---------------------------------------------------------------- BM=16 GEMM body (K=128), barrier-staged
__device__ __forceinline__ void gemm16_body(G16Sm& sm,
    const float* __restrict__ A, const float* __restrict__ Bp,
    const float* __restrict__ biasp, float* __restrict__ Cp,
    int row0, int ldb, int ldc)
{
  const int tid = threadIdx.x;
  const int tm = tid >> 5, tn = tid & 31;
  const int t0 = 2 * tm, e0 = 4 * tn;
  const int ar = tid >> 4, ak = (tid & 15) * 2;
  const int bk = tid >> 3, be = (tid & 7) * 16;
  float acc[2][4] = {};
  for (int k0 = 0; k0 < 128; k0 += 32) {
    float2 av = *(const float2*)(A + (size_t)(row0 + ar) * 128 + k0 + ak);
    sm.Sa[ak][ar] = av.x; sm.Sa[ak + 1][ar] = av.y;
    const float* bp = Bp + (size_t)(k0 + bk) * ldb + be;
    float4 b0v = *(const float4*)(bp + 0);
    float4 b1v = *(const float4*)(bp + 4);
    float4 b2v = *(const float4*)(bp + 8);
    float4 b3v = *(const float4*)(bp + 12);
    sm.Bs[bk][be + 0] = b0v.x;  sm.Bs[bk][be + 1] = b0v.y;  sm.Bs[bk][be + 2] = b0v.z;  sm.Bs[bk][be + 3] = b0v.w;
    sm.Bs[bk][be + 4] = b1v.x;  sm.Bs[bk][be + 5] = b1v.y;  sm.Bs[bk][be + 6] = b1v.z;  sm.Bs[bk][be + 7] = b1v.w;
    sm.Bs[bk][be + 8] = b2v.x;  sm.Bs[bk][be + 9] = b2v.y;  sm.Bs[bk][be + 10] = b2v.z; sm.Bs[bk][be + 11] = b2v.w;
    sm.Bs[bk][be + 12] = b3v.x; sm.Bs[bk][be + 13] = b3v.y; sm.Bs[bk][be + 14] = b3v.z; sm.Bs[bk][be + 15] = b3v.w;
    __syncthreads();
    #pragma unroll
    for (int kk = 0; kk < 32; kk++) {
      float2 a = *(const float2*)&sm.Sa[kk][t0];
      float4 b = *(const float4*)&sm.Bs[kk][e0];
      acc[0][0] += a.x * b.x; acc[0][1] += a.x * b.y; acc[0][2] += a.x * b.z; acc[0][3] += a.x * b.w;
      acc[1][0] += a.y * b.x; acc[1][1] += a.y * b.y; acc[1][2] += a.y * b.z; acc[1][3] += a.y * b.w;
    }
    __syncthreads();
  }
  #pragma unroll
  for (int i = 0; i < 2; i++) {
    float* cp = Cp + (size_t)(row0 + t0 + i) * ldc + e0;
    #pragma unroll
    for (int j = 0; j < 4; j++) cp[j] = acc[i][j] + biasp[e0 + j];
  }
}

// ---------------------------------------------------------------- merged QKV: graph (3x160) + seq (3x128)
__global__ __launch_bounds__(256) void qkv_k(
    int gBlocks,
    const float* __restrict__ ghb,
    const float* gqw, const float* gkw, const float* gvw,
    const float* gqb, const float* gkb, const float* gvb, float* gout,
    const float* __restrict__ sxs, const float* sw, const float* sb, float* sout)
{
  __shared__ G16Sm sm;
  int bx = blockIdx.x;
  if (bx < gBlocks) {
    int z = bx / 160, rt = bx % 160;
    const float* B = (z == 0) ? gqw : (z == 1) ? gkw : gvw;
    const float* bias = (z == 0) ? gqb : (z == 1) ? gkb : gvb;
    gemm16_body(sm, ghb, B, bias, gout + (size_t)z * 327680, rt * 16, 128, 128);
  } else {
    int i = bx - gBlocks;
    int z = i >> 7, rt = i & 127;
    gemm16_body(sm, sxs, sw + z * 128, sb + z * 128, sout + z * 128, rt * 16, 384, 384);
  }
}

// ---------------------------------------------------------------- graph attention body (N=32, GD=16)
__device__ __forceinline__ void gattn_body(GAttnSm& sm, int g, int h,
    const float* __restrict__ q, const float* __restrict__ k,
    const float* __restrict__ v, const float* __restrict__ dist, float* __restrict__ o)
{
  const int tid = threadIdx.x;
  {
    int idx = tid * 2;
    int i = idx >> 4, d = idx & 15;
    size_t base = ((size_t)(g * 32 + i)) * 128 + h * 16 + d;
    sm.qs[i][d] = q[base];  sm.qs[i][d + 1] = q[base + 1];
    sm.ksh[i][d] = k[base]; sm.ksh[i][d + 1] = k[base + 1];
    sm.vsh[i][d] = v[base]; sm.vsh[i][d + 1] = v[base + 1];
  }
  __syncthreads();
  {
    int i = tid >> 3, j0 = (tid & 7) * 4;
    for (int j = j0; j < j0 + 4; j++) {
      float a = 0;
      #pragma unroll
      for (int d = 0; d < 16; d++) a += sm.qs[i][d] * sm.ksh[j][d];
      a = a * 0.25f + dist[(size_t)g * 1024 + i * 32 + j];
      sm.ss[i][j] = fminf(fmaxf(a, -10.0f), 10.0f);
    }
  }
  __syncthreads();
  if (tid < 32) {
    float m = -1e30f;
    for (int j = 0; j < 32; j++) m = fmaxf(m, sm.ss[tid][j]);
    float s = 0;
    for (int j = 0; j < 32; j++) { float ex = expf(sm.ss[tid][j] - m); sm.ss[tid][j] = ex; s += ex; }
    sm.rs[tid] = 1.0f / s;
  }
  __syncthreads();
  {
    int idx = tid * 2;
    int i = idx >> 4, d = idx & 15;
    float a0 = 0, a1 = 0;
    for (int j = 0; j < 32; j++) { float wj = sm.ss[i][j]; a0 += wj * sm.vsh[j][d]; a1 += wj * sm.vsh[j][d + 1]; }
    float r = sm.rs[i];
    size_t base = ((size_t)(g * 32 + i)) * 128 + h * 16 + d;
    o[base] = a0 * r; o[base + 1] = a1 * r;
  }
}

// ---------------------------------------------------------------- seq attention body (slim, K/V tiled)
__device__ __forceinline__ void sattn_body(SAttnSm& sm, int b, int h, int qt,
    const float* __restrict__ qkv, float* __restrict__ o)
{
  const int tid = threadIdx.x;
  {
    int i = tid >> 3, d0 = (tid & 7) * 4;
    const float* qp = qkv + ((size_t)(b * 128 + qt * 32 + i)) * 384 + h * 32 + d0;
    sm.qs2[i][d0 + 0] = qp[0]; sm.qs2[i][d0 + 1] = qp[1];
    sm.qs2[i][d0 + 2] = qp[2]; sm.qs2[i][d0 + 3] = qp[3];
  }
  const int i = tid >> 3, sub = tid & 7;
  for (int jt = 0; jt < 4; jt++) {
    {
      int r = tid >> 3, dd = (tid & 7) * 4;
      const float* kp = qkv + ((size_t)(b * 128 + jt * 32 + r)) * 384 + 128 + h * 32 + dd;
      float4 kv4 = *(const float4*)kp;
      sm.kv[r][dd + 0] = kv4.x; sm.kv[r][dd + 1] = kv4.y;
      sm.kv[r][dd + 2] = kv4.z; sm.kv[r][dd + 3] = kv4.w;
    }
    __syncthreads();
    {
      int j0 = jt * 32 + sub * 4;
      for (int j = j0; j < j0 + 4; j++) {
        int jr = j - jt * 32;
        float a = 0;
        #pragma unroll
        for (int d = 0; d < 32; d++) a += sm.qs2[i][d] * sm.kv[jr][d];
        sm.ss2[i][j] = a * 0.17677669529663687f;
      }
    }
    __syncthreads();
  }
  float m = -1e30f;
  for (int j = sub; j < 128; j += 8) m = fmaxf(m, sm.ss2[i][j]);
  sm.red[i][sub] = m;
  __syncthreads();
  float mm = sm.red[i][0];
  #pragma unroll
  for (int t = 1; t < 8; t++) mm = fmaxf(mm, sm.red[i][t]);
  float ps = 0;
  for (int j = sub; j < 128; j += 8) { float ex = expf(sm.ss2[i][j] - mm); sm.ss2[i][j] = ex; ps += ex; }
  sm.red2[i][sub] = ps;
  __syncthreads();
  float s = 0;
  #pragma unroll
  for (int t = 0; t < 8; t++) s += sm.red2[i][t];
  float rinv = 1.0f / s;
  float a0 = 0, a1 = 0, a2 = 0, a3 = 0;
  const int d0 = sub * 4;
  for (int jt = 0; jt < 4; jt++) {
    __syncthreads();
    {
      int r = tid >> 3, dd = (tid & 7) * 4;
      const float* vp = qkv + ((size_t)(b * 128 + jt * 32 + r)) * 384 + 256 + h * 32 + dd;
      float4 vv = *(const float4*)vp;
      sm.kv[r][dd + 0] = vv.x; sm.kv[r][dd + 1] = vv.y;
      sm.kv[r][dd + 2] = vv.z; sm.kv[r][dd + 3] = vv.w;
    }
    __syncthreads();
    for (int jr = 0; jr < 32; jr++) {
      float wj = sm.ss2[i][jt * 32 + jr];
      a0 += wj * sm.kv[jr][d0 + 0]; a1 += wj * sm.kv[jr][d0 + 1];
      a2 += wj * sm.kv[jr][d0 + 2]; a3 += wj * sm.kv[jr][d0 + 3];
    }
  }
  float* op = o + ((size_t)(b * 128 + qt * 32 + i)) * 128 + h * 32 + d0;
  op[0] = a0 * rinv; op[1] = a1 * rinv; op[2] = a2 * rinv; op[3] = a3 * rinv;
}

// ---------------------------------------------------------------- merged attention: graph + seq (union LDS)
__global__ __launch_bounds__(256) void attn_k(
    int gBlocks, const float* q, const float* k, const float* v,
    const float* dist, float* go, const float* qkv, float* so)
{
  __shared__ AttnU u;
  int bx = blockIdx.x;
  if (bx < gBlocks) gattn_body(u.a, bx >> 3, bx & 7, q, k, v, dist, go);
  else { int i = bx - gBlocks; sattn_body(u.s, i >> 4, (i >> 2) & 3, i & 3, qkv, so); }
}

// ---------------------------------------------------------------- layer tail body (barrier-staged)
__device__ __forceinline__ void tail_body(TailSm& sm, int row0, const float* __restrict__ A,
    const float* __restrict__ Wo, const float* __restrict__ bo, const float* __restrict__ res,
    const float* __restrict__ g1, const float* __restrict__ b1n,
    const float* __restrict__ W1, const float* __restrict__ b1f,
    const float* __restrict__ W2, const float* __restrict__ b2f,
    const float* __restrict__ g2, const float* __restrict__ b2n,
    float* __restrict__ Out)
{
  float (*BsA)[136] = (float(*)[136])sm.sbuf;
  float (*Bs1)[260] = (float(*)[260])sm.sbuf;
  float (*Bs2)[136] = (float(*)[136])sm.sbuf;
  const int tid = threadIdx.x;
  // ---- stage A: x1 = LN(A@Wo + bo + res) ----
  {
    const int tm = tid >> 5, tn = tid & 31;
    const int t0 = 2 * tm, e0 = 4 * tn;
    const int ar = tid >> 4, ak = (tid & 15) * 2;
    const int bk = tid >> 3, be = (tid & 7) * 16;
    float acc[2][4] = {};
    for (int k0 = 0; k0 < 128; k0 += 32) {
      float2 av = *(const float2*)(A + (size_t)(row0 + ar) * 128 + k0 + ak);
      sm.Sa[ak][ar] = av.x; sm.Sa[ak + 1][ar] = av.y;
      const float* bp = Wo + (size_t)(k0 + bk) * 128 + be;
      float4 b0v = *(const float4*)(bp + 0);
      float4 b1v = *(const float4*)(bp + 4);
      float4 b2v = *(const float4*)(bp + 8);
      float4 b3v = *(const float4*)(bp + 12);
      BsA[bk][be + 0] = b0v.x;  BsA[bk][be + 1] = b0v.y;  BsA[bk][be + 2] = b0v.z;  BsA[bk][be + 3] = b0v.w;
      BsA[bk][be + 4] = b1v.x;  BsA[bk][be + 5] = b1v.y;  BsA[bk][be + 6] = b1v.z;  BsA[bk][be + 7] = b1v.w;
      BsA[bk][be + 8] = b2v.x;  BsA[bk][be + 9] = b2v.y;  BsA[bk][be + 10] = b2v.z; BsA[bk][be + 11] = b2v.w;
      BsA[bk][be + 12] = b3v.x; BsA[bk][be + 13] = b3v.y; BsA[bk][be + 14] = b3v.z; BsA[bk][be + 15] = b3v.w;
      __syncthreads();
      #pragma unroll
      for (int kk = 0; kk < 32; kk++) {
        float2 a = *(const float2*)&sm.Sa[kk][t0];
        float4 b = *(const float4*)&BsA[kk][e0];
        acc[0][0] += a.x * b.x; acc[0][1] += a.x * b.y; acc[0][2] += a.x * b.z; acc[0][3] += a.x * b.w;
        acc[1][0] += a.y * b.x; acc[1][1] += a.y * b.y; acc[1][2] += a.y * b.z; acc[1][3] += a.y * b.w;
      }
      __syncthreads();
    }
    #pragma unroll
    for (int i = 0; i < 2; i++) {
      int r = row0 + t0 + i;
      float v0 = acc[i][0] + bo[e0 + 0] + res[(size_t)r * 128 + e0 + 0];
      float v1 = acc[i][1] + bo[e0 + 1] + res[(size_t)r * 128 + e0 + 1];
      float v2 = acc[i][2] + bo[e0 + 2] + res[(size_t)r * 128 + e0 + 2];
      float v3 = acc[i][3] + bo[e0 + 3] + res[(size_t)r * 128 + e0 + 3];
      float s = v0 + v1 + v2 + v3;
      #pragma unroll
      for (int o = 1; o < 32; o <<= 1) s += __shfl_xor(s, o);
      float mean = s * (1.0f / 128.0f);
      float d0 = v0 - mean, d1 = v1 - mean, d2 = v2 - mean, d3 = v3 - mean;
      float sq = d0 * d0 + d1 * d1 + d2 * d2 + d3 * d3;
      #pragma unroll
      for (int o = 1; o < 32; o <<= 1) sq += __shfl_xor(sq, o);
      float rstd = 1.0f / sqrtf(sq * (1.0f / 128.0f) + 1e-5f);
      sm.x1[t0 + i][e0 + 0] = d0 * rstd * g1[e0 + 0] + b1n[e0 + 0];
      sm.x1[t0 + i][e0 + 1] = d1 * rstd * g1[e0 + 1] + b1n[e0 + 1];
      sm.x1[t0 + i][e0 + 2] = d2 * rstd * g1[e0 + 2] + b1n[e0 + 2];
      sm.x1[t0 + i][e0 + 3] = d3 * rstd * g1[e0 + 3] + b1n[e0 + 3];
    }
  }
  __syncthreads();
  // ---- stage B: hid = relu(x1 @ W1 + b1f), 16x256 ----
  {
    const int tm = tid >> 6, tn = tid & 63;
    const int t0 = 4 * tm, e0 = 4 * tn;
    const int ar = tid >> 4, ak = tid & 15;
    const int bk = tid >> 4, be = (tid & 15) * 16;
    float acc[4][4] = {};
    for (int k0 = 0; k0 < 128; k0 += 16) {
      sm.Sa[ak][ar] = sm.x1[ar][k0 + ak];
      const float* bp = W1 + (size_t)(k0 + bk) * 256 + be;
      float4 b0v = *(const float4*)(bp + 0);
      float4 b1v = *(const float4*)(bp + 4);
      float4 b2v = *(const float4*)(bp + 8);
      float4 b3v = *(const float4*)(bp + 12);
      Bs1[bk][be + 0] = b0v.x;  Bs1[bk][be + 1] = b0v.y;  Bs1[bk][be + 2] = b0v.z;  Bs1[bk][be + 3] = b0v.w;
      Bs1[bk][be + 4] = b1v.x;  Bs1[bk][be + 5] = b1v.y;  Bs1[bk][be + 6] = b1v.z;  Bs1[bk][be + 7] = b1v.w;
      Bs1[bk][be + 8] = b2v.x;  Bs1[bk][be + 9] = b2v.y;  Bs1[bk][be + 10] = b2v.z; Bs1[bk][be + 11] = b2v.w;
      Bs1[bk][be + 12] = b3v.x; Bs1[bk][be + 13] = b3v.y; Bs1[bk][be + 14] = b3v.z; Bs1[bk][be + 15] = b3v.w;
      __syncthreads();
      #pragma unroll
      for (int kk = 0; kk < 16; kk++) {
        float4 a = *(const float4*)&sm.Sa[kk][t0];
        float4 b = *(const float4*)&Bs1[kk][e0];
        acc[0][0] += a.x * b.x; acc[0][1] += a.x * b.y; acc[0][2] += a.x * b.z; acc[0][3] += a.x * b.w;
        acc[1][0] += a.y * b.x; acc[1][1] += a.y * b.y; acc[1][2] += a.y * b.z; acc[1][3] += a.y * b.w;
        acc[2][0] += a.z * b.x; acc[2][1] += a.z * b.y; acc[2][2] += a.z * b.z; acc[2][3] += a.z * b.w;
        acc[3][0] += a.w * b.x; acc[3][1] += a.w * b.y; acc[3][2] += a.w * b.z; acc[3][3] += a.w * b.w;
      }
      __syncthreads();
    }
    #pragma unroll
    for (int i = 0; i < 4; i++) {
      float4 hv;
      hv.x = fmaxf(acc[i][0] + b1f[e0 + 0], 0.0f);
      hv.y = fmaxf(acc[i][1] + b1f[e0 + 1], 0.0f);
      hv.z = fmaxf(acc[i][2] + b1f[e0 + 2], 0.0f);
      hv.w = fmaxf(acc[i][3] + b1f[e0 + 3], 0.0f);
      *(float4*)&sm.hid[t0 + i][e0] = hv;
    }
  }
  __syncthreads();
  // ---- stage C: Out = LN(hid@W2 + b2f + x1) ----
  {
    const int tm = tid >> 5, tn = tid & 31;
    const int t0 = 2 * tm, e0 = 4 * tn;
    const int bk = tid >> 3, be = (tid & 7) * 16;
    float acc[2][4] = {};
    for (int k0 = 0; k0 < 256; k0 += 32) {
      const float* bp = W2 + (size_t)(k0 + bk) * 128 + be;
      float4 b0v = *(const float4*)(bp + 0);
      float4 b1v = *(const float4*)(bp + 4);
      float4 b2v = *(const float4*)(bp + 8);
      float4 b3v = *(const float4*)(bp + 12);
      Bs2[bk][be + 0] = b0v.x;  Bs2[bk][be + 1] = b0v.y;  Bs2[bk][be + 2] = b0v.z;  Bs2[bk][be + 3] = b0v.w;
      Bs2[bk][be + 4] = b1v.x;  Bs2[bk][be + 5] = b1v.y;  Bs2[bk][be + 6] = b1v.z;  Bs2[bk][be + 7] = b1v.w;
      Bs2[bk][be + 8] = b2v.x;  Bs2[bk][be + 9] = b2v.y;  Bs2[bk][be + 10] = b2v.z; Bs2[bk][be + 11] = b2v.w;
      Bs2[bk][be + 12] = b3v.x; Bs2[bk][be + 13] = b3v.y; Bs2[bk][be + 14] = b3v.z; Bs2[bk][be + 15] = b3v.w;
      __syncthreads();
      #pragma unroll
      for (int kk = 0; kk < 32; kk++) {
        float a0 = sm.hid[t0 + 0][k0 + kk];
        float a1 = sm.hid[t0 + 1][k0 + kk];
        float4 b = *(const float4*)&Bs2[kk][e0];
        acc[0][0] += a0 * b.x; acc[0][1] += a0 * b.y; acc[0][2] += a0 * b.z; acc[0][3] += a0 * b.w;
        acc[1][0] += a1 * b.x; acc[1][1] += a1 * b.y; acc[1][2] += a1 * b.z; acc[1][3] += a1 * b.w;
      }
      __syncthreads();
    }
    #pragma unroll
    for (int i = 0; i < 2; i++) {
      int r = row0 + t0 + i;
      float v0 = acc[i][0] + b2f[e0 + 0] + sm.x1[t0 + i][e0 + 0];
      float v1 = acc[i][1] + b2f[e0 + 1] + sm.x1[t0 + i][e0 + 1];
      float v2 = acc[i][2] + b2f[e0 + 2] + sm.x1[t0 + i][e0 + 2];
      float v3 = acc[i][3] + b2f[e0 + 3] + sm.x1[t0 + i][e0 + 3];
      float s = v0 + v1 + v2 + v3;
      #pragma unroll
      for (int o = 1; o < 32; o <<= 1) s += __shfl_xor(s, o);
      float mean = s * (1.0f / 128.0f);
      float d0 = v0 - mean, d1 = v1 - mean, d2 = v2 - mean, d3 = v3 - mean;
      float sq = d0 * d0 + d1 * d1 + d2 * d2 + d3 * d3;
      #pragma unroll
      for (int o = 1; o < 32; o <<= 1) sq += __shfl_xor(sq, o);
      float rstd = 1.0f / sqrtf(sq * (1.0f / 128.0f) + 1e-5f);
      float* cp = Out + (size_t)r * 128 + e0;
      cp[0] = d0 * rstd * g2[e0 + 0] + b2n[e0 + 0];
      cp[1] = d1 * rstd * g2[e0 + 1] + b2n[e0 + 1];
      cp[2] = d2 * rstd * g2[e0 + 2] + b2n[e0 + 2];
      cp[3] = d3 * rstd * g2[e0 + 3] + b2n[e0 + 3];
    }
  }
}

// ---------------------------------------------------------------- merged tail: graph + seq
__global__ __launch_bounds__(256) void tail_k(
    int gBlocks,
    const float* gA, const float* gWo, const float* gbo, const float* gres,
    const float* gg1, const float* gb1, const float* gW1, const float* gbf1,
    const float* gW2, const float* gbf2, const float* gg2, const float* gb2, float* gOut,
    const float* sA, const float* sWo, const float* sbo, const float* sres,
    const float* sg1, const float* sb1, const float* sW1, const float* sbf1,
    const float* sW2, const float* sbf2, const float* sg2, const float* sb2, float* sOut)
{
  __shared__ TailSm sm;
  int bx = blockIdx.x;
  if (bx < gBlocks)
    tail_body(sm, bx * 16, gA, gWo, gbo, gres, gg1, gb1, gW1, gbf1, gW2, gbf2, gg2, gb2, gOut);
  else
    tail_body(sm, (bx - gBlocks) * 16, sA, sWo, sbo, sres, sg1, sb1, sW1, sbf1, sW2, sbf2, sg2, sb2, sOut);
}

// ---------------------------------------------------------------- LayerNorm rows of 128 (after edge aggr)
__global__ __launch_bounds__(128) void ln_k(
    const float* __restrict__ x, const float* __restrict__ res,
    const float* __restrict__ g, const float* __restrict__ b, float* __restrict__ out)
{
  __shared__ float sred[2];
  int r = blockIdx.x, e = threadIdx.x;
  size_t idx = (size_t)r * 128 + e;
  float v = x[idx] + res[idx];
  float nv = blk_norm(v, e, sred);
  out[idx] = nv * g[e] + b[e];
}

// ---------------------------------------------------------------- pool + smean + fusion + cross-modal + head
__global__ __launch_bounds__(128) void head_k(
    const float* __restrict__ hb, const float* __restrict__ xs, const float* __restrict__ gfeat,
    const float* fg1w, const float* fg1b, const float* fg2w, const float* fg2b,
    const float* g2s_vw, const float* g2s_vb, const float* g2s_ow, const float* g2s_ob,
    const float* n1g, const float* n1b,
    const float* s2g_vw, const float* s2g_vb, const float* s2g_ow, const float* s2g_ob,
    const float* n2g, const float* n2b,
    const float* r1w, const float* r1b, const float* r2w, const float* r2b,
    float* __restrict__ out)
{
  __shared__ float T[128], S[128], G[128], Sm[128], t1[128], t2[128], gh[64], sred[2];
  int mol = blockIdx.x, e = threadIdx.x;
  {
    float cs = 0;
    for (int c = 0; c < 4; c++) {
      int g = mol * 4 + c;
      float s = 0;
      for (int i = 0; i < 32; i++) s += hb[((size_t)(g * 32 + i)) * 128 + e];
      cs += s * (1.0f / 32.0f);
    }
    cs *= 0.25f;
    float s2 = 0;
    int g = 64 + mol;
    for (int i = 0; i < 32; i++) s2 += hb[((size_t)(g * 32 + i)) * 128 + e];
    T[e] = cs + s2 * (1.0f / 32.0f);
    float ss = 0;
    for (int l = 0; l < 128; l++) ss += xs[((size_t)(mol * 128 + l)) * 128 + e];
    S[e] = ss * (1.0f / 128.0f);
  }
  __syncthreads();
  if (e < 64) {
    float a = fg1b[e];
    for (int f = 0; f < 128; f++) a += T[f] * fg1w[f * 64 + e];
    for (int f = 0; f < 128; f++) a += S[f] * fg1w[(128 + f) * 64 + e];
    gh[e] = fmaxf(a, 0.0f);
  }
  __syncthreads();
  {
    float a = fg2b[e];
    for (int j = 0; j < 64; j++) a += gh[j] * fg2w[j * 128 + e];
    float gate = 1.0f / (1.0f + expf(-a));
    float fu = gate * T[e] + (1.0f - gate) * S[e];
    G[e] = fu; Sm[e] = fu;
  }
  __syncthreads();
  for (int l = 0; l < 2; l++) {
    const float* vw = g2s_vw + (size_t)l * 16384; const float* vb = g2s_vb + l * 128;
    const float* ow = g2s_ow + (size_t)l * 16384; const float* ob = g2s_ob + l * 128;
    float a = vb[e];
    for (int f = 0; f < 128; f++) a += Sm[f] * vw[f * 128 + e];
    t1[e] = a;
    __syncthreads();
    a = ob[e];
    for (int f = 0; f < 128; f++) a += t1[f] * ow[f * 128 + e];
    float nv = blk_norm(G[e] + a, e, sred);
    G[e] = nv * n1g[l * 128 + e] + n1b[l * 128 + e];
    __syncthreads();
    const float* vw2 = s2g_vw + (size_t)l * 16384; const float* vb2 = s2g_vb + l * 128;
    const float* ow2 = s2g_ow + (size_t)l * 16384; const float* ob2 = s2g_ob + l * 128;
    a = vb2[e];
    for (int f = 0; f < 128; f++) a += G[f] * vw2[f * 128 + e];
    t1[e] = a;
    __syncthreads();
    a = ob2[e];
    for (int f = 0; f < 128; f++) a += t1[f] * ow2[f * 128 + e];
    nv = blk_norm(Sm[e] + a, e, sred);
    Sm[e] = nv * n2g[l * 128 + e] + n2b[l * 128 + e];
    __syncthreads();
  }
  t2[e] = 0.5f * (G[e] + Sm[e]);
  __syncthreads();
  float a = r1b[e];
  for (int f = 0; f < 128; f++) a += t2[f] * r1w[f * 128 + e];
  for (int f = 0; f < 3; f++) a += gfeat[mol * 3 + f] * r1w[(128 + f) * 128 + e];
  a = fmaxf(a, 0.0f);
  float p = a * r2w[e];
  #pragma unroll
  for (int o = 1; o < 64; o <<= 1) p += __shfl_xor(p, o);
  if ((e & 63) == 0) sred[e >> 6] = p;
  __syncthreads();
  if (e == 0) out[mol] = sred[0] + sred[1] + r2b[0];
}

// ================================================================ host
extern "C" void kernel_launch(void* const* d_in, const int* in_sizes, int n_in,
                              void* d_out, int out_size, void* d_ws, size_t ws_size,
                              hipStream_t stream)
{
  (void)n_in; (void)out_size;
  const bool dict = (in_sizes[1] == 8192);
  auto IN = [&](int di, int si) { return d_in[dict ? di : si]; };

  const float* conf_x   = (const float*)IN(0, 0);
  const int*   conf_ei  = (const int*)  IN(1, 63);
  const float* conf_ea  = (const float*)IN(2, 1);
  const float* conf_pos = (const float*)IN(3, 2);
  const float* scaf_x   = (const float*)IN(4, 3);
  const int*   scaf_ei  = (const int*)  IN(5, 64);
  const float* scaf_ea  = (const float*)IN(6, 4);
  const float* scaf_pos = (const float*)IN(7, 5);
  const int*   tokens   = (const int*)  IN(8, 65);
  const float* gfeat    = (const float*)IN(9, 6);
  const float* gproj_w  = (const float*)IN(11, 7);
  const float* gproj_b  = (const float*)IN(12, 8);
  const float* elin_w   = (const float*)IN(13, 9);
  const float* elin_b   = (const float*)IN(14, 10);
  const float* eln_g    = (const float*)IN(15, 11);
  const float* eln_b    = (const float*)IN(16, 12);
  const float* gt_qw    = (const float*)IN(17, 13);
  const float* gt_qb    = (const float*)IN(18, 14);
  const float* gt_kw    = (const float*)IN(19, 15);
  const float* gt_kb    = (const float*)IN(20, 16);
  const float* gt_vw    = (const float*)IN(21, 17);
  const float* gt_vb    = (const float*)IN(22, 18);
  const float* gt_ow    = (const float*)IN(23, 19);
  const float* gt_ob    = (const float*)IN(24, 20);
  const float* gt_ln1g  = (const float*)IN(25, 21);
  const float* gt_ln1b  = (const float*)IN(26, 22);
  const float* gt_f1w   = (const float*)IN(27, 23);
  const float* gt_f1b   = (const float*)IN(28, 24);
  const float* gt_f2w   = (const float*)IN(29, 25);
  const float* gt_f2b   = (const float*)IN(30, 26);
  const float* gt_ln2g  = (const float*)IN(31, 27);
  const float* gt_ln2b  = (const float*)IN(32, 28);
  const float* tok_emb  = (const float*)IN(33, 29);
  const float* pos_emb  = (const float*)IN(34, 30);
  const float* se_inw   = (const float*)IN(35, 31);
  const float* se_inb   = (const float*)IN(36, 32);
  const float* se_ow    = (const float*)IN(37, 33);
  const float* se_ob    = (const float*)IN(38, 34);
  const float* se_ln1g  = (const float*)IN(39, 35);
  const float* se_ln1b  = (const float*)IN(40, 36);
  const float* se_f1w   = (const float*)IN(41, 37);
  const float* se_f1b   = (const float*)IN(42, 38);
  const float* se_f2w   = (const float*)IN(43, 39);
  const float* se_f2b   = (const float*)IN(44, 40);
  const float* se_ln2g  = (const float*)IN(45, 41);
  const float* se_ln2b  = (const float*)IN(46, 42);
  const float* fg1_w    = (const float*)IN(47, 43);
  const float* fg1_b    = (const float*)IN(48, 44);
  const float* fg2_w    = (const float*)IN(49, 45);
  const float* fg2_b    = (const float*)IN(50, 46);
  const float* cm_g2s_vw = (const float*)IN(51, 47);
  const float* cm_g2s_vb = (const float*)IN(52, 48);
  const float* cm_g2s_ow = (const float*)IN(53, 49);
  const float* cm_g2s_ob = (const float*)IN(54, 50);
  const float* cm_s2g_vw = (const float*)IN(55, 53);
  const float* cm_s2g_vb = (const float*)IN(56, 54);
  const float* cm_s2g_ow = (const float*)IN(57, 55);
  const float* cm_s2g_ob = (const float*)IN(58, 56);
  const float* cm_n1g   = (const float*)IN(59, 51);
  const float* cm_n1b   = (const float*)IN(60, 52);
  const float* cm_n2g   = (const float*)IN(61, 57);
  const float* cm_n2b   = (const float*)IN(62, 58);
  const float* r1_w     = (const float*)IN(63, 59);
  const float* r1_b     = (const float*)IN(64, 60);
  const float* r2_w     = (const float*)IN(65, 61);
  const float* r2_b     = (const float*)IN(66, 62);
  float* out = (float*)d_out;

  // ---- workspace (fp32) ----
  float* w = (float*)d_ws;
  size_t off = 0;
  auto alloc = [&](size_t n) { float* p = w + off; off += n; return p; };
  float* h     = alloc(2560 * 128);
  float* aggr  = alloc(2560 * 128);
  float* hb    = alloc(2560 * 128);
  float* distb = alloc(80 * 1024);
  float* qb    = alloc(3 * 327680);     // graph q/k/v
  float* atto  = alloc(327680);
  float* xs2   = alloc(2048 * 128);
  float* qkv3  = alloc(2048 * 384);
  float* satto = alloc(2048 * 128);
  float* xsfin = alloc(2048 * 128);
  float* Gws   = w + off;               // 2560*6272 (factorized path only)
  const size_t needed = (off + (size_t)2560 * 6272) * sizeof(float);
  const bool factorized = (ws_size >= needed);

  // front (node_proj + zero aggr + dist + embed)
  front_k<<<2384, 256, 0, stream>>>(conf_x, scaf_x, gproj_w, gproj_b, h, aggr,
                                    conf_pos, scaf_pos, distb,
                                    tokens, tok_emb, pos_emb, xs2);
  if (factorized) {
    node_gemm_k<<<dim3(80, 49), 256, 0, stream>>>(h, elin_w, elin_b, Gws);
    combine_k<<<1280, 256, 0, stream>>>(conf_ea, scaf_ea, conf_ei, scaf_ei, Gws, aggr);
  } else {
    edge_gemm_k<<<dim3(160, 7), 256, 0, stream>>>(conf_ea, scaf_ea, conf_ei, scaf_ei, h, elin_w, elin_b, aggr);
  }
  ln_k<<<2560, 128, 0, stream>>>(aggr, h, eln_g, eln_b, hb);

  // merged graph(3) + seq(4) transformer layers
  for (int l = 0; l < 4; l++) {
    const bool hasG = (l < 3);
    const int lg = hasG ? l : 0;
    const int gq = hasG ? 480 : 0;
    const int ga = hasG ? 640 : 0;
    const int gt = hasG ? 160 : 0;
    float* sOut = (l == 3) ? xsfin : xs2;
    qkv_k<<<gq + 384, 256, 0, stream>>>(gq,
        hb, gt_qw + (size_t)lg * 16384, gt_kw + (size_t)lg * 16384, gt_vw + (size_t)lg * 16384,
        gt_qb + lg * 128, gt_kb + lg * 128, gt_vb + lg * 128, qb,
        xs2, se_inw + (size_t)l * 49152, se_inb + l * 384, qkv3);
    attn_k<<<ga + 256, 256, 0, stream>>>(ga, qb, qb + 327680, qb + 655360, distb, atto, qkv3, satto);
    tail_k<<<gt + 128, 256, 0, stream>>>(gt,
        atto, gt_ow + (size_t)lg * 16384, gt_ob + lg * 128, hb,
        gt_ln1g + lg * 128, gt_ln1b + lg * 128,
        gt_f1w + (size_t)lg * 32768, gt_f1b + lg * 256,
        gt_f2w + (size_t)lg * 32768, gt_f2b + lg * 128,
        gt_ln2g + lg * 128, gt_ln2b + lg * 128, hb,
        satto, se_ow + (size_t)l * 16384, se_ob + l * 128, xs2,
        se_ln1g + l * 128, se_ln1b + l * 128,
        se_f1w + (size_t)l * 32768, se_f1b + l * 256,
        se_f2w + (size_t)l * 32768, se_f2b + l * 128,
        se_ln2g + l * 128, se_ln2b + l * 128, sOut);
  }

  // head
  head_k<<<16, 128, 0, stream>>>(hb, xsfin, gfeat,
                                 fg1_w, fg1_b, fg2_w, fg2_b,
                                 cm_g2s_vw, cm_g2s_vb, cm_g2s_ow, cm_g2s_ob, cm_n1g, cm_n1b,
                                 cm_s2g_vw, cm_s2g_vb, cm_s2g_ow, cm_s2g_ob, cm_n2g, cm_n2b,
                                 r1_w, r1_b, r2_w, r2_b, out);
}

// Round 15
// 533.193 us; speedup vs baseline: 1.4325x; 1.0398x over previous
//
#include <hip/hip_runtime.h>
#include <hip/hip_bf16.h>

// E=128 GH=8 GD=16 GL=3 | SH=4 SD=32 SL=4 | N=32 GC=64 GS=16 DEG=64 BMOL=16
// M_conf=4096 M_scaf=1024 M_tot=5120. All float tensors fp32.
// r14 base (554us: factorized edge + slim attn) + 1024-thread split-K head.

// ---------------------------------------------------------------- shared-mem structs
struct __align__(16) G16Sm   { float Sa[32][20]; float Bs[32][136]; };
struct __align__(16) GAttnSm { float qs[32][17], ksh[32][17], vsh[32][17], ss[32][33], rs[32]; };
struct __align__(16) SAttnSm { float kv[32][33], qs2[32][33], ss2[32][129], red[32][8], red2[32][8]; };
struct __align__(16) TailSm  { float x1[16][132]; float hid[16][260]; float sbuf[4352]; float Sa[32][20]; };
union AttnU { GAttnSm a; SAttnSm s; };

// ---------------------------------------------------------------- LN helper (block of 128 threads)
__device__ __forceinline__ float blk_norm(float v, int e, float* sred)
{
  float s = v;
  #pragma unroll
  for (int o = 1; o < 64; o <<= 1) s += __shfl_xor(s, o);
  if ((e & 63) == 0) sred[e >> 6] = s;
  __syncthreads();
  float mean = (sred[0] + sred[1]) * (1.0f / 128.0f);
  __syncthreads();
  float d = v - mean;
  float s2 = d * d;
  #pragma unroll
  for (int o = 1; o < 64; o <<= 1) s2 += __shfl_xor(s2, o);
  if ((e & 63) == 0) sred[e >> 6] = s2;
  __syncthreads();
  float var = (sred[0] + sred[1]) * (1.0f / 128.0f);
  __syncthreads();
  return d / sqrtf(var + 1e-5f);
}

// ---------------------------------------------------------------- merged front-end (r8, proven)
__global__ __launch_bounds__(256) void front_k(
    const float* __restrict__ cx, const float* __restrict__ sx,
    const float* __restrict__ w, const float* __restrict__ b,
    float* __restrict__ h, float* __restrict__ aggr,
    const float* __restrict__ cpos, const float* __restrict__ spos, float* __restrict__ dist,
    const int* __restrict__ tokens, const float* __restrict__ tok_emb,
    const float* __restrict__ pos_emb, float* __restrict__ xs)
{
  __shared__ float sP[128];
  const int bx = blockIdx.x, tid = threadIdx.x;
  if (bx < 1280) {
    int r = bx * 2 + (tid >> 7), e = tid & 127;
    const float* x = (r < 2048) ? (cx + (size_t)r * 64) : (sx + (size_t)(r - 2048) * 64);
    float* xrow = sP + (tid >> 7) * 64;
    if (e < 64) xrow[e] = x[e];
    __syncthreads();
    float acc = b[e];
    for (int a = 0; a < 64; a++) acc += xrow[a] * w[a * 128 + e];
    h[(size_t)r * 128 + e] = acc;
    aggr[(size_t)r * 128 + e] = 0.0f;
  } else if (bx < 1360) {
    int g = bx - 1280;
    const float* p = (g < 64) ? (cpos + (size_t)g * 96) : (spos + (size_t)(g - 64) * 96);
    if (tid < 96) sP[tid] = p[tid];
    __syncthreads();
    #pragma unroll
    for (int jj = 0; jj < 4; jj++) {
      int idx = tid * 4 + jj;
      int i = idx >> 5, j = idx & 31;
      float dx = sP[i * 3 + 0] - sP[j * 3 + 0];
      float dy = sP[i * 3 + 1] - sP[j * 3 + 1];
      float dz = sP[i * 3 + 2] - sP[j * 3 + 2];
      float d2 = dx * dx + dy * dy + dz * dz;
      dist[(size_t)g * 1024 + idx] = (d2 > 0.0f) ? sqrtf(d2) : 0.0f;
    }
  } else {
    int r = (bx - 1360) * 2 + (tid >> 7), e = tid & 127;
    int tk = tokens[r];
    xs[(size_t)r * 128 + e] = tok_emb[(size_t)tk * 128 + e] + pos_emb[(size_t)(r & 127) * 128 + e];
  }
}

// ---------------------------------------------------------------- EdgeNetwork GEMM (r8 exact — fallback path)
__global__ __launch_bounds__(256) void edge_gemm_k(
    const float* __restrict__ cea, const float* __restrict__ sea,
    const int* __restrict__ cei, const int* __restrict__ sei,
    const float* __restrict__ h,
    const float* __restrict__ elw, const float* __restrict__ elb,
    float* __restrict__ aggr)
{
  __shared__ float efs[32][8];
  __shared__ float As[32][36];
  __shared__ float Bs[32][136];
  const int tid = threadIdx.x;
  const int m0 = blockIdx.x * 32;
  const int kt0 = blockIdx.y * 28;
  const int c0 = kt0 >> 2;
  {
    int t = tid >> 3, cc = tid & 7;
    if (cc < 7) {
      int c = c0 + cc;
      int m = m0 + t;
      const float* attr = (m < 4096) ? (cea + (size_t)m * 17) : (sea + (size_t)(m - 4096) * 17);
      float val;
      if (c < 16) val = attr[c];
      else if (c < 48) {
        float d = fminf(fmaxf(attr[16], 0.0f), 10.0f);
        float t2 = d - (float)((c - 16) * (5.0 / 31.0));
        val = expf(-38.44f * t2 * t2);           // gamma = (31/5)^2
      } else val = 1.0f;
      efs[t][cc] = val;
    }
  }
  const int gk = tid & 31, gt = (tid >> 5) * 4;
  float hreg[4][4];
  #pragma unroll
  for (int i = 0; i < 4; i++) {
    int m = m0 + gt + i;
    int dst = (m < 4096) ? cei[4096 + m] : (sei[1024 + (m - 4096)] + 2048);
    const float* hp = h + (size_t)dst * 128 + gk;
    hreg[i][0] = hp[0]; hreg[i][1] = hp[32]; hreg[i][2] = hp[64]; hreg[i][3] = hp[96];
  }
  const int tn = tid & 31, tm = tid >> 5;
  const int e0 = 4 * tn, t0 = 4 * tm;
  const int se = tid >> 1, sk = (tid & 1) * 16;
  float acc[4][4] = {};
  __syncthreads();
  #pragma unroll 1
  for (int kt = kt0; kt < kt0 + 28; kt++) {
    int c = kt >> 2, cc = c - c0, j = kt & 3;
    float4 av;
    av.x = efs[gt + 0][cc] * hreg[0][j];
    av.y = efs[gt + 1][cc] * hreg[1][j];
    av.z = efs[gt + 2][cc] * hreg[2][j];
    av.w = efs[gt + 3][cc] * hreg[3][j];
    *(float4*)&As[gk][gt] = av;
    const float* bp = ((c < 48) ? (elw + (size_t)c * 16384) : elb) + (size_t)se * 128 + j * 32 + sk;
    float4 w0 = *(const float4*)(bp + 0);
    float4 w1 = *(const float4*)(bp + 4);
    float4 w2 = *(const float4*)(bp + 8);
    float4 w3 = *(const float4*)(bp + 12);
    Bs[sk + 0][se] = w0.x;  Bs[sk + 1][se] = w0.y;  Bs[sk + 2][se] = w0.z;  Bs[sk + 3][se] = w0.w;
    Bs[sk + 4][se] = w1.x;  Bs[sk + 5][se] = w1.y;  Bs[sk + 6][se] = w1.z;  Bs[sk + 7][se] = w1.w;
    Bs[sk + 8][se] = w2.x;  Bs[sk + 9][se] = w2.y;  Bs[sk + 10][se] = w2.z; Bs[sk + 11][se] = w2.w;
    Bs[sk + 12][se] = w3.x; Bs[sk + 13][se] = w3.y; Bs[sk + 14][se] = w3.z; Bs[sk + 15][se] = w3.w;
    __syncthreads();
    #pragma unroll
    for (int kk = 0; kk < 32; kk++) {
      float4 a = *(const float4*)&As[kk][t0];
      float4 b = *(const float4*)&Bs[kk][e0];
      acc[0][0] += a.x * b.x; acc[0][1] += a.x * b.y; acc[0][2] += a.x * b.z; acc[0][3] += a.x * b.w;
      acc[1][0] += a.y * b.x; acc[1][1] += a.y * b.y; acc[1][2] += a.y * b.z; acc[1][3] += a.y * b.w;
      acc[2][0] += a.z * b.x; acc[2][1] += a.z * b.y; acc[2][2] += a.z * b.z; acc[2][3] += a.z * b.w;
      acc[3][0] += a.w * b.x; acc[3][1] += a.w * b.y; acc[3][2] += a.w * b.z; acc[3][3] += a.w * b.w;
    }
    __syncthreads();
  }
  #pragma unroll
  for (int i = 0; i < 4; i++) {
    int m = m0 + t0 + i;
    int src = (m < 4096) ? cei[m] : (sei[m - 4096] + 2048);
    float* dst = aggr + (size_t)src * 128 + e0;
    atomicAdd(dst + 0, acc[i][0]);
    atomicAdd(dst + 1, acc[i][1]);
    atomicAdd(dst + 2, acc[i][2]);
    atomicAdd(dst + 3, acc[i][3]);
  }
}

// ---------------------------------------------------------------- node GEMM: G[n][c*128+e] = sum_f W_c[e][f] h[n][f]
__global__ __launch_bounds__(256) void node_gemm_k(
    const float* __restrict__ h, const float* __restrict__ elw, const float* __restrict__ elb,
    float* __restrict__ G)
{
  __shared__ float As[32][36];
  __shared__ float Bs[32][136];
  const int tid = threadIdx.x;
  const int n0 = blockIdx.x * 32;
  const int c = blockIdx.y;
  const float* W = (c < 48) ? (elw + (size_t)c * 16384) : elb;
  const int gk = tid & 31, gt = (tid >> 5) * 4;
  float hreg[4][4];
  #pragma unroll
  for (int i = 0; i < 4; i++) {
    const float* hp = h + (size_t)(n0 + gt + i) * 128 + gk;
    hreg[i][0] = hp[0]; hreg[i][1] = hp[32]; hreg[i][2] = hp[64]; hreg[i][3] = hp[96];
  }
  const int tn = tid & 31, tm = tid >> 5;
  const int e0 = 4 * tn, t0 = 4 * tm;
  const int se = tid >> 1, sk = (tid & 1) * 16;
  float acc[4][4] = {};
  #pragma unroll 1
  for (int j = 0; j < 4; j++) {
    float4 av;
    av.x = hreg[0][j]; av.y = hreg[1][j]; av.z = hreg[2][j]; av.w = hreg[3][j];
    *(float4*)&As[gk][gt] = av;
    const float* bp = W + (size_t)se * 128 + j * 32 + sk;
    float4 w0 = *(const float4*)(bp + 0);
    float4 w1 = *(const float4*)(bp + 4);
    float4 w2 = *(const float4*)(bp + 8);
    float4 w3 = *(const float4*)(bp + 12);
    Bs[sk + 0][se] = w0.x;  Bs[sk + 1][se] = w0.y;  Bs[sk + 2][se] = w0.z;  Bs[sk + 3][se] = w0.w;
    Bs[sk + 4][se] = w1.x;  Bs[sk + 5][se] = w1.y;  Bs[sk + 6][se] = w1.z;  Bs[sk + 7][se] = w1.w;
    Bs[sk + 8][se] = w2.x;  Bs[sk + 9][se] = w2.y;  Bs[sk + 10][se] = w2.z; Bs[sk + 11][se] = w2.w;
    Bs[sk + 12][se] = w3.x; Bs[sk + 13][se] = w3.y; Bs[sk + 14][se] = w3.z; Bs[sk + 15][se] = w3.w;
    __syncthreads();
    #pragma unroll
    for (int kk = 0; kk < 32; kk++) {
      float4 a = *(const float4*)&As[kk][t0];
      float4 b = *(const float4*)&Bs[kk][e0];
      acc[0][0] += a.x * b.x; acc[0][1] += a.x * b.y; acc[0][2] += a.x * b.z; acc[0][3] += a.x * b.w;
      acc[1][0] += a.y * b.x; acc[1][1] += a.y * b.y; acc[1][2] += a.y * b.z; acc[1][3] += a.y * b.w;
      acc[2][0] += a.z * b.x; acc[2][1] += a.z * b.y; acc[2][2] += a.z * b.z; acc[2][3] += a.z * b.w;
      acc[3][0] += a.w * b.x; acc[3][1] += a.w * b.y; acc[3][2] += a.w * b.z; acc[3][3] += a.w * b.w;
    }
    __syncthreads();
  }
  #pragma unroll
  for (int i = 0; i < 4; i++) {
    float4 cv;
    cv.x = acc[i][0]; cv.y = acc[i][1]; cv.z = acc[i][2]; cv.w = acc[i][3];
    *(float4*)(G + (size_t)(n0 + t0 + i) * 6272 + c * 128 + e0) = cv;
  }
}

// ---------------------------------------------------------------- combine: msg[m,e] = sum_c ef[m,c]*G[dst[m]][c*128+e]
__global__ __launch_bounds__(256) void combine_k(
    const float* __restrict__ cea, const float* __restrict__ sea,
    const int* __restrict__ cei, const int* __restrict__ sei,
    const float* __restrict__ G, float* __restrict__ aggr)
{
  __shared__ float efs[4][52];
  __shared__ int srcs[4], dsts[4];
  const int tid = threadIdx.x;
  const int m0 = blockIdx.x * 4;
  if (tid < 4) {
    int m = m0 + tid;
    int src, dst;
    if (m < 4096) { src = cei[m]; dst = cei[4096 + m]; }
    else { src = sei[m - 4096] + 2048; dst = sei[1024 + (m - 4096)] + 2048; }
    srcs[tid] = src; dsts[tid] = dst;
  }
  if (tid < 196) {
    int t = tid / 49, cc = tid - t * 49;
    int m = m0 + t;
    const float* attr = (m < 4096) ? (cea + (size_t)m * 17) : (sea + (size_t)(m - 4096) * 17);
    float val;
    if (cc < 16) val = attr[cc];
    else if (cc < 48) {
      float d = fminf(fmaxf(attr[16], 0.0f), 10.0f);
      float t2 = d - (float)((cc - 16) * (5.0 / 31.0));
      val = expf(-38.44f * t2 * t2);
    } else val = 1.0f;
    efs[t][cc] = val;
  }
  __syncthreads();
  const int e = tid & 127, half = tid >> 7;
  #pragma unroll
  for (int tt = 0; tt < 2; tt++) {
    int t = half * 2 + tt;
    const float* gp = G + (size_t)dsts[t] * 6272 + e;
    float acc = 0;
    #pragma unroll 7
    for (int c = 0; c < 49; c++) acc += efs[t][c] * gp[(size_t)c * 128];
    atomicAdd(aggr + (size_t)srcs[t] * 128 + e, acc);
  }
}

// ---------------------------------------------------------------- BM=16 GEMM body (K=128), barrier-staged
__device__ __forceinline__ void gemm16_body(G16Sm& sm,
    const float* __restrict__ A, const float* __restrict__ Bp,
    const float* __restrict__ biasp, float* __restrict__ Cp,
    int row0, int ldb, int ldc)
{
  const int tid = threadIdx.x;
  const int tm = tid >> 5, tn = tid & 31;
  const int t0 = 2 * tm, e0 = 4 * tn;
  const int ar = tid >> 4, ak = (tid & 15) * 2;
  const int bk = tid >> 3, be = (tid & 7) * 16;
  float acc[2][4] = {};
  for (int k0 = 0; k0 < 128; k0 += 32) {
    float2 av = *(const float2*)(A + (size_t)(row0 + ar) * 128 + k0 + ak);
    sm.Sa[ak][ar] = av.x; sm.Sa[ak + 1][ar] = av.y;
    const float* bp = Bp + (size_t)(k0 + bk) * ldb + be;
    float4 b0v = *(const float4*)(bp + 0);
    float4 b1v = *(const float4*)(bp + 4);
    float4 b2v = *(const float4*)(bp + 8);
    float4 b3v = *(const float4*)(bp + 12);
    sm.Bs[bk][be + 0] = b0v.x;  sm.Bs[bk][be + 1] = b0v.y;  sm.Bs[bk][be + 2] = b0v.z;  sm.Bs[bk][be + 3] = b0v.w;
    sm.Bs[bk][be + 4] = b1v.x;  sm.Bs[bk][be + 5] = b1v.y;  sm.Bs[bk][be + 6] = b1v.z;  sm.Bs[bk][be + 7] = b1v.w;
    sm.Bs[bk][be + 8] = b2v.x;  sm.Bs[bk][be + 9] = b2v.y;  sm.Bs[bk][be + 10] = b2v.z; sm.Bs[bk][be + 11] = b2v.w;
    sm.Bs[bk][be + 12] = b3v.x; sm.Bs[bk][be + 13] = b3v.y; sm.Bs[bk][be + 14] = b3v.z; sm.Bs[bk][be + 15] = b3v.w;
    __syncthreads();
    #pragma unroll
    for (int kk = 0; kk < 32; kk++) {
      float2 a = *(const float2*)&sm.Sa[kk][t0];
      float4 b = *(const float4*)&sm.Bs[kk][e0];
      acc[0][0] += a.x * b.x; acc[0][1] += a.x * b.y; acc[0][2] += a.x * b.z; acc[0][3] += a.x * b.w;
      acc[1][0] += a.y * b.x; acc[1][1] += a.y * b.y; acc[1][2] += a.y * b.z; acc[1][3] += a.y * b.w;
    }
    __syncthreads();
  }
  #pragma unroll
  for (int i = 0; i < 2; i++) {
    float* cp = Cp + (size_t)(row0 + t0 + i) * ldc + e0;
    #pragma unroll
    for (int j = 0; j < 4; j++) cp[j] = acc[i][j] + biasp[e0 + j];
  }
}

// ---------------------------------------------------------------- merged QKV: graph (3x160) + seq (3x128)
__global__ __launch_bounds__(256) void qkv_k(
    int gBlocks,
    const float* __restrict__ ghb,
    const float* gqw, const float* gkw, const float* gvw,
    const float* gqb, const float* gkb, const float* gvb, float* gout,
    const float* __restrict__ sxs, const float* sw, const float* sb, float* sout)
{
  __shared__ G16Sm sm;
  int bx = blockIdx.x;
  if (bx < gBlocks) {
    int z = bx / 160, rt = bx % 160;
    const float* B = (z == 0) ? gqw : (z == 1) ? gkw : gvw;
    const float* bias = (z == 0) ? gqb : (z == 1) ? gkb : gvb;
    gemm16_body(sm, ghb, B, bias, gout + (size_t)z * 327680, rt * 16, 128, 128);
  } else {
    int i = bx - gBlocks;
    int z = i >> 7, rt = i & 127;
    gemm16_body(sm, sxs, sw + z * 128, sb + z * 128, sout + z * 128, rt * 16, 384, 384);
  }
}

// ---------------------------------------------------------------- graph attention body (N=32, GD=16)
__device__ __forceinline__ void gattn_body(GAttnSm& sm, int g, int h,
    const float* __restrict__ q, const float* __restrict__ k,
    const float* __restrict__ v, const float* __restrict__ dist, float* __restrict__ o)
{
  const int tid = threadIdx.x;
  {
    int idx = tid * 2;
    int i = idx >> 4, d = idx & 15;
    size_t base = ((size_t)(g * 32 + i)) * 128 + h * 16 + d;
    sm.qs[i][d] = q[base];  sm.qs[i][d + 1] = q[base + 1];
    sm.ksh[i][d] = k[base]; sm.ksh[i][d + 1] = k[base + 1];
    sm.vsh[i][d] = v[base]; sm.vsh[i][d + 1] = v[base + 1];
  }
  __syncthreads();
  {
    int i = tid >> 3, j0 = (tid & 7) * 4;
    for (int j = j0; j < j0 + 4; j++) {
      float a = 0;
      #pragma unroll
      for (int d = 0; d < 16; d++) a += sm.qs[i][d] * sm.ksh[j][d];
      a = a * 0.25f + dist[(size_t)g * 1024 + i * 32 + j];
      sm.ss[i][j] = fminf(fmaxf(a, -10.0f), 10.0f);
    }
  }
  __syncthreads();
  if (tid < 32) {
    float m = -1e30f;
    for (int j = 0; j < 32; j++) m = fmaxf(m, sm.ss[tid][j]);
    float s = 0;
    for (int j = 0; j < 32; j++) { float ex = expf(sm.ss[tid][j] - m); sm.ss[tid][j] = ex; s += ex; }
    sm.rs[tid] = 1.0f / s;
  }
  __syncthreads();
  {
    int idx = tid * 2;
    int i = idx >> 4, d = idx & 15;
    float a0 = 0, a1 = 0;
    for (int j = 0; j < 32; j++) { float wj = sm.ss[i][j]; a0 += wj * sm.vsh[j][d]; a1 += wj * sm.vsh[j][d + 1]; }
    float r = sm.rs[i];
    size_t base = ((size_t)(g * 32 + i)) * 128 + h * 16 + d;
    o[base] = a0 * r; o[base + 1] = a1 * r;
  }
}

// ---------------------------------------------------------------- seq attention body (slim, K/V tiled)
__device__ __forceinline__ void sattn_body(SAttnSm& sm, int b, int h, int qt,
    const float* __restrict__ qkv, float* __restrict__ o)
{
  const int tid = threadIdx.x;
  {
    int i = tid >> 3, d0 = (tid & 7) * 4;
    const float* qp = qkv + ((size_t)(b * 128 + qt * 32 + i)) * 384 + h * 32 + d0;
    sm.qs2[i][d0 + 0] = qp[0]; sm.qs2[i][d0 + 1] = qp[1];
    sm.qs2[i][d0 + 2] = qp[2]; sm.qs2[i][d0 + 3] = qp[3];
  }
  const int i = tid >> 3, sub = tid & 7;
  for (int jt = 0; jt < 4; jt++) {
    {
      int r = tid >> 3, dd = (tid & 7) * 4;
      const float* kp = qkv + ((size_t)(b * 128 + jt * 32 + r)) * 384 + 128 + h * 32 + dd;
      float4 kv4 = *(const float4*)kp;
      sm.kv[r][dd + 0] = kv4.x; sm.kv[r][dd + 1] = kv4.y;
      sm.kv[r][dd + 2] = kv4.z; sm.kv[r][dd + 3] = kv4.w;
    }
    __syncthreads();
    {
      int j0 = jt * 32 + sub * 4;
      for (int j = j0; j < j0 + 4; j++) {
        int jr = j - jt * 32;
        float a = 0;
        #pragma unroll
        for (int d = 0; d < 32; d++) a += sm.qs2[i][d] * sm.kv[jr][d];
        sm.ss2[i][j] = a * 0.17677669529663687f;
      }
    }
    __syncthreads();
  }
  float m = -1e30f;
  for (int j = sub; j < 128; j += 8) m = fmaxf(m, sm.ss2[i][j]);
  sm.red[i][sub] = m;
  __syncthreads();
  float mm = sm.red[i][0];
  #pragma unroll
  for (int t = 1; t < 8; t++) mm = fmaxf(mm, sm.red[i][t]);
  float ps = 0;
  for (int j = sub; j < 128; j += 8) { float ex = expf(sm.ss2[i][j] - mm); sm.ss2[i][j] = ex; ps += ex; }
  sm.red2[i][sub] = ps;
  __syncthreads();
  float s = 0;
  #pragma unroll
  for (int t = 0; t < 8; t++) s += sm.red2[i][t];
  float rinv = 1.0f / s;
  float a0 = 0, a1 = 0, a2 = 0, a3 = 0;
  const int d0 = sub * 4;
  for (int jt = 0; jt < 4; jt++) {
    __syncthreads();
    {
      int r = tid >> 3, dd = (tid & 7) * 4;
      const float* vp = qkv + ((size_t)(b * 128 + jt * 32 + r)) * 384 + 256 + h * 32 + dd;
      float4 vv = *(const float4*)vp;
      sm.kv[r][dd + 0] = vv.x; sm.kv[r][dd + 1] = vv.y;
      sm.kv[r][dd + 2] = vv.z; sm.kv[r][dd + 3] = vv.w;
    }
    __syncthreads();
    for (int jr = 0; jr < 32; jr++) {
      float wj = sm.ss2[i][jt * 32 + jr];
      a0 += wj * sm.kv[jr][d0 + 0]; a1 += wj * sm.kv[jr][d0 + 1];
      a2 += wj * sm.kv[jr][d0 + 2]; a3 += wj * sm.kv[jr][d0 + 3];
    }
  }
  float* op = o + ((size_t)(b * 128 + qt * 32 + i)) * 128 + h * 32 + d0;
  op[0] = a0 * rinv; op[1] = a1 * rinv; op[2] = a2 * rinv; op[3] = a3 * rinv;
}

// ---------------------------------------------------------------- merged attention: graph + seq (union LDS)
__global__ __launch_bounds__(256) void attn_k(
    int gBlocks, const float* q, const float* k, const float* v,
    const float* dist, float* go, const float* qkv, float* so)
{
  __shared__ AttnU u;
  int bx = blockIdx.x;
  if (bx < gBlocks) gattn_body(u.a, bx >> 3, bx & 7, q, k, v, dist, go);
  else { int i = bx - gBlocks; sattn_body(u.s, i >> 4, (i >> 2) & 3, i & 3, qkv, so); }
}

// ---------------------------------------------------------------- layer tail body (barrier-staged)
__device__ __forceinline__ void tail_body(TailSm& sm, int row0, const float* __restrict__ A,
    const float* __restrict__ Wo, const float* __restrict__ bo, const float* __restrict__ res,
    const float* __restrict__ g1, const float* __restrict__ b1n,
    const float* __restrict__ W1, const float* __restrict__ b1f,
    const float* __restrict__ W2, const float* __restrict__ b2f,
    const float* __restrict__ g2, const float* __restrict__ b2n,
    float* __restrict__ Out)
{
  float (*BsA)[136] = (float(*)[136])sm.sbuf;
  float (*Bs1)[260] = (float(*)[260])sm.sbuf;
  float (*Bs2)[136] = (float(*)[136])sm.sbuf;
  const int tid = threadIdx.x;
  // ---- stage A: x1 = LN(A@Wo + bo + res) ----
  {
    const int tm = tid >> 5, tn = tid & 31;
    const int t0 = 2 * tm, e0 = 4 * tn;
    const int ar = tid >> 4, ak = (tid & 15) * 2;
    const int bk = tid >> 3, be = (tid & 7) * 16;
    float acc[2][4] = {};
    for (int k0 = 0; k0 < 128; k0 += 32) {
      float2 av = *(const float2*)(A + (size_t)(row0 + ar) * 128 + k0 + ak);
      sm.Sa[ak][ar] = av.x; sm.Sa[ak + 1][ar] = av.y;
      const float* bp = Wo + (size_t)(k0 + bk) * 128 + be;
      float4 b0v = *(const float4*)(bp + 0);
      float4 b1v = *(const float4*)(bp + 4);
      float4 b2v = *(const float4*)(bp + 8);
      float4 b3v = *(const float4*)(bp + 12);
      BsA[bk][be + 0] = b0v.x;  BsA[bk][be + 1] = b0v.y;  BsA[bk][be + 2] = b0v.z;  BsA[bk][be + 3] = b0v.w;
      BsA[bk][be + 4] = b1v.x;  BsA[bk][be + 5] = b1v.y;  BsA[bk][be + 6] = b1v.z;  BsA[bk][be + 7] = b1v.w;
      BsA[bk][be + 8] = b2v.x;  BsA[bk][be + 9] = b2v.y;  BsA[bk][be + 10] = b2v.z; BsA[bk][be + 11] = b2v.w;
      BsA[bk][be + 12] = b3v.x; BsA[bk][be + 13] = b3v.y; BsA[bk][be + 14] = b3v.z; BsA[bk][be + 15] = b3v.w;
      __syncthreads();
      #pragma unroll
      for (int kk = 0; kk < 32; kk++) {
        float2 a = *(const float2*)&sm.Sa[kk][t0];
        float4 b = *(const float4*)&BsA[kk][e0];
        acc[0][0] += a.x * b.x; acc[0][1] += a.x * b.y; acc[0][2] += a.x * b.z; acc[0][3] += a.x * b.w;
        acc[1][0] += a.y * b.x; acc[1][1] += a.y * b.y; acc[1][2] += a.y * b.z; acc[1][3] += a.y * b.w;
      }
      __syncthreads();
    }
    #pragma unroll
    for (int i = 0; i < 2; i++) {
      int r = row0 + t0 + i;
      float v0 = acc[i][0] + bo[e0 + 0] + res[(size_t)r * 128 + e0 + 0];
      float v1 = acc[i][1] + bo[e0 + 1] + res[(size_t)r * 128 + e0 + 1];
      float v2 = acc[i][2] + bo[e0 + 2] + res[(size_t)r * 128 + e0 + 2];
      float v3 = acc[i][3] + bo[e0 + 3] + res[(size_t)r * 128 + e0 + 3];
      float s = v0 + v1 + v2 + v3;
      #pragma unroll
      for (int o = 1; o < 32; o <<= 1) s += __shfl_xor(s, o);
      float mean = s * (1.0f / 128.0f);
      float d0 = v0 - mean, d1 = v1 - mean, d2 = v2 - mean, d3 = v3 - mean;
      float sq = d0 * d0 + d1 * d1 + d2 * d2 + d3 * d3;
      #pragma unroll
      for (int o = 1; o < 32; o <<= 1) sq += __shfl_xor(sq, o);
      float rstd = 1.0f / sqrtf(sq * (1.0f / 128.0f) + 1e-5f);
      sm.x1[t0 + i][e0 + 0] = d0 * rstd * g1[e0 + 0] + b1n[e0 + 0];
      sm.x1[t0 + i][e0 + 1] = d1 * rstd * g1[e0 + 1] + b1n[e0 + 1];
      sm.x1[t0 + i][e0 + 2] = d2 * rstd * g1[e0 + 2] + b1n[e0 + 2];
      sm.x1[t0 + i][e0 + 3] = d3 * rstd * g1[e0 + 3] + b1n[e0 + 3];
    }
  }
  __syncthreads();
  // ---- stage B: hid = relu(x1 @ W1 + b1f), 16x256 ----
  {
    const int tm = tid >> 6, tn = tid & 63;
    const int t0 = 4 * tm, e0 = 4 * tn;
    const int ar = tid >> 4, ak = tid & 15;
    const int bk = tid >> 4, be = (tid & 15) * 16;
    float acc[4][4] = {};
    for (int k0 = 0; k0 < 128; k0 += 16) {
      sm.Sa[ak][ar] = sm.x1[ar][k0 + ak];
      const float* bp = W1 + (size_t)(k0 + bk) * 256 + be;
      float4 b0v = *(const float4*)(bp + 0);
      float4 b1v = *(const float4*)(bp + 4);
      float4 b2v = *(const float4*)(bp + 8);
      float4 b3v = *(const float4*)(bp + 12);
      Bs1[bk][be + 0] = b0v.x;  Bs1[bk][be + 1] = b0v.y;  Bs1[bk][be + 2] = b0v.z;  Bs1[bk][be + 3] = b0v.w;
      Bs1[bk][be + 4] = b1v.x;  Bs1[bk][be + 5] = b1v.y;  Bs1[bk][be + 6] = b1v.z;  Bs1[bk][be + 7] = b1v.w;
      Bs1[bk][be + 8] = b2v.x;  Bs1[bk][be + 9] = b2v.y;  Bs1[bk][be + 10] = b2v.z; Bs1[bk][be + 11] = b2v.w;
      Bs1[bk][be + 12] = b3v.x; Bs1[bk][be + 13] = b3v.y; Bs1[bk][be + 14] = b3v.z; Bs1[bk][be + 15] = b3v.w;
      __syncthreads();
      #pragma unroll
      for (int kk = 0; kk < 16; kk++) {
        float4 a = *(const float4*)&sm.Sa[kk][t0];
        float4 b = *(const float4*)&Bs1[kk][e0];
        acc[0][0] += a.x * b.x; acc[0][1] += a.x * b.y; acc[0][2] += a.x * b.z; acc[0][3] += a.x * b.w;
        acc[1][0] += a.y * b.x; acc[1][1] += a.y * b.y; acc[1][2] += a.y * b.z; acc[1][3] += a.y * b.w;
        acc[2][0] += a.z * b.x; acc[2][1] += a.z * b.y; acc[2][2] += a.z * b.z; acc[2][3] += a.z * b.w;
        acc[3][0] += a.w * b.x; acc[3][1] += a.w * b.y; acc[3][2] += a.w * b.z; acc[3][3] += a.w * b.w;
      }
      __syncthreads();
    }
    #pragma unroll
    for (int i = 0; i < 4; i++) {
      float4 hv;
      hv.x = fmaxf(acc[i][0] + b1f[e0 + 0], 0.0f);
      hv.y = fmaxf(acc[i][1] + b1f[e0 + 1], 0.0f);
      hv.z = fmaxf(acc[i][2] + b1f[e0 + 2], 0.0f);
      hv.w = fmaxf(acc[i][3] + b1f[e0 + 3], 0.0f);
      *(float4*)&sm.hid[t0 + i][e0] = hv;
    }
  }
  __syncthreads();
  // ---- stage C: Out = LN(hid@W2 + b2f + x1) ----
  {
    const int tm = tid >> 5, tn = tid & 31;
    const int t0 = 2 * tm, e0 = 4 * tn;
    const int bk = tid >> 3, be = (tid & 7) * 16;
    float acc[2][4] = {};
    for (int k0 = 0; k0 < 256; k0 += 32) {
      const float* bp = W2 + (size_t)(k0 + bk) * 128 + be;
      float4 b0v = *(const float4*)(bp + 0);
      float4 b1v = *(const float4*)(bp + 4);
      float4 b2v = *(const float4*)(bp + 8);
      float4 b3v = *(const float4*)(bp + 12);
      Bs2[bk][be + 0] = b0v.x;  Bs2[bk][be + 1] = b0v.y;  Bs2[bk][be + 2] = b0v.z;  Bs2[bk][be + 3] = b0v.w;
      Bs2[bk][be + 4] = b1v.x;  Bs2[bk][be + 5] = b1v.y;  Bs2[bk][be + 6] = b1v.z;  Bs2[bk][be + 7] = b1v.w;
      Bs2[bk][be + 8] = b2v.x;  Bs2[bk][be + 9] = b2v.y;  Bs2[bk][be + 10] = b2v.z; Bs2[bk][be + 11] = b2v.w;
      Bs2[bk][be + 12] = b3v.x; Bs2[bk][be + 13] = b3v.y; Bs2[bk][be + 14] = b3v.z; Bs2[bk][be + 15] = b3v.w;
      __syncthreads();
      #pragma unroll
      for (int kk = 0; kk < 32; kk++) {
        float a0 = sm.hid[t0 + 0][k0 + kk];
        float a1 = sm.hid[t0 + 1][k0 + kk];
        float4 b = *(const float4*)&Bs2[kk][e0];
        acc[0][0] += a0 * b.x; acc[0][1] += a0 * b.y; acc[0][2] += a0 * b.z; acc[0][3] += a0 * b.w;
        acc[1][0] += a1 * b.x; acc[1][1] += a1 * b.y; acc[1][2] += a1 * b.z; acc[1][3] += a1 * b.w;
      }
      __syncthreads();
    }
    #pragma unroll
    for (int i = 0; i < 2; i++) {
      int r = row0 + t0 + i;
      float v0 = acc[i][0] + b2f[e0 + 0] + sm.x1[t0 + i][e0 + 0];
      float v1 = acc[i][1] + b2f[e0 + 1] + sm.x1[t0 + i][e0 + 1];
      float v2 = acc[i][2] + b2f[e0 + 2] + sm.x1[t0 + i][e0 + 2];
      float v3 = acc[i][3] + b2f[e0 + 3] + sm.x1[t0 + i][e0 + 3];
      float s = v0 + v1 + v2 + v3;
      #pragma unroll
      for (int o = 1; o < 32; o <<= 1) s += __shfl_xor(s, o);
      float mean = s * (1.0f / 128.0f);
      float d0 = v0 - mean, d1 = v1 - mean, d2 = v2 - mean, d3 = v3 - mean;
      float sq = d0 * d0 + d1 * d1 + d2 * d2 + d3 * d3;
      #pragma unroll
      for (int o = 1; o < 32; o <<= 1) sq += __shfl_xor(sq, o);
      float rstd = 1.0f / sqrtf(sq * (1.0f / 128.0f) + 1e-5f);
      float* cp = Out + (size_t)r * 128 + e0;
      cp[0] = d0 * rstd * g2[e0 + 0] + b2n[e0 + 0];
      cp[1] = d1 * rstd * g2[e0 + 1] + b2n[e0 + 1];
      cp[2] = d2 * rstd * g2[e0 + 2] + b2n[e0 + 2];
      cp[3] = d3 * rstd * g2[e0 + 3] + b2n[e0 + 3];
    }
  }
}

// ---------------------------------------------------------------- merged tail: graph + seq
__global__ __launch_bounds__(256) void tail_k(
    int gBlocks,
    const float* gA, const float* gWo, const float* gbo, const float* gres,
    const float* gg1, const float* gb1, const float* gW1, const float* gbf1,
    const float* gW2, const float* gbf2, const float* gg2, const float* gb2, float* gOut,
    const float* sA, const float* sWo, const float* sbo, const float* sres,
    const float* sg1, const float* sb1, const float* sW1, const float* sbf1,
    const float* sW2, const float* sbf2, const float* sg2, const float* sb2, float* sOut)
{
  __shared__ TailSm sm;
  int bx = blockIdx.x;
  if (bx < gBlocks)
    tail_body(sm, bx * 16, gA, gWo, gbo, gres, gg1, gb1, gW1, gbf1, gW2, gbf2, gg2, gb2, gOut);
  else
    tail_body(sm, (bx - gBlocks) * 16, sA, sWo, sbo, sres, sg1, sb1, sW1, sbf1, sW2, sbf2, sg2, sb2, sOut);
}

// ---------------------------------------------------------------- LayerNorm rows of 128 (after edge aggr)
__global__ __launch_bounds__(128) void ln_k(
    const float* __restrict__ x, const float* __restrict__ res,
    const float* __restrict__ g, const float* __restrict__ b, float* __restrict__ out)
{
  __shared__ float sred[2];
  int r = blockIdx.x, e = threadIdx.x;
  size_t idx = (size_t)r * 128 + e;
  float v = x[idx] + res[idx];
  float nv = blk_norm(v, e, sred);
  out[idx] = nv * g[e] + b[e];
}

// ---------------------------------------------------------------- 1024-thread split-K head
// tid = (q<<7)|e, q in [0,8). Matvec K=128: thread (e,q) sums 16 f's; reduce via red[8][128].
__global__ __launch_bounds__(1024) void head_k(
    const float* __restrict__ hb, const float* __restrict__ xs, const float* __restrict__ gfeat,
    const float* fg1w, const float* fg1b, const float* fg2w, const float* fg2b,
    const float* g2s_vw, const float* g2s_vb, const float* g2s_ow, const float* g2s_ob,
    const float* n1g, const float* n1b,
    const float* s2g_vw, const float* s2g_vb, const float* s2g_ow, const float* s2g_ob,
    const float* n2g, const float* n2b,
    const float* r1w, const float* r1b, const float* r2w, const float* r2b,
    float* __restrict__ out)
{
  __shared__ float T[128], S[128], Gv[128], Sm[128], t1[128], tmp[128], gh[64];
  __shared__ float red[16][128];
  __shared__ float sredA[2], sredB[2];
  const int mol = blockIdx.x, tid = threadIdx.x;
  const int e = tid & 127, q = tid >> 7;            // q in [0,8)
  // ---- pooling: T (conf mean + scaf mean), S (seq mean), 8-way split ----
  {
    float cs = 0;
    const float* cp = hb + ((size_t)(mol * 128 + q * 16)) * 128 + e;
    #pragma unroll
    for (int i = 0; i < 16; i++) cs += cp[(size_t)i * 128];
    float ss = 0;
    const float* sp = hb + ((size_t)((64 + mol) * 32 + q * 4)) * 128 + e;
    #pragma unroll
    for (int i = 0; i < 4; i++) ss += sp[(size_t)i * 128];
    red[q][e] = cs; red[8 + q][e] = ss;
  }
  __syncthreads();
  if (q == 0) {
    float cs = 0, ss = 0;
    #pragma unroll
    for (int r = 0; r < 8; r++) { cs += red[r][e]; ss += red[8 + r][e]; }
    T[e] = cs * (1.0f / 128.0f) + ss * (1.0f / 32.0f);
  }
  __syncthreads();
  {
    float xsum = 0;
    const float* xp = xs + ((size_t)(mol * 128 + q * 16)) * 128 + e;
    #pragma unroll
    for (int i = 0; i < 16; i++) xsum += xp[(size_t)i * 128];
    red[q][e] = xsum;
  }
  __syncthreads();
  if (q == 0) {
    float xsum = 0;
    #pragma unroll
    for (int r = 0; r < 8; r++) xsum += red[r][e];
    S[e] = xsum * (1.0f / 128.0f);
  }
  __syncthreads();
  // ---- fg1: gh[64] = relu(fg1b + [T;S] @ fg1w), K=256, 16-way split on 64 outputs ----
  {
    const int e6 = tid & 63, q16 = tid >> 6;        // q16 in [0,16)
    float partial = 0;
    #pragma unroll
    for (int i = 0; i < 16; i++) {
      int f = q16 * 16 + i;
      float inv = (f < 128) ? T[f] : S[f - 128];
      partial += inv * fg1w[f * 64 + e6];
    }
    red[q16][e6] = partial;
  }
  __syncthreads();
  if (tid < 64) {
    float a = fg1b[tid];
    #pragma unroll
    for (int r = 0; r < 16; r++) a += red[r][tid];
    gh[tid] = fmaxf(a, 0.0f);
  }
  __syncthreads();
  // ---- gate: K=64, 8-way split ----
  {
    float partial = 0;
    #pragma unroll
    for (int i = 0; i < 8; i++) { int f = q * 8 + i; partial += gh[f] * fg2w[f * 128 + e]; }
    red[q][e] = partial;
  }
  __syncthreads();
  if (q == 0) {
    float a = fg2b[e];
    #pragma unroll
    for (int r = 0; r < 8; r++) a += red[r][e];
    float gate = 1.0f / (1.0f + expf(-a));
    float fu = gate * T[e] + (1.0f - gate) * S[e];
    Gv[e] = fu; Sm[e] = fu;
  }
  __syncthreads();
  // ---- cross-modal: 2 layers x (vproj, oproj, LN) x 2 streams ----
  for (int l = 0; l < 2; l++) {
    const float* mats[4] = { g2s_vw + (size_t)l * 16384, g2s_ow + (size_t)l * 16384,
                             s2g_vw + (size_t)l * 16384, s2g_ow + (size_t)l * 16384 };
    const float* biases[4] = { g2s_vb + l * 128, g2s_ob + l * 128, s2g_vb + l * 128, s2g_ob + l * 128 };
    #pragma unroll 1
    for (int st = 0; st < 4; st++) {
      const float* inv = (st == 0) ? Sm : (st == 1) ? t1 : (st == 2) ? Gv : t1;
      float* outv = (st == 0 || st == 2) ? t1 : tmp;
      const float* W = mats[st];
      float partial = 0;
      #pragma unroll
      for (int i = 0; i < 16; i++) { int f = q * 16 + i; partial += inv[f] * W[f * 128 + e]; }
      red[q][e] = partial;
      __syncthreads();
      if (q == 0) {
        float a = biases[st][e];
        #pragma unroll
        for (int r = 0; r < 8; r++) a += red[r][e];
        outv[e] = a;
      }
      __syncthreads();
      if (st == 1 || st == 3) {
        // LN(residual + tmp) into Gv (st==1) or Sm (st==3)
        float* vec = (st == 1) ? Gv : Sm;
        const float* gg = (st == 1) ? (n1g + l * 128) : (n2g + l * 128);
        const float* bb = (st == 1) ? (n1b + l * 128) : (n2b + l * 128);
        float v = 0, d = 0;
        if (tid < 128) {
          v = vec[tid] + tmp[tid];
          float s = v;
          #pragma unroll
          for (int o = 1; o < 64; o <<= 1) s += __shfl_xor(s, o);
          if ((tid & 63) == 0) sredA[tid >> 6] = s;
        }
        __syncthreads();
        float mean = (sredA[0] + sredA[1]) * (1.0f / 128.0f);
        if (tid < 128) {
          d = v - mean;
          float s2 = d * d;
          #pragma unroll
          for (int o = 1; o < 64; o <<= 1) s2 += __shfl_xor(s2, o);
          if ((tid & 63) == 0) sredB[tid >> 6] = s2;
        }
        __syncthreads();
        if (tid < 128) {
          float var = (sredB[0] + sredB[1]) * (1.0f / 128.0f);
          vec[tid] = (d / sqrtf(var + 1e-5f)) * gg[tid] + bb[tid];
        }
        __syncthreads();
      }
    }
  }
  // ---- final = 0.5*(G+Sm); a = relu(r1b + final@r1w + gfeat terms); p = sum a*r2w ----
  if (tid < 128) tmp[tid] = 0.5f * (Gv[tid] + Sm[tid]);
  __syncthreads();
  {
    float partial = 0;
    #pragma unroll
    for (int i = 0; i < 16; i++) { int f = q * 16 + i; partial += tmp[f] * r1w[f * 128 + e]; }
    red[q][e] = partial;
  }
  __syncthreads();
  if (q == 0) {
    float a = r1b[e];
    #pragma unroll
    for (int r = 0; r < 8; r++) a += red[r][e];
    #pragma unroll
    for (int f = 0; f < 3; f++) a += gfeat[mol * 3 + f] * r1w[(128 + f) * 128 + e];
    t1[e] = fmaxf(a, 0.0f);
  }
  __syncthreads();
  {
    float p = 0;
    if (tid < 128) {
      p = t1[tid] * r2w[tid];
      #pragma unroll
      for (int o = 1; o < 64; o <<= 1) p += __shfl_xor(p, o);
      if ((tid & 63) == 0) sredA[tid >> 6] = p;
    }
    __syncthreads();
    if (tid == 0) out[mol] = sredA[0] + sredA[1] + r2b[0];
  }
}

// ================================================================ host
extern "C" void kernel_launch(void* const* d_in, const int* in_sizes, int n_in,
                              void* d_out, int out_size, void* d_ws, size_t ws_size,
                              hipStream_t stream)
{
  (void)n_in; (void)out_size;
  const bool dict = (in_sizes[1] == 8192);
  auto IN = [&](int di, int si) { return d_in[dict ? di : si]; };

  const float* conf_x   = (const float*)IN(0, 0);
  const int*   conf_ei  = (const int*)  IN(1, 63);
  const float* conf_ea  = (const float*)IN(2, 1);
  const float* conf_pos = (const float*)IN(3, 2);
  const float* scaf_x   = (const float*)IN(4, 3);
  const int*   scaf_ei  = (const int*)  IN(5, 64);
  const float* scaf_ea  = (const float*)IN(6, 4);
  const float* scaf_pos = (const float*)IN(7, 5);
  const int*   tokens   = (const int*)  IN(8, 65);
  const float* gfeat    = (const float*)IN(9, 6);
  const float* gproj_w  = (const float*)IN(11, 7);
  const float* gproj_b  = (const float*)IN(12, 8);
  const float* elin_w   = (const float*)IN(13, 9);
  const float* elin_b   = (const float*)IN(14, 10);
  const float* eln_g    = (const float*)IN(15, 11);
  const float* eln_b    = (const float*)IN(16, 12);
  const float* gt_qw    = (const float*)IN(17, 13);
  const float* gt_qb    = (const float*)IN(18, 14);
  const float* gt_kw    = (const float*)IN(19, 15);
  const float* gt_kb    = (const float*)IN(20, 16);
  const float* gt_vw    = (const float*)IN(21, 17);
  const float* gt_vb    = (const float*)IN(22, 18);
  const float* gt_ow    = (const float*)IN(23, 19);
  const float* gt_ob    = (const float*)IN(24, 20);
  const float* gt_ln1g  = (const float*)IN(25, 21);
  const float* gt_ln1b  = (const float*)IN(26, 22);
  const float* gt_f1w   = (const float*)IN(27, 23);
  const float* gt_f1b   = (const float*)IN(28, 24);
  const float* gt_f2w   = (const float*)IN(29, 25);
  const float* gt_f2b   = (const float*)IN(30, 26);
  const float* gt_ln2g  = (const float*)IN(31, 27);
  const float* gt_ln2b  = (const float*)IN(32, 28);
  const float* tok_emb  = (const float*)IN(33, 29);
  const float* pos_emb  = (const float*)IN(34, 30);
  const float* se_inw   = (const float*)IN(35, 31);
  const float* se_inb   = (const float*)IN(36, 32);
  const float* se_ow    = (const float*)IN(37, 33);
  const float* se_ob    = (const float*)IN(38, 34);
  const float* se_ln1g  = (const float*)IN(39, 35);
  const float* se_ln1b  = (const float*)IN(40, 36);
  const float* se_f1w   = (const float*)IN(41, 37);
  const float* se_f1b   = (const float*)IN(42, 38);
  const float* se_f2w   = (const float*)IN(43, 39);
  const float* se_f2b   = (const float*)IN(44, 40);
  const float* se_ln2g  = (const float*)IN(45, 41);
  const float* se_ln2b  = (const float*)IN(46, 42);
  const float* fg1_w    = (const float*)IN(47, 43);
  const float* fg1_b    = (const float*)IN(48, 44);
  const float* fg2_w    = (const float*)IN(49, 45);
  const float* fg2_b    = (const float*)IN(50, 46);
  const float* cm_g2s_vw = (const float*)IN(51, 47);
  const float* cm_g2s_vb = (const float*)IN(52, 48);
  const float* cm_g2s_ow = (const float*)IN(53, 49);
  const float* cm_g2s_ob = (const float*)IN(54, 50);
  const float* cm_s2g_vw = (const float*)IN(55, 53);
  const float* cm_s2g_vb = (const float*)IN(56, 54);
  const float* cm_s2g_ow = (const float*)IN(57, 55);
  const float* cm_s2g_ob = (const float*)IN(58, 56);
  const float* cm_n1g   = (const float*)IN(59, 51);
  const float* cm_n1b   = (const float*)IN(60, 52);
  const float* cm_n2g   = (const float*)IN(61, 57);
  const float* cm_n2b   = (const float*)IN(62, 58);
  const float* r1_w     = (const float*)IN(63, 59);
  const float* r1_b     = (const float*)IN(64, 60);
  const float* r2_w     = (const float*)IN(65, 61);
  const float* r2_b     = (const float*)IN(66, 62);
  float* out = (float*)d_out;

  // ---- workspace (fp32) ----
  float* w = (float*)d_ws;
  size_t off = 0;
  auto alloc = [&](size_t n) { float* p = w + off; off += n; return p; };
  float* h     = alloc(2560 * 128);
  float* aggr  = alloc(2560 * 128);
  float* hb    = alloc(2560 * 128);
  float* distb = alloc(80 * 1024);
  float* qb    = alloc(3 * 327680);     // graph q/k/v
  float* atto  = alloc(327680);
  float* xs2   = alloc(2048 * 128);
  float* qkv3  = alloc(2048 * 384);
  float* satto = alloc(2048 * 128);
  float* xsfin = alloc(2048 * 128);
  float* Gws   = w + off;               // 2560*6272 (factorized path only)
  const size_t needed = (off + (size_t)2560 * 6272) * sizeof(float);
  const bool factorized = (ws_size >= needed);

  // front (node_proj + zero aggr + dist + embed)
  front_k<<<2384, 256, 0, stream>>>(conf_x, scaf_x, gproj_w, gproj_b, h, aggr,
                                    conf_pos, scaf_pos, distb,
                                    tokens, tok_emb, pos_emb, xs2);
  if (factorized) {
    node_gemm_k<<<dim3(80, 49), 256, 0, stream>>>(h, elin_w, elin_b, Gws);
    combine_k<<<1280, 256, 0, stream>>>(conf_ea, scaf_ea, conf_ei, scaf_ei, Gws, aggr);
  } else {
    edge_gemm_k<<<dim3(160, 7), 256, 0, stream>>>(conf_ea, scaf_ea, conf_ei, scaf_ei, h, elin_w, elin_b, aggr);
  }
  ln_k<<<2560, 128, 0, stream>>>(aggr, h, eln_g, eln_b, hb);

  // merged graph(3) + seq(4) transformer layers
  for (int l = 0; l < 4; l++) {
    const bool hasG = (l < 3);
    const int lg = hasG ? l : 0;
    const int gq = hasG ? 480 : 0;
    const int ga = hasG ? 640 : 0;
    const int gt = hasG ? 160 : 0;
    float* sOut = (l == 3) ? xsfin : xs2;
    qkv_k<<<gq + 384, 256, 0, stream>>>(gq,
        hb, gt_qw + (size_t)lg * 16384, gt_kw + (size_t)lg * 16384, gt_vw + (size_t)lg * 16384,
        gt_qb + lg * 128, gt_kb + lg * 128, gt_vb + lg * 128, qb,
        xs2, se_inw + (size_t)l * 49152, se_inb + l * 384, qkv3);
    attn_k<<<ga + 256, 256, 0, stream>>>(ga, qb, qb + 327680, qb + 655360, distb, atto, qkv3, satto);
    tail_k<<<gt + 128, 256, 0, stream>>>(gt,
        atto, gt_ow + (size_t)lg * 16384, gt_ob + lg * 128, hb,
        gt_ln1g + lg * 128, gt_ln1b + lg * 128,
        gt_f1w + (size_t)lg * 32768, gt_f1b + lg * 256,
        gt_f2w + (size_t)lg * 32768, gt_f2b + lg * 128,
        gt_ln2g + lg * 128, gt_ln2b + lg * 128, hb,
        satto, se_ow + (size_t)l * 16384, se_ob + l * 128, xs2,
        se_ln1g + l * 128, se_ln1b + l * 128,
        se_f1w + (size_t)l * 32768, se_f1b + l * 256,
        se_f2w + (size_t)l * 32768, se_f2b + l * 128,
        se_ln2g + l * 128, se_ln2b + l * 128, sOut);
  }

  // head (1024-thread split-K)
  head_k<<<16, 1024, 0, stream>>>(hb, xsfin, gfeat,
                                  fg1_w, fg1_b, fg2_w, fg2_b,
                                  cm_g2s_vw, cm_g2s_vb, cm_g2s_ow, cm_g2s_ob, cm_n1g, cm_n1b,
                                  cm_s2g_vw, cm_s2g_vb, cm_s2g_ow, cm_s2g_ob, cm_n2g, cm_n2b,
                                  r1_w, r1_b, r2_w, r2_b, out);
}